// Round 6
// baseline (1164.189 us; speedup 1.0000x reference)
//
#include <hip/hip_runtime.h>

typedef unsigned short u16;
typedef unsigned int u32;
typedef unsigned long long u64;
typedef __attribute__((ext_vector_type(8))) short bfrag8;
typedef __attribute__((ext_vector_type(4))) float f32x4;
typedef __attribute__((address_space(1))) const void gconst_void;
typedef __attribute__((address_space(3))) void lds_void_t;

// ---------- helpers ----------
__device__ __forceinline__ float bf2f(u16 u) {
  return __uint_as_float(((u32)u) << 16);
}
__device__ __forceinline__ u16 f2bf(float f) {
  u32 u = __float_as_uint(f);
  u32 r = (u + 0x7FFFu + ((u >> 16) & 1u)) >> 16;  // RTNE
  return (u16)r;
}
__device__ __forceinline__ float ld1(const void* p, int isbf, long idx) {
  return isbf ? bf2f(((const u16*)p)[idx]) : ((const float*)p)[idx];
}
__device__ __forceinline__ void ld4(const void* p, int isbf, long base, long gc, long bound, float v[4]) {
  if (gc + 3 < bound && ((base & 3) == 0)) {
    if (isbf) {
      const ushort4 u = *(const ushort4*)((const u16*)p + base);
      v[0] = bf2f(u.x); v[1] = bf2f(u.y); v[2] = bf2f(u.z); v[3] = bf2f(u.w);
    } else {
      const float4 f = *(const float4*)((const float*)p + base);
      v[0] = f.x; v[1] = f.y; v[2] = f.z; v[3] = f.w;
    }
  } else {
    #pragma unroll
    for (int d = 0; d < 4; ++d) v[d] = (gc + d < bound) ? ld1(p, isbf, base + d) : 0.f;
  }
}

// ---------- input dtype autodetect (bf16 vs f32) ----------
__global__ void detect_init_k(int* flag) { if (threadIdx.x == 0 && blockIdx.x == 0) *flag = 0; }

__global__ void detect_k(const u32* __restrict__ a, long nw, int* __restrict__ flag) {
  long stride = (long)gridDim.x * 256;
  int f = 0;
  for (long j = (long)blockIdx.x * 256 + threadIdx.x; j < nw; j += stride) {
    u32 w = a[j];
    if (w == 0x00003F80u || w == 0x3F803F80u) f = 1;
  }
  if (__any(f)) {
    if ((threadIdx.x & 63) == 0) atomicOr(flag, 1);
  }
}

__device__ __forceinline__ int get_bf(int abf, const int* dtf) {
  return (abf >= 0) ? abf : *dtf;
}

// ---------- async global->LDS stage: 64 lanes x 16B ----------
__device__ __forceinline__ void stage16(const u16* g, u16* ldsbase, int lane) {
#if __has_builtin(__builtin_amdgcn_global_load_lds)
  __builtin_amdgcn_global_load_lds((gconst_void*)g, (lds_void_t*)ldsbase, 16, 0, 0);
#else
  *(ushort4*)(ldsbase + lane * 8) = *(const ushort4*)g;
#endif
}

// ---------- K-split triangle MFMA SYRK with atomic accumulate ----------
// C += (Ah+Al)(Ah+Al)^T over k-chunk [z*per, (z+1)*per); mirror-write; C must be
// zeroed first; diag zeroed afterwards. Exact: all values integers < 2^24, so
// fp32 atomicAdd is order-independent. grid = (nt(nt+1)/2, z)
template<int HASAL>
__global__ __launch_bounds__(256) void syrk_tri_z(
    const u16* __restrict__ Ah, const u16* __restrict__ Al, int ldk,
    float* __restrict__ C, int ldc, int per)
{
  __shared__ u16 Ath[128 * 32];
  __shared__ u16 Bth[128 * 32];
  __shared__ u16 Atl[HASAL ? 128 * 32 : 64];
  __shared__ u16 Btl[HASAL ? 128 * 32 : 64];
  __shared__ float tb[4][16][17];
  const int t = blockIdx.x;
  int ti = (int)((sqrtf((float)(8 * t + 1)) - 1.0f) * 0.5f);
  while ((ti + 1) * (ti + 2) / 2 <= t) ++ti;
  while (ti * (ti + 1) / 2 > t) --ti;
  const int tj = t - ti * (ti + 1) / 2;

  const int tid = threadIdx.x;
  const int wave = tid >> 6, lane = tid & 63;
  const int wr = wave >> 1, wc = wave & 1;
  const long rowA0 = (long)ti * 128;
  const long rowB0 = (long)tj * 128;
  const int kbeg = blockIdx.y * per;
  const int kend = kbeg + per;

  f32x4 acc[4][4];
  #pragma unroll
  for (int i = 0; i < 4; ++i)
    #pragma unroll
    for (int j = 0; j < 4; ++j) acc[i][j] = (f32x4)0.f;

  const int srow = (lane >> 2);
  const int scol = (lane & 3) * 8;
  const int m = lane & 15, q = lane >> 4;

  for (int k0 = kbeg; k0 < kend; k0 += 32) {
    #pragma unroll
    for (int tt = 0; tt < 2; ++tt) {
      const int r = wave * 32 + tt * 16;
      stage16(Ah + (rowA0 + r + srow) * (long)ldk + k0 + scol, Ath + r * 32, lane);
      stage16(Ah + (rowB0 + r + srow) * (long)ldk + k0 + scol, Bth + r * 32, lane);
      if (HASAL) {
        stage16(Al + (rowA0 + r + srow) * (long)ldk + k0 + scol, Atl + r * 32, lane);
        stage16(Al + (rowB0 + r + srow) * (long)ldk + k0 + scol, Btl + r * 32, lane);
      }
    }
    __syncthreads();

    bfrag8 afh[4], bfh[4];
    #pragma unroll
    for (int mt = 0; mt < 4; ++mt)
      afh[mt] = *(const bfrag8*)(Ath + (wr * 64 + mt * 16 + m) * 32 + q * 8);
    #pragma unroll
    for (int nt = 0; nt < 4; ++nt)
      bfh[nt] = *(const bfrag8*)(Bth + (wc * 64 + nt * 16 + m) * 32 + q * 8);
    if (HASAL) {
      bfrag8 afl[4], bfl[4];
      #pragma unroll
      for (int mt = 0; mt < 4; ++mt)
        afl[mt] = *(const bfrag8*)(Atl + (wr * 64 + mt * 16 + m) * 32 + q * 8);
      #pragma unroll
      for (int nt = 0; nt < 4; ++nt)
        bfl[nt] = *(const bfrag8*)(Btl + (wc * 64 + nt * 16 + m) * 32 + q * 8);
      #pragma unroll
      for (int mt = 0; mt < 4; ++mt)
        #pragma unroll
        for (int nt = 0; nt < 4; ++nt) {
          acc[mt][nt] = __builtin_amdgcn_mfma_f32_16x16x32_bf16(afh[mt], bfh[nt], acc[mt][nt], 0, 0, 0);
          acc[mt][nt] = __builtin_amdgcn_mfma_f32_16x16x32_bf16(afh[mt], bfl[nt], acc[mt][nt], 0, 0, 0);
          acc[mt][nt] = __builtin_amdgcn_mfma_f32_16x16x32_bf16(afl[mt], bfh[nt], acc[mt][nt], 0, 0, 0);
          acc[mt][nt] = __builtin_amdgcn_mfma_f32_16x16x32_bf16(afl[mt], bfl[nt], acc[mt][nt], 0, 0, 0);
        }
    } else {
      #pragma unroll
      for (int mt = 0; mt < 4; ++mt)
        #pragma unroll
        for (int nt = 0; nt < 4; ++nt)
          acc[mt][nt] = __builtin_amdgcn_mfma_f32_16x16x32_bf16(afh[mt], bfh[nt], acc[mt][nt], 0, 0, 0);
    }
    __syncthreads();
  }

  // lower-triangle tile accumulate
  #pragma unroll
  for (int mt = 0; mt < 4; ++mt) {
    #pragma unroll
    for (int nt = 0; nt < 4; ++nt) {
      const long gr0 = rowA0 + wr * 64 + mt * 16 + q * 4;
      const long gc = rowB0 + wc * 64 + nt * 16 + m;
      #pragma unroll
      for (int r = 0; r < 4; ++r)
        atomicAdd(&C[(gr0 + r) * ldc + gc], acc[mt][nt][r]);
    }
  }
  // mirror accumulate via in-LDS 16x16 fragment transpose (coalesced)
  if (ti != tj) {
    #pragma unroll
    for (int mt = 0; mt < 4; ++mt) {
      #pragma unroll
      for (int nt = 0; nt < 4; ++nt) {
        #pragma unroll
        for (int r = 0; r < 4; ++r) tb[wave][q * 4 + r][m] = acc[mt][nt][r];
        const long baseR = rowB0 + wc * 64 + nt * 16;
        const long baseC = rowA0 + wr * 64 + mt * 16;
        #pragma unroll
        for (int r = 0; r < 4; ++r)
          atomicAdd(&C[(baseR + q * 4 + r) * ldc + baseC + m], tb[wave][m][q * 4 + r]);
      }
    }
  }
}

__global__ void zerodiag_k(float* __restrict__ A, int n) {
  int i = blockIdx.x * 256 + threadIdx.x;
  if (i < n) A[(long)i * n + i] = 0.f;
}

// build level-2 augment operand in exact 2-plane bf16: v = As2[perm_r, c] + (c==perm_r)
__global__ void build_ag3_split_k(const float* __restrict__ src, int nsrc,
                                  const int* __restrict__ perm, long tot, int ld,
                                  u16* __restrict__ Agh, u16* __restrict__ Agl) {
  long idx = (long)blockIdx.x * 256 + threadIdx.x;
  if (idx >= tot) return;
  int r = (int)(idx / ld);
  int c = (int)(idx - (long)r * ld);
  int p = perm[r];
  float v = src[(long)p * nsrc + c];
  if (c == p) v += 1.f;
  u16 h = f2bf(v);
  Agh[idx] = h;
  Agl[idx] = f2bf(v - bf2f(h));
}

// ---------- MFMA aggregation: Y = A @ Z (A exact bf16 planes, Z 3-plane split) ----------
template<int NT>
__global__ __launch_bounds__(256) void agg_mfma(
    const u16* __restrict__ Ah, const u16* __restrict__ Al,
    const u16* __restrict__ ZT, float* __restrict__ parts,
    int K, int per_steps)
{
  __shared__ u16 At[128 * 32];
  __shared__ u16 Alt[128 * 32];
  __shared__ u16 Zt[3 * NT * 512];
  const int tid = threadIdx.x;
  const int wave = tid >> 6, lane = tid & 63;
  const long row0 = (long)blockIdx.x * 128;
  const int chunk = blockIdx.y;
  const int kbeg = chunk * per_steps * 32;
  const int kend = min(K, kbeg + per_steps * 32);
  const int m = lane & 15, q = lane >> 4;
  const int srow = lane >> 2, scol = (lane & 3) * 8;
  const bool hasAl = (Al != nullptr);

  f32x4 acc[2][NT];
  #pragma unroll
  for (int rt = 0; rt < 2; ++rt)
    #pragma unroll
    for (int ct = 0; ct < NT; ++ct) acc[rt][ct] = (f32x4)0.f;

  for (int k0 = kbeg; k0 < kend; k0 += 32) {
    #pragma unroll
    for (int t = 0; t < 2; ++t) {
      const int r = wave * 32 + t * 16;
      stage16(Ah + (row0 + r + srow) * (long)K + k0 + scol, At + r * 32, lane);
      if (hasAl)
        stage16(Al + (row0 + r + srow) * (long)K + k0 + scol, Alt + r * 32, lane);
    }
    for (int s = wave; s < 3 * NT; s += 4) {
      const u16* g = ZT + ((long)(s * 16 + srow)) * K + k0 + scol;
      stage16(g, Zt + s * 512, lane);
    }
    __syncthreads();

    bfrag8 af0 = *(const bfrag8*)(At + (wave * 32 + m) * 32 + q * 8);
    bfrag8 af1 = *(const bfrag8*)(At + (wave * 32 + 16 + m) * 32 + q * 8);
    bfrag8 al0, al1;
    if (hasAl) {
      al0 = *(const bfrag8*)(Alt + (wave * 32 + m) * 32 + q * 8);
      al1 = *(const bfrag8*)(Alt + (wave * 32 + 16 + m) * 32 + q * 8);
    }
    #pragma unroll
    for (int ct = 0; ct < NT; ++ct) {
      bfrag8 b0 = *(const bfrag8*)(Zt + (0 * NT + ct) * 512 + m * 32 + q * 8);
      bfrag8 b1 = *(const bfrag8*)(Zt + (1 * NT + ct) * 512 + m * 32 + q * 8);
      bfrag8 b2 = *(const bfrag8*)(Zt + (2 * NT + ct) * 512 + m * 32 + q * 8);
      acc[0][ct] = __builtin_amdgcn_mfma_f32_16x16x32_bf16(af0, b0, acc[0][ct], 0, 0, 0);
      acc[0][ct] = __builtin_amdgcn_mfma_f32_16x16x32_bf16(af0, b1, acc[0][ct], 0, 0, 0);
      acc[0][ct] = __builtin_amdgcn_mfma_f32_16x16x32_bf16(af0, b2, acc[0][ct], 0, 0, 0);
      acc[1][ct] = __builtin_amdgcn_mfma_f32_16x16x32_bf16(af1, b0, acc[1][ct], 0, 0, 0);
      acc[1][ct] = __builtin_amdgcn_mfma_f32_16x16x32_bf16(af1, b1, acc[1][ct], 0, 0, 0);
      acc[1][ct] = __builtin_amdgcn_mfma_f32_16x16x32_bf16(af1, b2, acc[1][ct], 0, 0, 0);
      if (hasAl) {
        acc[0][ct] = __builtin_amdgcn_mfma_f32_16x16x32_bf16(al0, b0, acc[0][ct], 0, 0, 0);
        acc[0][ct] = __builtin_amdgcn_mfma_f32_16x16x32_bf16(al0, b1, acc[0][ct], 0, 0, 0);
        acc[1][ct] = __builtin_amdgcn_mfma_f32_16x16x32_bf16(al1, b0, acc[1][ct], 0, 0, 0);
        acc[1][ct] = __builtin_amdgcn_mfma_f32_16x16x32_bf16(al1, b1, acc[1][ct], 0, 0, 0);
      }
    }
    __syncthreads();
  }

  float* P = parts + (long)chunk * gridDim.x * 128 * (NT * 16);
  #pragma unroll
  for (int rt = 0; rt < 2; ++rt) {
    #pragma unroll
    for (int ct = 0; ct < NT; ++ct) {
      const long grow0 = row0 + wave * 32 + rt * 16 + q * 4;
      const long gcol = ct * 16 + m;
      #pragma unroll
      for (int r = 0; r < 4; ++r)
        P[(grow0 + r) * (NT * 16) + gcol] = acc[rt][ct][r];
    }
  }
}

__global__ void reduce_k(const float* __restrict__ parts, float* __restrict__ Y,
                         long n208, int nz) {
  long idx = (long)blockIdx.x * 256 + threadIdx.x;
  if (idx >= n208) return;
  float s = 0.f;
  for (int c = 0; c < nz; ++c) s += parts[(long)c * n208 + idx];
  Y[idx] = s;
}

// Z (n x 200 f32) -> 3 bf16 planes transposed: ZT[(p*208+c)*n + k]
__global__ void zsplit_k(const float* __restrict__ Z, int n, int h, u16* __restrict__ ZT) {
  __shared__ float t[32][33];
  const int kb = blockIdx.x * 32;
  const int cb = blockIdx.y * 32;
  #pragma unroll
  for (int i = 0; i < 32; i += 8) {
    int k = kb + threadIdx.y + i;
    int c = cb + threadIdx.x;
    t[threadIdx.y + i][threadIdx.x] = (c < h) ? Z[(long)k * h + c] : 0.f;
  }
  __syncthreads();
  #pragma unroll
  for (int i = 0; i < 32; i += 8) {
    int c = cb + threadIdx.y + i;
    if (c >= 208) continue;
    long k = kb + threadIdx.x;
    float v = t[threadIdx.x][threadIdx.y + i];
    u16 hi = f2bf(v); float r1 = v - bf2f(hi);
    u16 mi = f2bf(r1); float r2 = r1 - bf2f(mi);
    u16 lo = f2bf(r2);
    ZT[((long)0 * 208 + c) * n + k] = hi;
    ZT[((long)1 * 208 + c) * n + k] = mi;
    ZT[((long)2 * 208 + c) * n + k] = lo;
  }
}

// split fp32 A into exact bf16 hi/lo planes (Al nullable)
__global__ void asplit_k(const float* __restrict__ src, long tot,
                         u16* __restrict__ Ah, u16* __restrict__ Al) {
  long idx = (long)blockIdx.x * 256 + threadIdx.x;
  if (idx >= tot) return;
  float v = src[idx];
  u16 h = f2bf(v);
  Ah[idx] = h;
  if (Al) Al[idx] = f2bf(v - bf2f(h));
}

__global__ void a_from_adj_k(const void* __restrict__ adj, const int* __restrict__ dtf,
                             long tot, u16* __restrict__ Ah) {
  int bf = *dtf;
  long idx = (long)blockIdx.x * 256 + threadIdx.x;
  if (idx >= tot) return;
  Ah[idx] = bf ? ((const u16*)adj)[idx] : f2bf(((const float*)adj)[idx]);
}

// build Ag (bf16) = src[perm,:] + I
__global__ void build_ag_bf_k(const void* __restrict__ src, int srcbf, int nsrc,
                              const int* __restrict__ perm, long tot, int ld,
                              u16* __restrict__ Ag, const int* __restrict__ dtf) {
  long idx = (long)blockIdx.x * 256 + threadIdx.x;
  if (idx >= tot) return;
  int r = (int)(idx / ld);
  int c = (int)(idx - (long)r * ld);
  int p = perm[r];
  float v = ld1(src, get_bf(srcbf, dtf), (long)p * nsrc + c);
  if (c == p) v += 1.f;
  Ag[idx] = f2bf(v);
}

// ---------- fp64-accumulating GEMM, 64x64 tile (x@W feature path) ----------
__global__ __launch_bounds__(256) void gemm64_f64(
    const void* __restrict__ Ap, long lda, int abf,
    const void* __restrict__ Bp, long ldb, int bbf,
    float* __restrict__ C, long ldc, int M, int N, int K,
    const int* __restrict__ dtf)
{
  const int abf_ = get_bf(abf, dtf);
  const int bbf_ = get_bf(bbf, dtf);
  __shared__ float As[16][64];
  __shared__ float Bs[16][64];
  const int tid = threadIdx.x;
  const int tr = tid >> 4, tc = tid & 15;
  const long row0 = (long)blockIdx.y * 64;
  const long col0 = (long)blockIdx.x * 64;
  double acc[4][4];
  #pragma unroll
  for (int i = 0; i < 4; ++i)
    #pragma unroll
    for (int j = 0; j < 4; ++j) acc[i][j] = 0.0;

  const int am = tid >> 2;
  const int ak = (tid & 3) * 4;
  const int bk = tid >> 4;
  const int bn = (tid & 15) * 4;

  for (int k0 = 0; k0 < K; k0 += 16) {
    float va[4] = {0.f, 0.f, 0.f, 0.f};
    {
      long gm = row0 + am; long gk = k0 + ak;
      if (gm < M && gk < K) ld4(Ap, abf_, gm * lda + gk, gk, K, va);
    }
    As[ak + 0][am] = va[0]; As[ak + 1][am] = va[1];
    As[ak + 2][am] = va[2]; As[ak + 3][am] = va[3];

    float vb[4] = {0.f, 0.f, 0.f, 0.f};
    {
      long gk = k0 + bk; long gn = col0 + bn;
      if (gk < K && gn < N) ld4(Bp, bbf_, gk * ldb + gn, gn, N, vb);
    }
    Bs[bk][bn + 0] = vb[0]; Bs[bk][bn + 1] = vb[1];
    Bs[bk][bn + 2] = vb[2]; Bs[bk][bn + 3] = vb[3];

    __syncthreads();
    #pragma unroll
    for (int kk = 0; kk < 16; ++kk) {
      float a[4], b[4];
      #pragma unroll
      for (int i = 0; i < 4; ++i) a[i] = As[kk][tr * 4 + i];
      #pragma unroll
      for (int j = 0; j < 4; ++j) b[j] = Bs[kk][tc * 4 + j];
      #pragma unroll
      for (int i = 0; i < 4; ++i)
        #pragma unroll
        for (int j = 0; j < 4; ++j)
          acc[i][j] += (double)a[i] * (double)b[j];
    }
    __syncthreads();
  }
  #pragma unroll
  for (int i = 0; i < 4; ++i) {
    long gm = row0 + tr * 4 + i;
    if (gm >= M) continue;
    #pragma unroll
    for (int j = 0; j < 4; ++j) {
      long gn = col0 + tc * 4 + j;
      if (gn < N) C[gm * ldc + gn] = (float)acc[i][j];
    }
  }
}

// ---------- small kernels ----------
__global__ void upcast_k(const void* __restrict__ src, float* __restrict__ dst, int n,
                         const int* __restrict__ dtf) {
  int bf = *dtf;
  int i = blockIdx.x * 256 + threadIdx.x;
  if (i < n) dst[i] = ld1(src, bf, i);
}

__global__ void rowsum_dinv_k(const void* __restrict__ A, int abf, int n, float* __restrict__ dinv,
                              const int* __restrict__ dtf) {
  const int bf = get_bf(abf, dtf);
  const int row = blockIdx.x;
  const int tid = threadIdx.x;
  const long base = (long)row * n;
  double s = 0.0;
  for (int j = tid; j < n; j += 256) s += (double)ld1(A, bf, base + j);
  __shared__ double red[256];
  red[tid] = s; __syncthreads();
  for (int st = 128; st > 0; st >>= 1) {
    if (tid < st) red[tid] += red[tid + st];
    __syncthreads();
  }
  if (tid == 0) dinv[row] = (float)(1.0 / sqrt(red[0] + 2.0));
}

__global__ void scale_rows_k(float* __restrict__ Z, const float* __restrict__ dinv, int n, int h) {
  long idx = (long)blockIdx.x * 256 + threadIdx.x;
  if (idx < (long)n * h) Z[idx] *= dinv[idx / h];
}

// Y has leading dim 208; Zs has leading dim h(=200)
__global__ void gcn_epi_k(const float* __restrict__ Y, const float* __restrict__ Zs,
                          const float* __restrict__ dinv, const float* __restrict__ b,
                          float* __restrict__ out, int n, int h, int relu) {
  long idx = (long)blockIdx.x * 256 + threadIdx.x;
  if (idx >= (long)n * h) return;
  int i = (int)(idx / h);
  int j = (int)(idx - (long)i * h);
  float v = dinv[i] * (Y[(long)i * 208 + j] + 2.f * Zs[idx]) + b[j];
  if (relu) v = fmaxf(v, 0.f);
  out[idx] = v;
}

__global__ void pnorm_k(const float* __restrict__ p, int h, double* __restrict__ out) {
  int tid = threadIdx.x;
  double s = 0.0;
  for (int j = tid; j < h; j += 256) { double v = p[j]; s += v * v; }
  __shared__ double red[256];
  red[tid] = s; __syncthreads();
  for (int st = 128; st > 0; st >>= 1) {
    if (tid < st) red[tid] += red[tid + st];
    __syncthreads();
  }
  if (tid == 0) out[0] = sqrt(red[0]);
}

__global__ void score_k(const float* __restrict__ x, int h, const float* __restrict__ pw,
                        const double* __restrict__ pnorm, float* __restrict__ score) {
  int row = blockIdx.x, lane = threadIdx.x;
  const long base = (long)row * h;
  double s = 0.0;
  for (int j = lane; j < h; j += 64) s += (double)x[base + j] * (double)pw[j];
  for (int off = 32; off > 0; off >>= 1) s += __shfl_down(s, off);
  if (lane == 0) score[row] = (float)tanh(s / pnorm[0]);
}

// exact jax.lax.top_k order: descending value, ascending index on ties
__global__ __launch_bounds__(1024) void topk_k(const float* __restrict__ score,
                                               int n, int np2, int k, int* __restrict__ perm) {
  __shared__ u64 keys[4096];
  const int tid = threadIdx.x;
  for (int i = tid; i < np2; i += 1024) {
    u64 key = 0ULL;
    if (i < n) {
      u32 b = __float_as_uint(score[i]);
      u32 u = (b & 0x80000000u) ? ~b : (b | 0x80000000u);
      key = ((u64)u << 32) | (u32)(~(u32)i);
    }
    keys[i] = key;
  }
  __syncthreads();
  for (int size = 2; size <= np2; size <<= 1) {
    for (int stride = size >> 1; stride > 0; stride >>= 1) {
      for (int i = tid; i < np2; i += 1024) {
        int j = i ^ stride;
        if (j > i) {
          u64 a = keys[i], b = keys[j];
          bool up = ((i & size) == 0);
          if (up ? (a > b) : (a < b)) { keys[i] = b; keys[j] = a; }
        }
      }
      __syncthreads();
    }
  }
  for (int r = tid; r < k; r += 1024) {
    u64 kk = keys[np2 - 1 - r];
    perm[r] = (int)(~(u32)(kk & 0xFFFFFFFFull));
  }
}

__global__ void gatherx_k(const float* __restrict__ xsrc, const float* __restrict__ score,
                          const int* __restrict__ perm, int k, int h, float* __restrict__ xdst) {
  long idx = (long)blockIdx.x * 256 + threadIdx.x;
  if (idx >= (long)k * h) return;
  int r = (int)(idx / h);
  int c = (int)(idx - (long)r * h);
  int p = perm[r];
  xdst[idx] = xsrc[(long)p * h + c] * score[p];
}

__global__ void copy_k(const float* __restrict__ src, float* __restrict__ dst, long n) {
  long idx = (long)blockIdx.x * 256 + threadIdx.x;
  if (idx < n) dst[idx] = src[idx];
}

__global__ void scatter_add_k(float* __restrict__ dst, const int* __restrict__ perm,
                              const float* __restrict__ src, int k, int h) {
  long idx = (long)blockIdx.x * 256 + threadIdx.x;
  if (idx >= (long)k * h) return;
  int r = (int)(idx / h);
  int c = (int)(idx - (long)r * h);
  dst[(long)perm[r] * h + c] += src[idx];
}

__global__ void matvec2_k(const void* __restrict__ A, int abf, int n,
                          const float* __restrict__ Zs, float* __restrict__ Y,
                          const int* __restrict__ dtf) {
  const int bf = get_bf(abf, dtf);
  int row = blockIdx.x, tid = threadIdx.x;
  const long base = (long)row * n;
  double s0 = 0.0, s1 = 0.0;
  for (int j = tid; j < n; j += 256) {
    double a = (double)ld1(A, bf, base + j);
    s0 += a * (double)Zs[2 * j];
    s1 += a * (double)Zs[2 * j + 1];
  }
  __shared__ double r0[256], r1[256];
  r0[tid] = s0; r1[tid] = s1; __syncthreads();
  for (int st = 128; st > 0; st >>= 1) {
    if (tid < st) { r0[tid] += r0[tid + st]; r1[tid] += r1[tid + st]; }
    __syncthreads();
  }
  if (tid == 0) { Y[2 * row] = (float)r0[0]; Y[2 * row + 1] = (float)r1[0]; }
}

__global__ void final_k(const float* __restrict__ Y, const float* __restrict__ Zs,
                        const float* __restrict__ dinv, const float* __restrict__ b2,
                        int n, float* __restrict__ out) {
  int i = blockIdx.x * 256 + threadIdx.x;
  if (i >= n) return;
  double di = dinv[i];
  double t0 = di * ((double)Y[2 * i] + 2.0 * (double)Zs[2 * i]) + (double)b2[0];
  double t1 = di * ((double)Y[2 * i + 1] + 2.0 * (double)Zs[2 * i + 1]) + (double)b2[1];
  double m = fmax(t0, t1);
  double l = m + log(exp(t0 - m) + exp(t1 - m));
  out[2 * i] = (float)(t0 - l);
  out[2 * i + 1] = (float)(t1 - l);
}

// ---------- host orchestration ----------
extern "C" void kernel_launch(void* const* d_in, const int* in_sizes, int n_in,
                              void* d_out, int out_size, void* d_ws, size_t ws_size,
                              hipStream_t stream) {
  const int N0 = 4096, H = 200;
  const int K1 = 3072, K2 = 1536, K3 = 768;

  const void* in_x = d_in[0];
  const void* adj  = d_in[1];
  const void* w0 = d_in[2];  const void* b0 = d_in[3];
  const void* w1 = d_in[4];  const void* b1 = d_in[5];
  const void* w2 = d_in[6];  const void* b2 = d_in[7];
  const void* w3 = d_in[8];  const void* b3 = d_in[9];
  const void* p1 = d_in[10]; const void* p2 = d_in[11];
  const void* p3 = d_in[12];
  const void* u0w = d_in[13]; const void* u0b = d_in[14];
  const void* u1w = d_in[15]; const void* u1b = d_in[16];
  const void* u2w = d_in[17]; const void* u2b = d_in[18];

  char* wp = (char*)d_ws;
  auto alloc = [&](size_t bytes) -> void* {
    void* p = (void*)wp;
    wp += (bytes + 255) & ~(size_t)255;
    return p;
  };
  float* As1  = (float*)alloc((size_t)K1 * K1 * 4);          // 37.7 MB
  float* As2  = (float*)alloc((size_t)K2 * K2 * 4);          // 9.4 MB
  float* A3   = (float*)alloc((size_t)K3 * K3 * 4);          // 2.4 MB
  // shared scratch: Agb (syrk staging) / parts (agg k-split) — lifetimes disjoint
  size_t scrBytes = (size_t)36864 * 208 * 4 + 1024;          // 30.7 MB (12x3072 & 24x1536 chunks)
  void* scratchU = alloc(scrBytes);
  u16*   Agb  = (u16*)scratchU;
  float* parts = (float*)scratchU;
  u16* Ag3h = (u16*)alloc((size_t)K3 * K2 * 2);              // 2.4 MB
  u16* Ag3l = (u16*)alloc((size_t)K3 * K2 * 2);              // 2.4 MB
  u16* Ah0 = (u16*)alloc((size_t)N0 * N0 * 2);               // 33.5 MB
  u16* Ah1 = (u16*)alloc((size_t)K1 * K1 * 2);               // 18.9 MB
  u16* Ah2 = (u16*)alloc((size_t)K2 * K2 * 2);               // 4.7 MB
  u16* Al2 = (u16*)alloc((size_t)K2 * K2 * 2);               // 4.7 MB
  u16* Ah3 = (u16*)alloc((size_t)K3 * K3 * 2);               // 1.2 MB
  u16* Al3 = (u16*)alloc((size_t)K3 * K3 * 2);               // 1.2 MB
  u16* ZT  = (u16*)alloc((size_t)3 * 208 * N0 * 2);          // 5.1 MB
  float* xs0  = (float*)alloc((size_t)N0 * H * 4);
  float* xs1  = (float*)alloc((size_t)K1 * H * 4);
  float* xs2  = (float*)alloc((size_t)K2 * H * 4);
  float* xcur = (float*)alloc((size_t)N0 * H * 4);
  float* xtmp = (float*)alloc((size_t)N0 * H * 4);
  float* Zbuf = (float*)alloc((size_t)N0 * H * 4);
  float* Ybuf = (float*)alloc((size_t)N0 * 208 * 4);
  float* Xinf = (float*)alloc((size_t)N0 * 3 * 4);
  float* dinv0 = (float*)alloc((size_t)N0 * 4);
  float* dinv1 = (float*)alloc((size_t)K1 * 4);
  float* dinv2 = (float*)alloc((size_t)K2 * 4);
  float* dinv3 = (float*)alloc((size_t)K3 * 4);
  float* scores = (float*)alloc((size_t)N0 * 4);
  int* perm1 = (int*)alloc((size_t)K1 * 4);
  int* perm2 = (int*)alloc((size_t)K2 * 4);
  int* perm3 = (int*)alloc((size_t)K3 * 4);
  double* pn = (double*)alloc(8);
  int* dtflag = (int*)alloc(256);
  float* w0f = (float*)alloc(3 * H * 4);  float* b0f = (float*)alloc(H * 4);
  float* w1f = (float*)alloc(H * H * 4);  float* b1f = (float*)alloc(H * 4);
  float* w2f = (float*)alloc(H * H * 4);  float* b2f = (float*)alloc(H * 4);
  float* w3f = (float*)alloc(H * H * 4);  float* b3f = (float*)alloc(H * 4);
  float* p1f = (float*)alloc(H * 4);
  float* p2f = (float*)alloc(H * 4);
  float* p3f = (float*)alloc(H * 4);
  float* u0wf = (float*)alloc(H * H * 4); float* u0bf = (float*)alloc(H * 4);
  float* u1wf = (float*)alloc(H * H * 4); float* u1bf = (float*)alloc(H * 4);
  float* u2wf = (float*)alloc(H * 2 * 4); float* u2bf = (float*)alloc(2 * 4);
  (void)in_sizes; (void)n_in; (void)out_size; (void)ws_size;

  detect_init_k<<<dim3(1), dim3(64), 0, stream>>>(dtflag);
  detect_k<<<dim3(4096), dim3(256), 0, stream>>>((const u32*)adj, (long)N0 * N0 / 2, dtflag);

  auto up = [&](const void* s, float* d, int n) {
    upcast_k<<<dim3((n + 255) / 256), dim3(256), 0, stream>>>(s, d, n, dtflag);
  };
  up(in_x, Xinf, N0 * 3);
  up(w0, w0f, 3 * H);  up(b0, b0f, H);
  up(w1, w1f, H * H);  up(b1, b1f, H);
  up(w2, w2f, H * H);  up(b2, b2f, H);
  up(w3, w3f, H * H);  up(b3, b3f, H);
  up(p1, p1f, H); up(p2, p2f, H); up(p3, p3f, H);
  up(u0w, u0wf, H * H); up(u0b, u0bf, H);
  up(u1w, u1wf, H * H); up(u1b, u1bf, H);
  up(u2w, u2wf, H * 2); up(u2b, u2bf, 2);

  a_from_adj_k<<<dim3((unsigned)(((long)N0 * N0 + 255) / 256)), dim3(256), 0, stream>>>(
      adj, dtflag, (long)N0 * N0, Ah0);

  auto gemm64 = [&](const void* A, long lda, int abf, const void* B, long ldb, int bbf,
                    float* C, long ldc, int M, int Nn, int K) {
    dim3 g((Nn + 63) / 64, (M + 63) / 64);
    gemm64_f64<<<g, dim3(256), 0, stream>>>(A, lda, abf, B, ldb, bbf, C, ldc, M, Nn, K, dtflag);
  };

  // GCN: out = maybe_relu(dinv .* (A@Zs + 2 Zs) + b); chunks chosen for occupancy
  auto gcn = [&](const u16* Ah, const u16* Al, int n, int chunks, const float* dinv,
                 const float* Xin_, int din, const float* W, const float* bb,
                 float* out, int relu) {
    gemm64(Xin_, din, 0, W, H, 0, Zbuf, H, n, H, din);
    long tot = (long)n * H;
    scale_rows_k<<<dim3((unsigned)((tot + 255) / 256)), dim3(256), 0, stream>>>(Zbuf, dinv, n, H);
    zsplit_k<<<dim3(n / 32, 7), dim3(32, 8), 0, stream>>>(Zbuf, n, H, ZT);
    agg_mfma<13><<<dim3(n / 128, chunks), dim3(256), 0, stream>>>(
        Ah, Al, ZT, parts, n, (n / 32) / chunks);
    long n208 = (long)n * 208;
    reduce_k<<<dim3((unsigned)((n208 + 255) / 256)), dim3(256), 0, stream>>>(
        parts, Ybuf, n208, chunks);
    gcn_epi_k<<<dim3((unsigned)((tot + 255) / 256)), dim3(256), 0, stream>>>(
        Ybuf, Zbuf, dinv, bb, out, n, H, relu);
  };

  auto pool = [&](const float* xin, int n, int np2, int k, const float* pwf,
                  int* perm, float* xout) {
    pnorm_k<<<dim3(1), dim3(256), 0, stream>>>(pwf, H, pn);
    score_k<<<dim3(n), dim3(64), 0, stream>>>(xin, H, pwf, pn, scores);
    topk_k<<<dim3(1), dim3(1024), 0, stream>>>(scores, n, np2, k, perm);
    long tot = (long)k * H;
    gatherx_k<<<dim3((unsigned)((tot + 255) / 256)), dim3(256), 0, stream>>>(
        xin, scores, perm, k, H, xout);
  };

  // K-split atomic triangle SYRK: dst = Ag@Ag^T, diag 0 (exact integers)
  auto syrk = [&](const u16* Ah, const u16* Al, int k, int Kdim, int z, float* dst) {
    hipMemsetAsync(dst, 0, (size_t)k * k * 4, stream);
    int nt = k / 128;
    dim3 g(nt * (nt + 1) / 2, z);
    if (Al)
      syrk_tri_z<1><<<g, dim3(256), 0, stream>>>(Ah, Al, Kdim, dst, k, Kdim / z);
    else
      syrk_tri_z<0><<<g, dim3(256), 0, stream>>>(Ah, nullptr, Kdim, dst, k, Kdim / z);
    zerodiag_k<<<dim3((k + 255) / 256), dim3(256), 0, stream>>>(dst, k);
  };

  // ---------------- forward ----------------
  rowsum_dinv_k<<<dim3(N0), dim3(256), 0, stream>>>(adj, -1, N0, dinv0, dtflag);
  gcn(Ah0, nullptr, N0, 8, dinv0, Xinf, 3, w0f, b0f, xs0, 1);

  // down 0
  pool(xs0, N0, 4096, K1, p1f, perm1, xcur);
  {
    long tot = (long)K1 * N0;
    build_ag_bf_k<<<dim3((unsigned)((tot + 255) / 256)), dim3(256), 0, stream>>>(
        adj, -1, N0, perm1, tot, N0, Agb, dtflag);
    syrk(Agb, nullptr, K1, N0, 2, As1);                       // 600 blocks
  }
  asplit_k<<<dim3((unsigned)(((long)K1 * K1 + 255) / 256)), dim3(256), 0, stream>>>(
      As1, (long)K1 * K1, Ah1, nullptr);
  rowsum_dinv_k<<<dim3(K1), dim3(256), 0, stream>>>(As1, 0, K1, dinv1, dtflag);
  gcn(Ah1, nullptr, K1, 12, dinv1, xcur, H, w1f, b1f, xs1, 1);

  // down 1
  pool(xs1, K1, 4096, K2, p2f, perm2, xcur);
  {
    long tot = (long)K2 * K1;
    build_ag_bf_k<<<dim3((unsigned)((tot + 255) / 256)), dim3(256), 0, stream>>>(
        As1, 0, K1, perm2, tot, K1, Agb, dtflag);
    syrk(Agb, nullptr, K2, K1, 4, As2);                       // 312 blocks
  }
  asplit_k<<<dim3((unsigned)(((long)K2 * K2 + 255) / 256)), dim3(256), 0, stream>>>(
      As2, (long)K2 * K2, Ah2, Al2);
  rowsum_dinv_k<<<dim3(K2), dim3(256), 0, stream>>>(As2, 0, K2, dinv2, dtflag);
  gcn(Ah2, Al2, K2, 24, dinv2, xcur, H, w2f, b2f, xs2, 1);

  // down 2 (2-plane exact)
  pool(xs2, K2, 2048, K3, p3f, perm3, xcur);
  {
    long tot = (long)K3 * K2;
    build_ag3_split_k<<<dim3((unsigned)((tot + 255) / 256)), dim3(256), 0, stream>>>(
        As2, K2, perm3, tot, K2, Ag3h, Ag3l);
    syrk(Ag3h, Ag3l, K3, K2, 8, A3);                          // 168 blocks
  }
  asplit_k<<<dim3((unsigned)(((long)K3 * K3 + 255) / 256)), dim3(256), 0, stream>>>(
      A3, (long)K3 * K3, Ah3, Al3);
  rowsum_dinv_k<<<dim3(K3), dim3(256), 0, stream>>>(A3, 0, K3, dinv3, dtflag);
  gcn(Ah3, Al3, K3, 24, dinv3, xcur, H, w3f, b3f, xcur, 1);

  // up 0: j=2
  copy_k<<<dim3((unsigned)(((long)K2 * H + 255) / 256)), dim3(256), 0, stream>>>(xs2, xtmp, (long)K2 * H);
  scatter_add_k<<<dim3((unsigned)(((long)K3 * H + 255) / 256)), dim3(256), 0, stream>>>(xtmp, perm3, xcur, K3, H);
  gcn(Ah2, Al2, K2, 24, dinv2, xtmp, H, u0wf, u0bf, xcur, 1);

  // up 1: j=1
  copy_k<<<dim3((unsigned)(((long)K1 * H + 255) / 256)), dim3(256), 0, stream>>>(xs1, xtmp, (long)K1 * H);
  scatter_add_k<<<dim3((unsigned)(((long)K2 * H + 255) / 256)), dim3(256), 0, stream>>>(xtmp, perm2, xcur, K2, H);
  gcn(Ah1, nullptr, K1, 12, dinv1, xtmp, H, u1wf, u1bf, xcur, 1);

  // up 2: j=0
  copy_k<<<dim3((unsigned)(((long)N0 * H + 255) / 256)), dim3(256), 0, stream>>>(xs0, xtmp, (long)N0 * H);
  scatter_add_k<<<dim3((unsigned)(((long)K1 * H + 255) / 256)), dim3(256), 0, stream>>>(xtmp, perm1, xcur, K1, H);
  gemm64(xtmp, H, 0, u2wf, 2, 0, Zbuf, 2, N0, 2, H);
  scale_rows_k<<<dim3((N0 * 2 + 255) / 256), dim3(256), 0, stream>>>(Zbuf, dinv0, N0, 2);
  matvec2_k<<<dim3(N0), dim3(256), 0, stream>>>(adj, -1, N0, Zbuf, Ybuf, dtflag);
  final_k<<<dim3((N0 + 255) / 256), dim3(256), 0, stream>>>(Ybuf, Zbuf, dinv0, u2bf, N0, (float*)d_out);
}

// Round 7
// 1034.588 us; speedup vs baseline: 1.1253x; 1.1253x over previous
//
#include <hip/hip_runtime.h>

typedef unsigned short u16;
typedef unsigned int u32;
typedef unsigned long long u64;
typedef signed char s8;
typedef __attribute__((ext_vector_type(8))) short bfrag8;
typedef __attribute__((ext_vector_type(4))) float f32x4;
typedef __attribute__((ext_vector_type(4))) int i32x4;
typedef __attribute__((address_space(1))) const void gconst_void;
typedef __attribute__((address_space(3))) void lds_void_t;

// ---------- helpers ----------
__device__ __forceinline__ float bf2f(u16 u) {
  return __uint_as_float(((u32)u) << 16);
}
__device__ __forceinline__ u16 f2bf(float f) {
  u32 u = __float_as_uint(f);
  u32 r = (u + 0x7FFFu + ((u >> 16) & 1u)) >> 16;  // RTNE
  return (u16)r;
}
__device__ __forceinline__ float ld1(const void* p, int isbf, long idx) {
  return isbf ? bf2f(((const u16*)p)[idx]) : ((const float*)p)[idx];
}
__device__ __forceinline__ void ld4(const void* p, int isbf, long base, long gc, long bound, float v[4]) {
  if (gc + 3 < bound && ((base & 3) == 0)) {
    if (isbf) {
      const ushort4 u = *(const ushort4*)((const u16*)p + base);
      v[0] = bf2f(u.x); v[1] = bf2f(u.y); v[2] = bf2f(u.z); v[3] = bf2f(u.w);
    } else {
      const float4 f = *(const float4*)((const float*)p + base);
      v[0] = f.x; v[1] = f.y; v[2] = f.z; v[3] = f.w;
    }
  } else {
    #pragma unroll
    for (int d = 0; d < 4; ++d) v[d] = (gc + d < bound) ? ld1(p, isbf, base + d) : 0.f;
  }
}

// ---------- input dtype autodetect (bf16 vs f32) ----------
__global__ void detect_init_k(int* flag) { if (threadIdx.x == 0 && blockIdx.x == 0) *flag = 0; }

__global__ void detect_k(const u32* __restrict__ a, long nw, int* __restrict__ flag) {
  long stride = (long)gridDim.x * 256;
  int f = 0;
  for (long j = (long)blockIdx.x * 256 + threadIdx.x; j < nw; j += stride) {
    u32 w = a[j];
    if (w == 0x00003F80u || w == 0x3F803F80u) f = 1;
  }
  if (__any(f)) {
    if ((threadIdx.x & 63) == 0) atomicOr(flag, 1);
  }
}

__device__ __forceinline__ int get_bf(int abf, const int* dtf) {
  return (abf >= 0) ? abf : *dtf;
}

// ---------- async global->LDS stage: 16B per lane ----------
__device__ __forceinline__ void stageB16(const void* g, void* lds) {
#if __has_builtin(__builtin_amdgcn_global_load_lds)
  __builtin_amdgcn_global_load_lds((gconst_void*)g, (lds_void_t*)lds, 16, 0, 0);
#else
  int lane = threadIdx.x & 63;
  *(int4*)((char*)lds + lane * 16) = *(const int4*)g;
#endif
}

// ---------- i8 triangle MFMA SYRK: C = Ag @ Ag^T, zero diag, mirror-write ----------
// Ag entries integers in [0,127]; i32 accumulation exact; grid = nt(nt+1)/2
__global__ __launch_bounds__(256) void syrk_tri_i8(
    const s8* __restrict__ Ag, int ldk, float* __restrict__ C, int ldc, int K)
{
  __shared__ s8 At[128 * 64];
  __shared__ s8 Bt[128 * 64];
  __shared__ int tb[4][16][17];
  const int t = blockIdx.x;
  int ti = (int)((sqrtf((float)(8 * t + 1)) - 1.0f) * 0.5f);
  while ((ti + 1) * (ti + 2) / 2 <= t) ++ti;
  while (ti * (ti + 1) / 2 > t) --ti;
  const int tj = t - ti * (ti + 1) / 2;

  const int tid = threadIdx.x;
  const int wave = tid >> 6, lane = tid & 63;
  const int wr = wave >> 1, wc = wave & 1;
  const long rowA0 = (long)ti * 128;
  const long rowB0 = (long)tj * 128;

  i32x4 acc[4][4];
  #pragma unroll
  for (int i = 0; i < 4; ++i)
    #pragma unroll
    for (int j = 0; j < 4; ++j) acc[i][j] = (i32x4)0;

  const int srow = lane >> 2;          // 0..15
  const int scol = (lane & 3) * 16;    // byte col in 64-wide k-tile
  const int m = lane & 15, q = lane >> 4;

  for (int k0 = 0; k0 < K; k0 += 64) {
    #pragma unroll
    for (int tt = 0; tt < 2; ++tt) {
      const int r = wave * 32 + tt * 16;
      stageB16(Ag + (rowA0 + r + srow) * (long)ldk + k0 + scol, At + r * 64);
      stageB16(Ag + (rowB0 + r + srow) * (long)ldk + k0 + scol, Bt + r * 64);
    }
    __syncthreads();

    i32x4 af[4], bf[4];
    #pragma unroll
    for (int mt = 0; mt < 4; ++mt)
      af[mt] = *(const i32x4*)(At + (wr * 64 + mt * 16 + m) * 64 + q * 16);
    #pragma unroll
    for (int nt = 0; nt < 4; ++nt)
      bf[nt] = *(const i32x4*)(Bt + (wc * 64 + nt * 16 + m) * 64 + q * 16);
    #pragma unroll
    for (int mt = 0; mt < 4; ++mt)
      #pragma unroll
      for (int nt = 0; nt < 4; ++nt)
        acc[mt][nt] = __builtin_amdgcn_mfma_i32_16x16x64_i8(af[mt], bf[nt], acc[mt][nt], 0, 0, 0);
    __syncthreads();
  }

  // lower-triangle tile write, diag zero (C/D layout: col=lane&15, row=q*4+r)
  #pragma unroll
  for (int mt = 0; mt < 4; ++mt) {
    #pragma unroll
    for (int nt = 0; nt < 4; ++nt) {
      const long gr0 = rowA0 + wr * 64 + mt * 16 + q * 4;
      const long gc = rowB0 + wc * 64 + nt * 16 + m;
      #pragma unroll
      for (int r = 0; r < 4; ++r) {
        const long gr = gr0 + r;
        C[gr * ldc + gc] = (gr == gc) ? 0.f : (float)acc[mt][nt][r];
      }
    }
  }
  // mirror write via in-LDS 16x16 fragment transpose
  if (ti != tj) {
    #pragma unroll
    for (int mt = 0; mt < 4; ++mt) {
      #pragma unroll
      for (int nt = 0; nt < 4; ++nt) {
        #pragma unroll
        for (int r = 0; r < 4; ++r) tb[wave][q * 4 + r][m] = acc[mt][nt][r];
        const long baseR = rowB0 + wc * 64 + nt * 16;
        const long baseC = rowA0 + wr * 64 + mt * 16;
        #pragma unroll
        for (int r = 0; r < 4; ++r)
          C[(baseR + q * 4 + r) * ldc + baseC + m] = (float)tb[wave][m][q * 4 + r];
      }
    }
  }
}

// ---------- bf16 2-plane triangle SYRK, deterministic K-split into parts (L3) ----------
// parts[z] lower tiles of (Ah+Al)(Ah+Al)^T over k-chunk z. grid = (nt(nt+1)/2, z)
__global__ __launch_bounds__(256) void syrk_tri2_parts(
    const u16* __restrict__ Ah, const u16* __restrict__ Al, int ldk,
    float* __restrict__ parts, int n, int per)
{
  __shared__ u16 Ath[128 * 32];
  __shared__ u16 Bth[128 * 32];
  __shared__ u16 Atl[128 * 32];
  __shared__ u16 Btl[128 * 32];
  const int t = blockIdx.x;
  int ti = (int)((sqrtf((float)(8 * t + 1)) - 1.0f) * 0.5f);
  while ((ti + 1) * (ti + 2) / 2 <= t) ++ti;
  while (ti * (ti + 1) / 2 > t) --ti;
  const int tj = t - ti * (ti + 1) / 2;

  const int tid = threadIdx.x;
  const int wave = tid >> 6, lane = tid & 63;
  const int wr = wave >> 1, wc = wave & 1;
  const long rowA0 = (long)ti * 128;
  const long rowB0 = (long)tj * 128;
  const int kbeg = blockIdx.y * per;
  const int kend = kbeg + per;

  f32x4 acc[4][4];
  #pragma unroll
  for (int i = 0; i < 4; ++i)
    #pragma unroll
    for (int j = 0; j < 4; ++j) acc[i][j] = (f32x4)0.f;

  const int srow = lane >> 2;
  const int scol = (lane & 3) * 8;
  const int m = lane & 15, q = lane >> 4;

  for (int k0 = kbeg; k0 < kend; k0 += 32) {
    #pragma unroll
    for (int tt = 0; tt < 2; ++tt) {
      const int r = wave * 32 + tt * 16;
      stageB16(Ah + (rowA0 + r + srow) * (long)ldk + k0 + scol, Ath + r * 32);
      stageB16(Ah + (rowB0 + r + srow) * (long)ldk + k0 + scol, Bth + r * 32);
      stageB16(Al + (rowA0 + r + srow) * (long)ldk + k0 + scol, Atl + r * 32);
      stageB16(Al + (rowB0 + r + srow) * (long)ldk + k0 + scol, Btl + r * 32);
    }
    __syncthreads();

    bfrag8 afh[4], afl[4], bfh[4], bfl[4];
    #pragma unroll
    for (int mt = 0; mt < 4; ++mt) {
      afh[mt] = *(const bfrag8*)(Ath + (wr * 64 + mt * 16 + m) * 32 + q * 8);
      afl[mt] = *(const bfrag8*)(Atl + (wr * 64 + mt * 16 + m) * 32 + q * 8);
    }
    #pragma unroll
    for (int nt = 0; nt < 4; ++nt) {
      bfh[nt] = *(const bfrag8*)(Bth + (wc * 64 + nt * 16 + m) * 32 + q * 8);
      bfl[nt] = *(const bfrag8*)(Btl + (wc * 64 + nt * 16 + m) * 32 + q * 8);
    }
    #pragma unroll
    for (int mt = 0; mt < 4; ++mt)
      #pragma unroll
      for (int nt = 0; nt < 4; ++nt) {
        acc[mt][nt] = __builtin_amdgcn_mfma_f32_16x16x32_bf16(afh[mt], bfh[nt], acc[mt][nt], 0, 0, 0);
        acc[mt][nt] = __builtin_amdgcn_mfma_f32_16x16x32_bf16(afh[mt], bfl[nt], acc[mt][nt], 0, 0, 0);
        acc[mt][nt] = __builtin_amdgcn_mfma_f32_16x16x32_bf16(afl[mt], bfh[nt], acc[mt][nt], 0, 0, 0);
        acc[mt][nt] = __builtin_amdgcn_mfma_f32_16x16x32_bf16(afl[mt], bfl[nt], acc[mt][nt], 0, 0, 0);
      }
    __syncthreads();
  }

  float* P = parts + (long)blockIdx.y * n * n;
  #pragma unroll
  for (int mt = 0; mt < 4; ++mt) {
    #pragma unroll
    for (int nt = 0; nt < 4; ++nt) {
      const long gr0 = rowA0 + wr * 64 + mt * 16 + q * 4;
      const long gc = rowB0 + wc * 64 + nt * 16 + m;
      #pragma unroll
      for (int r = 0; r < 4; ++r)
        P[(gr0 + r) * n + gc] = acc[mt][nt][r];
    }
  }
}

// sum nz parts (lower triangle valid), mirror to full matrix, zero diag
__global__ void reduce_tri_mirror_k(const float* __restrict__ parts, float* __restrict__ C,
                                    int n, int nz) {
  long idx = (long)blockIdx.x * 256 + threadIdx.x;
  long nn = (long)n * n;
  if (idx >= nn) return;
  long r = idx / n, c = idx - r * n;
  if (r < c) return;
  if (r == c) { C[idx] = 0.f; return; }
  float s = 0.f;
  for (int z = 0; z < nz; ++z) s += parts[(long)z * nn + r * n + c];
  C[r * n + c] = s;
  C[c * n + r] = s;
}

// build i8 augment operand: Ag[r][c] = src[perm_r, c] + (c==perm_r)   (values <= 127)
__global__ void build_ag_i8_k(const void* __restrict__ src, int srcbf, int nsrc,
                              const int* __restrict__ perm, long tot,
                              s8* __restrict__ Ag, const int* __restrict__ dtf) {
  long idx = (long)blockIdx.x * 256 + threadIdx.x;
  if (idx >= tot) return;
  int r = (int)(idx / nsrc);
  int c = (int)(idx - (long)r * nsrc);
  int p = perm[r];
  float v = ld1(src, get_bf(srcbf, dtf), (long)p * nsrc + c);
  if (c == p) v += 1.f;
  Ag[idx] = (s8)(int)v;
}

// build level-2 augment operand in exact 2-plane bf16
__global__ void build_ag3_split_k(const float* __restrict__ src, int nsrc,
                                  const int* __restrict__ perm, long tot, int ld,
                                  u16* __restrict__ Agh, u16* __restrict__ Agl) {
  long idx = (long)blockIdx.x * 256 + threadIdx.x;
  if (idx >= tot) return;
  int r = (int)(idx / ld);
  int c = (int)(idx - (long)r * ld);
  int p = perm[r];
  float v = src[(long)p * nsrc + c];
  if (c == p) v += 1.f;
  u16 h = f2bf(v);
  Agh[idx] = h;
  Agl[idx] = f2bf(v - bf2f(h));
}

// ---------- MFMA aggregation: Y = A @ Z (A exact bf16 planes, Z 3-plane split) ----------
template<int NT>
__global__ __launch_bounds__(256) void agg_mfma(
    const u16* __restrict__ Ah, const u16* __restrict__ Al,
    const u16* __restrict__ ZT, float* __restrict__ parts,
    int K, int per_steps)
{
  __shared__ u16 At[128 * 32];
  __shared__ u16 Alt[128 * 32];
  __shared__ u16 Zt[3 * NT * 512];
  const int tid = threadIdx.x;
  const int wave = tid >> 6, lane = tid & 63;
  const long row0 = (long)blockIdx.x * 128;
  const int chunk = blockIdx.y;
  const int kbeg = chunk * per_steps * 32;
  const int kend = min(K, kbeg + per_steps * 32);
  const int m = lane & 15, q = lane >> 4;
  const int srow = lane >> 2, scol = (lane & 3) * 8;
  const bool hasAl = (Al != nullptr);

  f32x4 acc[2][NT];
  #pragma unroll
  for (int rt = 0; rt < 2; ++rt)
    #pragma unroll
    for (int ct = 0; ct < NT; ++ct) acc[rt][ct] = (f32x4)0.f;

  for (int k0 = kbeg; k0 < kend; k0 += 32) {
    #pragma unroll
    for (int t = 0; t < 2; ++t) {
      const int r = wave * 32 + t * 16;
      stageB16(Ah + (row0 + r + srow) * (long)K + k0 + scol, At + r * 32);
      if (hasAl)
        stageB16(Al + (row0 + r + srow) * (long)K + k0 + scol, Alt + r * 32);
    }
    for (int s = wave; s < 3 * NT; s += 4) {
      const u16* g = ZT + ((long)(s * 16 + srow)) * K + k0 + scol;
      stageB16(g, Zt + s * 512);
    }
    __syncthreads();

    bfrag8 af0 = *(const bfrag8*)(At + (wave * 32 + m) * 32 + q * 8);
    bfrag8 af1 = *(const bfrag8*)(At + (wave * 32 + 16 + m) * 32 + q * 8);
    bfrag8 al0, al1;
    if (hasAl) {
      al0 = *(const bfrag8*)(Alt + (wave * 32 + m) * 32 + q * 8);
      al1 = *(const bfrag8*)(Alt + (wave * 32 + 16 + m) * 32 + q * 8);
    }
    #pragma unroll
    for (int ct = 0; ct < NT; ++ct) {
      bfrag8 b0 = *(const bfrag8*)(Zt + (0 * NT + ct) * 512 + m * 32 + q * 8);
      bfrag8 b1 = *(const bfrag8*)(Zt + (1 * NT + ct) * 512 + m * 32 + q * 8);
      bfrag8 b2 = *(const bfrag8*)(Zt + (2 * NT + ct) * 512 + m * 32 + q * 8);
      acc[0][ct] = __builtin_amdgcn_mfma_f32_16x16x32_bf16(af0, b0, acc[0][ct], 0, 0, 0);
      acc[0][ct] = __builtin_amdgcn_mfma_f32_16x16x32_bf16(af0, b1, acc[0][ct], 0, 0, 0);
      acc[0][ct] = __builtin_amdgcn_mfma_f32_16x16x32_bf16(af0, b2, acc[0][ct], 0, 0, 0);
      acc[1][ct] = __builtin_amdgcn_mfma_f32_16x16x32_bf16(af1, b0, acc[1][ct], 0, 0, 0);
      acc[1][ct] = __builtin_amdgcn_mfma_f32_16x16x32_bf16(af1, b1, acc[1][ct], 0, 0, 0);
      acc[1][ct] = __builtin_amdgcn_mfma_f32_16x16x32_bf16(af1, b2, acc[1][ct], 0, 0, 0);
      if (hasAl) {
        acc[0][ct] = __builtin_amdgcn_mfma_f32_16x16x32_bf16(al0, b0, acc[0][ct], 0, 0, 0);
        acc[0][ct] = __builtin_amdgcn_mfma_f32_16x16x32_bf16(al0, b1, acc[0][ct], 0, 0, 0);
        acc[1][ct] = __builtin_amdgcn_mfma_f32_16x16x32_bf16(al1, b0, acc[1][ct], 0, 0, 0);
        acc[1][ct] = __builtin_amdgcn_mfma_f32_16x16x32_bf16(al1, b1, acc[1][ct], 0, 0, 0);
      }
    }
    __syncthreads();
  }

  float* P = parts + (long)chunk * gridDim.x * 128 * (NT * 16);
  #pragma unroll
  for (int rt = 0; rt < 2; ++rt) {
    #pragma unroll
    for (int ct = 0; ct < NT; ++ct) {
      const long grow0 = row0 + wave * 32 + rt * 16 + q * 4;
      const long gcol = ct * 16 + m;
      #pragma unroll
      for (int r = 0; r < 4; ++r)
        P[(grow0 + r) * (NT * 16) + gcol] = acc[rt][ct][r];
    }
  }
}

__global__ void reduce_k(const float* __restrict__ parts, float* __restrict__ Y,
                         long n208, int nz) {
  long idx = (long)blockIdx.x * 256 + threadIdx.x;
  if (idx >= n208) return;
  float s = 0.f;
  for (int c = 0; c < nz; ++c) s += parts[(long)c * n208 + idx];
  Y[idx] = s;
}

// Z (n x 200 f32) -> 3 bf16 planes transposed: ZT[(p*208+c)*n + k]
__global__ void zsplit_k(const float* __restrict__ Z, int n, int h, u16* __restrict__ ZT) {
  __shared__ float t[32][33];
  const int kb = blockIdx.x * 32;
  const int cb = blockIdx.y * 32;
  #pragma unroll
  for (int i = 0; i < 32; i += 8) {
    int k = kb + threadIdx.y + i;
    int c = cb + threadIdx.x;
    t[threadIdx.y + i][threadIdx.x] = (c < h) ? Z[(long)k * h + c] : 0.f;
  }
  __syncthreads();
  #pragma unroll
  for (int i = 0; i < 32; i += 8) {
    int c = cb + threadIdx.y + i;
    if (c >= 208) continue;
    long k = kb + threadIdx.x;
    float v = t[threadIdx.x][threadIdx.y + i];
    u16 hi = f2bf(v); float r1 = v - bf2f(hi);
    u16 mi = f2bf(r1); float r2 = r1 - bf2f(mi);
    u16 lo = f2bf(r2);
    ZT[((long)0 * 208 + c) * n + k] = hi;
    ZT[((long)1 * 208 + c) * n + k] = mi;
    ZT[((long)2 * 208 + c) * n + k] = lo;
  }
}

// split fp32 A into exact bf16 hi/lo planes (Al nullable)
__global__ void asplit_k(const float* __restrict__ src, long tot,
                         u16* __restrict__ Ah, u16* __restrict__ Al) {
  long idx = (long)blockIdx.x * 256 + threadIdx.x;
  if (idx >= tot) return;
  float v = src[idx];
  u16 h = f2bf(v);
  Ah[idx] = h;
  if (Al) Al[idx] = f2bf(v - bf2f(h));
}

__global__ void a_from_adj_k(const void* __restrict__ adj, const int* __restrict__ dtf,
                             long tot, u16* __restrict__ Ah) {
  int bf = *dtf;
  long idx = (long)blockIdx.x * 256 + threadIdx.x;
  if (idx >= tot) return;
  Ah[idx] = bf ? ((const u16*)adj)[idx] : f2bf(((const float*)adj)[idx]);
}

// ---------- fp64-accumulating GEMM, 64x64 tile (x@W), fused row-scale epilogue ----------
__global__ __launch_bounds__(256) void gemm64_f64(
    const void* __restrict__ Ap, long lda, int abf,
    const void* __restrict__ Bp, long ldb, int bbf,
    float* __restrict__ C, long ldc, int M, int N, int K,
    const float* __restrict__ dscale, const int* __restrict__ dtf)
{
  const int abf_ = get_bf(abf, dtf);
  const int bbf_ = get_bf(bbf, dtf);
  __shared__ float As[16][64];
  __shared__ float Bs[16][64];
  const int tid = threadIdx.x;
  const int tr = tid >> 4, tc = tid & 15;
  const long row0 = (long)blockIdx.y * 64;
  const long col0 = (long)blockIdx.x * 64;
  double acc[4][4];
  #pragma unroll
  for (int i = 0; i < 4; ++i)
    #pragma unroll
    for (int j = 0; j < 4; ++j) acc[i][j] = 0.0;

  const int am = tid >> 2;
  const int ak = (tid & 3) * 4;
  const int bk = tid >> 4;
  const int bn = (tid & 15) * 4;

  for (int k0 = 0; k0 < K; k0 += 16) {
    float va[4] = {0.f, 0.f, 0.f, 0.f};
    {
      long gm = row0 + am; long gk = k0 + ak;
      if (gm < M && gk < K) ld4(Ap, abf_, gm * lda + gk, gk, K, va);
    }
    As[ak + 0][am] = va[0]; As[ak + 1][am] = va[1];
    As[ak + 2][am] = va[2]; As[ak + 3][am] = va[3];

    float vb[4] = {0.f, 0.f, 0.f, 0.f};
    {
      long gk = k0 + bk; long gn = col0 + bn;
      if (gk < K && gn < N) ld4(Bp, bbf_, gk * ldb + gn, gn, N, vb);
    }
    Bs[bk][bn + 0] = vb[0]; Bs[bk][bn + 1] = vb[1];
    Bs[bk][bn + 2] = vb[2]; Bs[bk][bn + 3] = vb[3];

    __syncthreads();
    #pragma unroll
    for (int kk = 0; kk < 16; ++kk) {
      float a[4], b[4];
      #pragma unroll
      for (int i = 0; i < 4; ++i) a[i] = As[kk][tr * 4 + i];
      #pragma unroll
      for (int j = 0; j < 4; ++j) b[j] = Bs[kk][tc * 4 + j];
      #pragma unroll
      for (int i = 0; i < 4; ++i)
        #pragma unroll
        for (int j = 0; j < 4; ++j)
          acc[i][j] += (double)a[i] * (double)b[j];
    }
    __syncthreads();
  }
  #pragma unroll
  for (int i = 0; i < 4; ++i) {
    long gm = row0 + tr * 4 + i;
    if (gm >= M) continue;
    float sc = dscale ? dscale[gm] : 1.f;
    #pragma unroll
    for (int j = 0; j < 4; ++j) {
      long gn = col0 + tc * 4 + j;
      if (gn < N) {
        float v = (float)acc[i][j];  // f64 -> f32 first (bit-identical to old path)
        C[gm * ldc + gn] = v * sc;
      }
    }
  }
}

// ---------- small kernels ----------
struct UpBatch {
  const void* src[19];
  float* dst[19];
  int n[19];
};

__global__ void upcast_batch_k(UpBatch ub, const int* __restrict__ dtf) {
  int bf = *dtf;
  int a = blockIdx.y;
  int i = blockIdx.x * 256 + threadIdx.x;
  if (i < ub.n[a]) ub.dst[a][i] = ld1(ub.src[a], bf, i);
}

__global__ void rowsum_dinv_k(const void* __restrict__ A, int abf, int n, float* __restrict__ dinv,
                              const int* __restrict__ dtf) {
  const int bf = get_bf(abf, dtf);
  const int row = blockIdx.x;
  const int tid = threadIdx.x;
  const long base = (long)row * n;
  double s = 0.0;
  for (int j = tid; j < n; j += 256) s += (double)ld1(A, bf, base + j);
  __shared__ double red[256];
  red[tid] = s; __syncthreads();
  for (int st = 128; st > 0; st >>= 1) {
    if (tid < st) red[tid] += red[tid + st];
    __syncthreads();
  }
  if (tid == 0) dinv[row] = (float)(1.0 / sqrt(red[0] + 2.0));
}

// Y has leading dim 208; Zs has leading dim h(=200)
__global__ void gcn_epi_k(const float* __restrict__ Y, const float* __restrict__ Zs,
                          const float* __restrict__ dinv, const float* __restrict__ b,
                          float* __restrict__ out, int n, int h, int relu) {
  long idx = (long)blockIdx.x * 256 + threadIdx.x;
  if (idx >= (long)n * h) return;
  int i = (int)(idx / h);
  int j = (int)(idx - (long)i * h);
  float v = dinv[i] * (Y[(long)i * 208 + j] + 2.f * Zs[idx]) + b[j];
  if (relu) v = fmaxf(v, 0.f);
  out[idx] = v;
}

// fused ||p|| + score (one wave per row; norm recomputed per block, deterministic)
__global__ void score_k(const float* __restrict__ x, int h, const float* __restrict__ pw,
                        float* __restrict__ score) {
  int row = blockIdx.x, lane = threadIdx.x;
  double ps = 0.0;
  for (int j = lane; j < h; j += 64) { double w = pw[j]; ps += w * w; }
  for (int off = 32; off > 0; off >>= 1) ps += __shfl_down(ps, off);
  double nrm = sqrt(__shfl(ps, 0));
  const long base = (long)row * h;
  double s = 0.0;
  for (int j = lane; j < h; j += 64) s += (double)x[base + j] * (double)pw[j];
  for (int off = 32; off > 0; off >>= 1) s += __shfl_down(s, off);
  if (lane == 0) score[row] = (float)tanh(s / nrm);
}

// exact jax.lax.top_k order: descending value, ascending index on ties
__global__ __launch_bounds__(1024) void topk_k(const float* __restrict__ score,
                                               int n, int np2, int k, int* __restrict__ perm) {
  __shared__ u64 keys[4096];
  const int tid = threadIdx.x;
  for (int i = tid; i < np2; i += 1024) {
    u64 key = 0ULL;
    if (i < n) {
      u32 b = __float_as_uint(score[i]);
      u32 u = (b & 0x80000000u) ? ~b : (b | 0x80000000u);
      key = ((u64)u << 32) | (u32)(~(u32)i);
    }
    keys[i] = key;
  }
  __syncthreads();
  for (int size = 2; size <= np2; size <<= 1) {
    for (int stride = size >> 1; stride > 0; stride >>= 1) {
      for (int i = tid; i < np2; i += 1024) {
        int j = i ^ stride;
        if (j > i) {
          u64 a = keys[i], b = keys[j];
          bool up = ((i & size) == 0);
          if (up ? (a > b) : (a < b)) { keys[i] = b; keys[j] = a; }
        }
      }
      __syncthreads();
    }
  }
  for (int r = tid; r < k; r += 1024) {
    u64 kk = keys[np2 - 1 - r];
    perm[r] = (int)(~(u32)(kk & 0xFFFFFFFFull));
  }
}

__global__ void gatherx_k(const float* __restrict__ xsrc, const float* __restrict__ score,
                          const int* __restrict__ perm, int k, int h, float* __restrict__ xdst) {
  long idx = (long)blockIdx.x * 256 + threadIdx.x;
  if (idx >= (long)k * h) return;
  int r = (int)(idx / h);
  int c = (int)(idx - (long)r * h);
  int p = perm[r];
  xdst[idx] = xsrc[(long)p * h + c] * score[p];
}

__global__ void copy_k(const float* __restrict__ src, float* __restrict__ dst, long n) {
  long idx = (long)blockIdx.x * 256 + threadIdx.x;
  if (idx < n) dst[idx] = src[idx];
}

__global__ void scatter_add_k(float* __restrict__ dst, const int* __restrict__ perm,
                              const float* __restrict__ src, int k, int h) {
  long idx = (long)blockIdx.x * 256 + threadIdx.x;
  if (idx >= (long)k * h) return;
  int r = (int)(idx / h);
  int c = (int)(idx - (long)r * h);
  dst[(long)perm[r] * h + c] += src[idx];
}

__global__ void matvec2_k(const void* __restrict__ A, int abf, int n,
                          const float* __restrict__ Zs, float* __restrict__ Y,
                          const int* __restrict__ dtf) {
  const int bf = get_bf(abf, dtf);
  int row = blockIdx.x, tid = threadIdx.x;
  const long base = (long)row * n;
  double s0 = 0.0, s1 = 0.0;
  for (int j = tid; j < n; j += 256) {
    double a = (double)ld1(A, bf, base + j);
    s0 += a * (double)Zs[2 * j];
    s1 += a * (double)Zs[2 * j + 1];
  }
  __shared__ double r0[256], r1[256];
  r0[tid] = s0; r1[tid] = s1; __syncthreads();
  for (int st = 128; st > 0; st >>= 1) {
    if (tid < st) { r0[tid] += r0[tid + st]; r1[tid] += r1[tid + st]; }
    __syncthreads();
  }
  if (tid == 0) { Y[2 * row] = (float)r0[0]; Y[2 * row + 1] = (float)r1[0]; }
}

__global__ void final_k(const float* __restrict__ Y, const float* __restrict__ Zs,
                        const float* __restrict__ dinv, const float* __restrict__ b2,
                        int n, float* __restrict__ out) {
  int i = blockIdx.x * 256 + threadIdx.x;
  if (i >= n) return;
  double di = dinv[i];
  double t0 = di * ((double)Y[2 * i] + 2.0 * (double)Zs[2 * i]) + (double)b2[0];
  double t1 = di * ((double)Y[2 * i + 1] + 2.0 * (double)Zs[2 * i + 1]) + (double)b2[1];
  double m = fmax(t0, t1);
  double l = m + log(exp(t0 - m) + exp(t1 - m));
  out[2 * i] = (float)(t0 - l);
  out[2 * i + 1] = (float)(t1 - l);
}

// ---------- host orchestration ----------
extern "C" void kernel_launch(void* const* d_in, const int* in_sizes, int n_in,
                              void* d_out, int out_size, void* d_ws, size_t ws_size,
                              hipStream_t stream) {
  const int N0 = 4096, H = 200;
  const int K1 = 3072, K2 = 1536, K3 = 768;

  const void* in_x = d_in[0];
  const void* adj  = d_in[1];
  const void* w0 = d_in[2];  const void* b0 = d_in[3];
  const void* w1 = d_in[4];  const void* b1 = d_in[5];
  const void* w2 = d_in[6];  const void* b2 = d_in[7];
  const void* w3 = d_in[8];  const void* b3 = d_in[9];
  const void* p1 = d_in[10]; const void* p2 = d_in[11];
  const void* p3 = d_in[12];
  const void* u0w = d_in[13]; const void* u0b = d_in[14];
  const void* u1w = d_in[15]; const void* u1b = d_in[16];
  const void* u2w = d_in[17]; const void* u2b = d_in[18];

  char* wp = (char*)d_ws;
  auto alloc = [&](size_t bytes) -> void* {
    void* p = (void*)wp;
    wp += (bytes + 255) & ~(size_t)255;
    return p;
  };
  float* As1  = (float*)alloc((size_t)K1 * K1 * 4);          // 37.7 MB
  float* As2  = (float*)alloc((size_t)K2 * K2 * 4);          // 9.4 MB
  float* A3   = (float*)alloc((size_t)K3 * K3 * 4);          // 2.4 MB
  // shared scratch: Agb_i8 (syrk operand) / parts (agg + L3 k-split) — disjoint lifetimes
  size_t scrBytes = (size_t)36864 * 208 * 4 + 1024;          // 30.7 MB
  void* scratchU = alloc(scrBytes);
  s8*    Agb  = (s8*)scratchU;
  float* parts = (float*)scratchU;
  u16* Ag3h = (u16*)alloc((size_t)K3 * K2 * 2);              // 2.4 MB
  u16* Ag3l = (u16*)alloc((size_t)K3 * K2 * 2);              // 2.4 MB
  u16* Ah0 = (u16*)alloc((size_t)N0 * N0 * 2);               // 33.5 MB
  u16* Ah1 = (u16*)alloc((size_t)K1 * K1 * 2);               // 18.9 MB
  u16* Ah2 = (u16*)alloc((size_t)K2 * K2 * 2);               // 4.7 MB
  u16* Al2 = (u16*)alloc((size_t)K2 * K2 * 2);               // 4.7 MB
  u16* Ah3 = (u16*)alloc((size_t)K3 * K3 * 2);               // 1.2 MB
  u16* Al3 = (u16*)alloc((size_t)K3 * K3 * 2);               // 1.2 MB
  u16* ZT  = (u16*)alloc((size_t)3 * 208 * N0 * 2);          // 5.1 MB
  float* xs0  = (float*)alloc((size_t)N0 * H * 4);
  float* xs1  = (float*)alloc((size_t)K1 * H * 4);
  float* xs2  = (float*)alloc((size_t)K2 * H * 4);
  float* xcur = (float*)alloc((size_t)N0 * H * 4);
  float* xtmp = (float*)alloc((size_t)N0 * H * 4);
  float* Zbuf = (float*)alloc((size_t)N0 * H * 4);
  float* Ybuf = (float*)alloc((size_t)N0 * 208 * 4);
  float* Xinf = (float*)alloc((size_t)N0 * 3 * 4);
  float* dinv0 = (float*)alloc((size_t)N0 * 4);
  float* dinv1 = (float*)alloc((size_t)K1 * 4);
  float* dinv2 = (float*)alloc((size_t)K2 * 4);
  float* dinv3 = (float*)alloc((size_t)K3 * 4);
  float* scores = (float*)alloc((size_t)N0 * 4);
  int* perm1 = (int*)alloc((size_t)K1 * 4);
  int* perm2 = (int*)alloc((size_t)K2 * 4);
  int* perm3 = (int*)alloc((size_t)K3 * 4);
  int* dtflag = (int*)alloc(256);
  float* w0f = (float*)alloc(3 * H * 4);  float* b0f = (float*)alloc(H * 4);
  float* w1f = (float*)alloc(H * H * 4);  float* b1f = (float*)alloc(H * 4);
  float* w2f = (float*)alloc(H * H * 4);  float* b2f = (float*)alloc(H * 4);
  float* w3f = (float*)alloc(H * H * 4);  float* b3f = (float*)alloc(H * 4);
  float* p1f = (float*)alloc(H * 4);
  float* p2f = (float*)alloc(H * 4);
  float* p3f = (float*)alloc(H * 4);
  float* u0wf = (float*)alloc(H * H * 4); float* u0bf = (float*)alloc(H * 4);
  float* u1wf = (float*)alloc(H * H * 4); float* u1bf = (float*)alloc(H * 4);
  float* u2wf = (float*)alloc(H * 2 * 4); float* u2bf = (float*)alloc(2 * 4);
  (void)in_sizes; (void)n_in; (void)out_size; (void)ws_size;

  detect_init_k<<<dim3(1), dim3(64), 0, stream>>>(dtflag);
  detect_k<<<dim3(4096), dim3(256), 0, stream>>>((const u32*)adj, (long)N0 * N0 / 2, dtflag);

  // batched upcast of all small params (19 arrays, one launch)
  {
    UpBatch ub;
    const void* srcs[19] = {in_x, w0, b0, w1, b1, w2, b2, w3, b3, p1, p2, p3,
                            u0w, u0b, u1w, u1b, u2w, u2b, u2b};
    float* dsts[19] = {Xinf, w0f, b0f, w1f, b1f, w2f, b2f, w3f, b3f, p1f, p2f, p3f,
                       u0wf, u0bf, u1wf, u1bf, u2wf, u2bf, u2bf};
    int ns[19] = {N0 * 3, 3 * H, H, H * H, H, H * H, H, H * H, H, H, H, H,
                  H * H, H, H * H, H, H * 2, 2, 2};
    for (int i = 0; i < 19; ++i) { ub.src[i] = srcs[i]; ub.dst[i] = dsts[i]; ub.n[i] = ns[i]; }
    upcast_batch_k<<<dim3((N0 * 3 + 255) / 256, 19), dim3(256), 0, stream>>>(ub, dtflag);
  }

  a_from_adj_k<<<dim3((unsigned)(((long)N0 * N0 + 255) / 256)), dim3(256), 0, stream>>>(
      adj, dtflag, (long)N0 * N0, Ah0);

  auto gemm64 = [&](const void* A, long lda, int abf, const void* B, long ldb, int bbf,
                    float* C, long ldc, int M, int Nn, int K, const float* dscale) {
    dim3 g((Nn + 63) / 64, (M + 63) / 64);
    gemm64_f64<<<g, dim3(256), 0, stream>>>(A, lda, abf, B, ldb, bbf, C, ldc, M, Nn, K,
                                            dscale, dtflag);
  };

  // GCN: out = maybe_relu(dinv .* (A@Zs + 2 Zs) + b)
  auto gcn = [&](const u16* Ah, const u16* Al, int n, int chunks, const float* dinv,
                 const float* Xin_, int din, const float* W, const float* bb,
                 float* out, int relu) {
    gemm64(Xin_, din, 0, W, H, 0, Zbuf, H, n, H, din, dinv);  // Z = dinv .* (Xin @ W)
    long tot = (long)n * H;
    zsplit_k<<<dim3(n / 32, 7), dim3(32, 8), 0, stream>>>(Zbuf, n, H, ZT);
    agg_mfma<13><<<dim3(n / 128, chunks), dim3(256), 0, stream>>>(
        Ah, Al, ZT, parts, n, (n / 32) / chunks);
    long n208 = (long)n * 208;
    reduce_k<<<dim3((unsigned)((n208 + 255) / 256)), dim3(256), 0, stream>>>(
        parts, Ybuf, n208, chunks);
    gcn_epi_k<<<dim3((unsigned)((tot + 255) / 256)), dim3(256), 0, stream>>>(
        Ybuf, Zbuf, dinv, bb, out, n, H, relu);
  };

  auto pool = [&](const float* xin, int n, int np2, int k, const float* pwf,
                  int* perm, float* xout) {
    score_k<<<dim3(n), dim3(64), 0, stream>>>(xin, H, pwf, scores);
    topk_k<<<dim3(1), dim3(1024), 0, stream>>>(scores, n, np2, k, perm);
    long tot = (long)k * H;
    gatherx_k<<<dim3((unsigned)((tot + 255) / 256)), dim3(256), 0, stream>>>(
        xin, scores, perm, k, H, xout);
  };

  // ---------------- forward ----------------
  rowsum_dinv_k<<<dim3(N0), dim3(256), 0, stream>>>(adj, -1, N0, dinv0, dtflag);
  gcn(Ah0, nullptr, N0, 8, dinv0, Xinf, 3, w0f, b0f, xs0, 1);

  // down 0: i8 SYRK (entries {0,1,2})
  pool(xs0, N0, 4096, K1, p1f, perm1, xcur);
  {
    long tot = (long)K1 * N0;
    build_ag_i8_k<<<dim3((unsigned)((tot + 255) / 256)), dim3(256), 0, stream>>>(
        adj, -1, N0, perm1, tot, Agb, dtflag);
    int nt = K1 / 128;
    syrk_tri_i8<<<dim3(nt * (nt + 1) / 2), dim3(256), 0, stream>>>(Agb, N0, As1, K1, N0);
  }
  asplit_k<<<dim3((unsigned)(((long)K1 * K1 + 255) / 256)), dim3(256), 0, stream>>>(
      As1, (long)K1 * K1, Ah1, nullptr);
  rowsum_dinv_k<<<dim3(K1), dim3(256), 0, stream>>>(As1, 0, K1, dinv1, dtflag);
  gcn(Ah1, nullptr, K1, 12, dinv1, xcur, H, w1f, b1f, xs1, 1);

  // down 1: i8 SYRK (entries <= ~71)
  pool(xs1, K1, 4096, K2, p2f, perm2, xcur);
  {
    long tot = (long)K2 * K1;
    build_ag_i8_k<<<dim3((unsigned)((tot + 255) / 256)), dim3(256), 0, stream>>>(
        As1, 0, K1, perm2, tot, Agb, dtflag);
    int nt = K2 / 128;
    syrk_tri_i8<<<dim3(nt * (nt + 1) / 2), dim3(256), 0, stream>>>(Agb, K1, As2, K2, K1);
  }
  asplit_k<<<dim3((unsigned)(((long)K2 * K2 + 255) / 256)), dim3(256), 0, stream>>>(
      As2, (long)K2 * K2, Ah2, Al2);
  rowsum_dinv_k<<<dim3(K2), dim3(256), 0, stream>>>(As2, 0, K2, dinv2, dtflag);
  gcn(Ah2, Al2, K2, 24, dinv2, xcur, H, w2f, b2f, xs2, 1);

  // down 2: bf16 2-plane deterministic K-split triangle (values may exceed 127)
  pool(xs2, K2, 2048, K3, p3f, perm3, xcur);
  {
    long tot = (long)K3 * K2;
    build_ag3_split_k<<<dim3((unsigned)((tot + 255) / 256)), dim3(256), 0, stream>>>(
        As2, K2, perm3, tot, K2, Ag3h, Ag3l);
    int nt = K3 / 128;
    syrk_tri2_parts<<<dim3(nt * (nt + 1) / 2, 8), dim3(256), 0, stream>>>(
        Ag3h, Ag3l, K2, parts, K3, K2 / 8);
    long nn = (long)K3 * K3;
    reduce_tri_mirror_k<<<dim3((unsigned)((nn + 255) / 256)), dim3(256), 0, stream>>>(
        parts, A3, K3, 8);
  }
  asplit_k<<<dim3((unsigned)(((long)K3 * K3 + 255) / 256)), dim3(256), 0, stream>>>(
      A3, (long)K3 * K3, Ah3, Al3);
  rowsum_dinv_k<<<dim3(K3), dim3(256), 0, stream>>>(A3, 0, K3, dinv3, dtflag);
  gcn(Ah3, Al3, K3, 24, dinv3, xcur, H, w3f, b3f, xcur, 1);

  // up 0: j=2
  copy_k<<<dim3((unsigned)(((long)K2 * H + 255) / 256)), dim3(256), 0, stream>>>(xs2, xtmp, (long)K2 * H);
  scatter_add_k<<<dim3((unsigned)(((long)K3 * H + 255) / 256)), dim3(256), 0, stream>>>(xtmp, perm3, xcur, K3, H);
  gcn(Ah2, Al2, K2, 24, dinv2, xtmp, H, u0wf, u0bf, xcur, 1);

  // up 1: j=1
  copy_k<<<dim3((unsigned)(((long)K1 * H + 255) / 256)), dim3(256), 0, stream>>>(xs1, xtmp, (long)K1 * H);
  scatter_add_k<<<dim3((unsigned)(((long)K2 * H + 255) / 256)), dim3(256), 0, stream>>>(xtmp, perm2, xcur, K2, H);
  gcn(Ah1, nullptr, K1, 12, dinv1, xtmp, H, u1wf, u1bf, xcur, 1);

  // up 2: j=0
  copy_k<<<dim3((unsigned)(((long)N0 * H + 255) / 256)), dim3(256), 0, stream>>>(xs0, xtmp, (long)N0 * H);
  scatter_add_k<<<dim3((unsigned)(((long)K1 * H + 255) / 256)), dim3(256), 0, stream>>>(xtmp, perm1, xcur, K1, H);
  gemm64(xtmp, H, 0, u2wf, 2, 0, Zbuf, 2, N0, 2, H, dinv0);   // Z2 = dinv0 .* (x @ u2w)
  matvec2_k<<<dim3(N0), dim3(256), 0, stream>>>(adj, -1, N0, Zbuf, Ybuf, dtflag);
  final_k<<<dim3((N0 + 255) / 256), dim3(256), 0, stream>>>(Ybuf, Zbuf, dinv0, u2bf, N0, (float*)d_out);
}

// Round 8
// 973.517 us; speedup vs baseline: 1.1959x; 1.0627x over previous
//
#include <hip/hip_runtime.h>

typedef unsigned short u16;
typedef unsigned int u32;
typedef unsigned long long u64;
typedef signed char s8;
typedef __attribute__((ext_vector_type(8))) short bfrag8;
typedef __attribute__((ext_vector_type(4))) float f32x4;
typedef __attribute__((ext_vector_type(4))) int i32x4;
typedef __attribute__((address_space(1))) const void gconst_void;
typedef __attribute__((address_space(3))) void lds_void_t;

// ---------- helpers ----------
__device__ __forceinline__ float bf2f(u16 u) {
  return __uint_as_float(((u32)u) << 16);
}
__device__ __forceinline__ u16 f2bf(float f) {
  u32 u = __float_as_uint(f);
  u32 r = (u + 0x7FFFu + ((u >> 16) & 1u)) >> 16;  // RTNE
  return (u16)r;
}
__device__ __forceinline__ float ld1(const void* p, int isbf, long idx) {
  return isbf ? bf2f(((const u16*)p)[idx]) : ((const float*)p)[idx];
}
__device__ __forceinline__ void ld4(const void* p, int isbf, long base, long gc, long bound, float v[4]) {
  if (gc + 3 < bound && ((base & 3) == 0)) {
    if (isbf) {
      const ushort4 u = *(const ushort4*)((const u16*)p + base);
      v[0] = bf2f(u.x); v[1] = bf2f(u.y); v[2] = bf2f(u.z); v[3] = bf2f(u.w);
    } else {
      const float4 f = *(const float4*)((const float*)p + base);
      v[0] = f.x; v[1] = f.y; v[2] = f.z; v[3] = f.w;
    }
  } else {
    #pragma unroll
    for (int d = 0; d < 4; ++d) v[d] = (gc + d < bound) ? ld1(p, isbf, base + d) : 0.f;
  }
}

// ---------- input dtype autodetect (bf16 vs f32) ----------
__global__ void detect_init_k(int* flag) { if (threadIdx.x == 0 && blockIdx.x == 0) *flag = 0; }

__global__ void detect_k(const u32* __restrict__ a, long nw, int* __restrict__ flag) {
  long stride = (long)gridDim.x * 256;
  int f = 0;
  for (long j = (long)blockIdx.x * 256 + threadIdx.x; j < nw; j += stride) {
    u32 w = a[j];
    if (w == 0x00003F80u || w == 0x3F803F80u) f = 1;
  }
  if (__any(f)) {
    if ((threadIdx.x & 63) == 0) atomicOr(flag, 1);
  }
}

__device__ __forceinline__ int get_bf(int abf, const int* dtf) {
  return (abf >= 0) ? abf : *dtf;
}

// ---------- async global->LDS stage: 16B per lane ----------
__device__ __forceinline__ void stageB16(const void* g, void* lds) {
#if __has_builtin(__builtin_amdgcn_global_load_lds)
  __builtin_amdgcn_global_load_lds((gconst_void*)g, (lds_void_t*)lds, 16, 0, 0);
#else
  int lane = threadIdx.x & 63;
  *(int4*)((char*)lds + lane * 16) = *(const int4*)g;
#endif
}

// ---------- i8 triangle MFMA SYRK: C = Ag @ Ag^T, zero diag, mirror-write ----------
// Ag entries integers in [0,127]; i32 accumulation exact; grid = nt(nt+1)/2
__global__ __launch_bounds__(256) void syrk_tri_i8(
    const s8* __restrict__ Ag, int ldk, float* __restrict__ C, int ldc, int K)
{
  __shared__ s8 At[128 * 64];
  __shared__ s8 Bt[128 * 64];
  __shared__ int tb[4][16][17];
  const int t = blockIdx.x;
  int ti = (int)((sqrtf((float)(8 * t + 1)) - 1.0f) * 0.5f);
  while ((ti + 1) * (ti + 2) / 2 <= t) ++ti;
  while (ti * (ti + 1) / 2 > t) --ti;
  const int tj = t - ti * (ti + 1) / 2;

  const int tid = threadIdx.x;
  const int wave = tid >> 6, lane = tid & 63;
  const int wr = wave >> 1, wc = wave & 1;
  const long rowA0 = (long)ti * 128;
  const long rowB0 = (long)tj * 128;

  i32x4 acc[4][4];
  #pragma unroll
  for (int i = 0; i < 4; ++i)
    #pragma unroll
    for (int j = 0; j < 4; ++j) acc[i][j] = (i32x4)0;

  const int srow = lane >> 2;          // 0..15
  const int scol = (lane & 3) * 16;    // byte col in 64-wide k-tile
  const int m = lane & 15, q = lane >> 4;

  for (int k0 = 0; k0 < K; k0 += 64) {
    #pragma unroll
    for (int tt = 0; tt < 2; ++tt) {
      const int r = wave * 32 + tt * 16;
      stageB16(Ag + (rowA0 + r + srow) * (long)ldk + k0 + scol, At + r * 64);
      stageB16(Ag + (rowB0 + r + srow) * (long)ldk + k0 + scol, Bt + r * 64);
    }
    __syncthreads();

    i32x4 af[4], bf[4];
    #pragma unroll
    for (int mt = 0; mt < 4; ++mt)
      af[mt] = *(const i32x4*)(At + (wr * 64 + mt * 16 + m) * 64 + q * 16);
    #pragma unroll
    for (int nt = 0; nt < 4; ++nt)
      bf[nt] = *(const i32x4*)(Bt + (wc * 64 + nt * 16 + m) * 64 + q * 16);
    #pragma unroll
    for (int mt = 0; mt < 4; ++mt)
      #pragma unroll
      for (int nt = 0; nt < 4; ++nt)
        acc[mt][nt] = __builtin_amdgcn_mfma_i32_16x16x64_i8(af[mt], bf[nt], acc[mt][nt], 0, 0, 0);
    __syncthreads();
  }

  // lower-triangle tile write, diag zero (C/D layout: col=lane&15, row=q*4+r)
  #pragma unroll
  for (int mt = 0; mt < 4; ++mt) {
    #pragma unroll
    for (int nt = 0; nt < 4; ++nt) {
      const long gr0 = rowA0 + wr * 64 + mt * 16 + q * 4;
      const long gc = rowB0 + wc * 64 + nt * 16 + m;
      #pragma unroll
      for (int r = 0; r < 4; ++r) {
        const long gr = gr0 + r;
        C[gr * ldc + gc] = (gr == gc) ? 0.f : (float)acc[mt][nt][r];
      }
    }
  }
  // mirror write via in-LDS 16x16 fragment transpose
  if (ti != tj) {
    #pragma unroll
    for (int mt = 0; mt < 4; ++mt) {
      #pragma unroll
      for (int nt = 0; nt < 4; ++nt) {
        #pragma unroll
        for (int r = 0; r < 4; ++r) tb[wave][q * 4 + r][m] = acc[mt][nt][r];
        const long baseR = rowB0 + wc * 64 + nt * 16;
        const long baseC = rowA0 + wr * 64 + mt * 16;
        #pragma unroll
        for (int r = 0; r < 4; ++r)
          C[(baseR + q * 4 + r) * ldc + baseC + m] = (float)tb[wave][m][q * 4 + r];
      }
    }
  }
}

// ---------- bf16 2-plane triangle SYRK, deterministic K-split into parts (L3) ----------
__global__ __launch_bounds__(256) void syrk_tri2_parts(
    const u16* __restrict__ Ah, const u16* __restrict__ Al, int ldk,
    float* __restrict__ parts, int n, int per)
{
  __shared__ u16 Ath[128 * 32];
  __shared__ u16 Bth[128 * 32];
  __shared__ u16 Atl[128 * 32];
  __shared__ u16 Btl[128 * 32];
  const int t = blockIdx.x;
  int ti = (int)((sqrtf((float)(8 * t + 1)) - 1.0f) * 0.5f);
  while ((ti + 1) * (ti + 2) / 2 <= t) ++ti;
  while (ti * (ti + 1) / 2 > t) --ti;
  const int tj = t - ti * (ti + 1) / 2;

  const int tid = threadIdx.x;
  const int wave = tid >> 6, lane = tid & 63;
  const int wr = wave >> 1, wc = wave & 1;
  const long rowA0 = (long)ti * 128;
  const long rowB0 = (long)tj * 128;
  const int kbeg = blockIdx.y * per;
  const int kend = kbeg + per;

  f32x4 acc[4][4];
  #pragma unroll
  for (int i = 0; i < 4; ++i)
    #pragma unroll
    for (int j = 0; j < 4; ++j) acc[i][j] = (f32x4)0.f;

  const int srow = lane >> 2;
  const int scol = (lane & 3) * 8;
  const int m = lane & 15, q = lane >> 4;

  for (int k0 = kbeg; k0 < kend; k0 += 32) {
    #pragma unroll
    for (int tt = 0; tt < 2; ++tt) {
      const int r = wave * 32 + tt * 16;
      stageB16(Ah + (rowA0 + r + srow) * (long)ldk + k0 + scol, Ath + r * 32);
      stageB16(Ah + (rowB0 + r + srow) * (long)ldk + k0 + scol, Bth + r * 32);
      stageB16(Al + (rowA0 + r + srow) * (long)ldk + k0 + scol, Atl + r * 32);
      stageB16(Al + (rowB0 + r + srow) * (long)ldk + k0 + scol, Btl + r * 32);
    }
    __syncthreads();

    bfrag8 afh[4], afl[4], bfh[4], bfl[4];
    #pragma unroll
    for (int mt = 0; mt < 4; ++mt) {
      afh[mt] = *(const bfrag8*)(Ath + (wr * 64 + mt * 16 + m) * 32 + q * 8);
      afl[mt] = *(const bfrag8*)(Atl + (wr * 64 + mt * 16 + m) * 32 + q * 8);
    }
    #pragma unroll
    for (int nt = 0; nt < 4; ++nt) {
      bfh[nt] = *(const bfrag8*)(Bth + (wc * 64 + nt * 16 + m) * 32 + q * 8);
      bfl[nt] = *(const bfrag8*)(Btl + (wc * 64 + nt * 16 + m) * 32 + q * 8);
    }
    #pragma unroll
    for (int mt = 0; mt < 4; ++mt)
      #pragma unroll
      for (int nt = 0; nt < 4; ++nt) {
        acc[mt][nt] = __builtin_amdgcn_mfma_f32_16x16x32_bf16(afh[mt], bfh[nt], acc[mt][nt], 0, 0, 0);
        acc[mt][nt] = __builtin_amdgcn_mfma_f32_16x16x32_bf16(afh[mt], bfl[nt], acc[mt][nt], 0, 0, 0);
        acc[mt][nt] = __builtin_amdgcn_mfma_f32_16x16x32_bf16(afl[mt], bfh[nt], acc[mt][nt], 0, 0, 0);
        acc[mt][nt] = __builtin_amdgcn_mfma_f32_16x16x32_bf16(afl[mt], bfl[nt], acc[mt][nt], 0, 0, 0);
      }
    __syncthreads();
  }

  float* P = parts + (long)blockIdx.y * n * n;
  #pragma unroll
  for (int mt = 0; mt < 4; ++mt) {
    #pragma unroll
    for (int nt = 0; nt < 4; ++nt) {
      const long gr0 = rowA0 + wr * 64 + mt * 16 + q * 4;
      const long gc = rowB0 + wc * 64 + nt * 16 + m;
      #pragma unroll
      for (int r = 0; r < 4; ++r)
        P[(gr0 + r) * n + gc] = acc[mt][nt][r];
    }
  }
}

// sum nz parts (lower triangle valid), mirror to full matrix, zero diag
__global__ void reduce_tri_mirror_k(const float* __restrict__ parts, float* __restrict__ C,
                                    int n, int nz) {
  long idx = (long)blockIdx.x * 256 + threadIdx.x;
  long nn = (long)n * n;
  if (idx >= nn) return;
  long r = idx / n, c = idx - r * n;
  if (r < c) return;
  if (r == c) { C[idx] = 0.f; return; }
  float s = 0.f;
  for (int z = 0; z < nz; ++z) s += parts[(long)z * nn + r * n + c];
  C[r * n + c] = s;
  C[c * n + r] = s;
}

// build i8 augment operand: Ag[r][c] = src[perm_r, c] + (c==perm_r)   (values <= 127)
__global__ void build_ag_i8_k(const void* __restrict__ src, int srcbf, int nsrc,
                              const int* __restrict__ perm, long tot,
                              s8* __restrict__ Ag, const int* __restrict__ dtf) {
  long idx = (long)blockIdx.x * 256 + threadIdx.x;
  if (idx >= tot) return;
  int r = (int)(idx / nsrc);
  int c = (int)(idx - (long)r * nsrc);
  int p = perm[r];
  float v = ld1(src, get_bf(srcbf, dtf), (long)p * nsrc + c);
  if (c == p) v += 1.f;
  Ag[idx] = (s8)(int)v;
}

// build level-2 augment operand in exact 2-plane bf16
__global__ void build_ag3_split_k(const float* __restrict__ src, int nsrc,
                                  const int* __restrict__ perm, long tot, int ld,
                                  u16* __restrict__ Agh, u16* __restrict__ Agl) {
  long idx = (long)blockIdx.x * 256 + threadIdx.x;
  if (idx >= tot) return;
  int r = (int)(idx / ld);
  int c = (int)(idx - (long)r * ld);
  int p = perm[r];
  float v = src[(long)p * nsrc + c];
  if (c == p) v += 1.f;
  u16 h = f2bf(v);
  Agh[idx] = h;
  Agl[idx] = f2bf(v - bf2f(h));
}

// ---------- MFMA aggregation: Y = A @ Z (A exact bf16 planes, Z 3-plane split) ----------
template<int NT>
__global__ __launch_bounds__(256) void agg_mfma(
    const u16* __restrict__ Ah, const u16* __restrict__ Al,
    const u16* __restrict__ ZT, float* __restrict__ parts,
    int K, int per_steps)
{
  __shared__ u16 At[128 * 32];
  __shared__ u16 Alt[128 * 32];
  __shared__ u16 Zt[3 * NT * 512];
  const int tid = threadIdx.x;
  const int wave = tid >> 6, lane = tid & 63;
  const long row0 = (long)blockIdx.x * 128;
  const int chunk = blockIdx.y;
  const int kbeg = chunk * per_steps * 32;
  const int kend = min(K, kbeg + per_steps * 32);
  const int m = lane & 15, q = lane >> 4;
  const int srow = lane >> 2, scol = (lane & 3) * 8;
  const bool hasAl = (Al != nullptr);

  f32x4 acc[2][NT];
  #pragma unroll
  for (int rt = 0; rt < 2; ++rt)
    #pragma unroll
    for (int ct = 0; ct < NT; ++ct) acc[rt][ct] = (f32x4)0.f;

  for (int k0 = kbeg; k0 < kend; k0 += 32) {
    #pragma unroll
    for (int t = 0; t < 2; ++t) {
      const int r = wave * 32 + t * 16;
      stageB16(Ah + (row0 + r + srow) * (long)K + k0 + scol, At + r * 32);
      if (hasAl)
        stageB16(Al + (row0 + r + srow) * (long)K + k0 + scol, Alt + r * 32);
    }
    for (int s = wave; s < 3 * NT; s += 4) {
      const u16* g = ZT + ((long)(s * 16 + srow)) * K + k0 + scol;
      stageB16(g, Zt + s * 512);
    }
    __syncthreads();

    bfrag8 af0 = *(const bfrag8*)(At + (wave * 32 + m) * 32 + q * 8);
    bfrag8 af1 = *(const bfrag8*)(At + (wave * 32 + 16 + m) * 32 + q * 8);
    bfrag8 al0, al1;
    if (hasAl) {
      al0 = *(const bfrag8*)(Alt + (wave * 32 + m) * 32 + q * 8);
      al1 = *(const bfrag8*)(Alt + (wave * 32 + 16 + m) * 32 + q * 8);
    }
    #pragma unroll
    for (int ct = 0; ct < NT; ++ct) {
      bfrag8 b0 = *(const bfrag8*)(Zt + (0 * NT + ct) * 512 + m * 32 + q * 8);
      bfrag8 b1 = *(const bfrag8*)(Zt + (1 * NT + ct) * 512 + m * 32 + q * 8);
      bfrag8 b2 = *(const bfrag8*)(Zt + (2 * NT + ct) * 512 + m * 32 + q * 8);
      acc[0][ct] = __builtin_amdgcn_mfma_f32_16x16x32_bf16(af0, b0, acc[0][ct], 0, 0, 0);
      acc[0][ct] = __builtin_amdgcn_mfma_f32_16x16x32_bf16(af0, b1, acc[0][ct], 0, 0, 0);
      acc[0][ct] = __builtin_amdgcn_mfma_f32_16x16x32_bf16(af0, b2, acc[0][ct], 0, 0, 0);
      acc[1][ct] = __builtin_amdgcn_mfma_f32_16x16x32_bf16(af1, b0, acc[1][ct], 0, 0, 0);
      acc[1][ct] = __builtin_amdgcn_mfma_f32_16x16x32_bf16(af1, b1, acc[1][ct], 0, 0, 0);
      acc[1][ct] = __builtin_amdgcn_mfma_f32_16x16x32_bf16(af1, b2, acc[1][ct], 0, 0, 0);
      if (hasAl) {
        acc[0][ct] = __builtin_amdgcn_mfma_f32_16x16x32_bf16(al0, b0, acc[0][ct], 0, 0, 0);
        acc[0][ct] = __builtin_amdgcn_mfma_f32_16x16x32_bf16(al0, b1, acc[0][ct], 0, 0, 0);
        acc[1][ct] = __builtin_amdgcn_mfma_f32_16x16x32_bf16(al1, b0, acc[1][ct], 0, 0, 0);
        acc[1][ct] = __builtin_amdgcn_mfma_f32_16x16x32_bf16(al1, b1, acc[1][ct], 0, 0, 0);
      }
    }
    __syncthreads();
  }

  float* P = parts + (long)chunk * gridDim.x * 128 * (NT * 16);
  #pragma unroll
  for (int rt = 0; rt < 2; ++rt) {
    #pragma unroll
    for (int ct = 0; ct < NT; ++ct) {
      const long grow0 = row0 + wave * 32 + rt * 16 + q * 4;
      const long gcol = ct * 16 + m;
      #pragma unroll
      for (int r = 0; r < 4; ++r)
        P[(grow0 + r) * (NT * 16) + gcol] = acc[rt][ct][r];
    }
  }
}

__global__ void reduce_k(const float* __restrict__ parts, float* __restrict__ Y,
                         long n208, int nz) {
  long idx = (long)blockIdx.x * 256 + threadIdx.x;
  if (idx >= n208) return;
  float s = 0.f;
  for (int c = 0; c < nz; ++c) s += parts[(long)c * n208 + idx];
  Y[idx] = s;
}

// Z (n x 200 f32) -> 3 bf16 planes transposed: ZT[(p*208+c)*n + k]
__global__ void zsplit_k(const float* __restrict__ Z, int n, int h, u16* __restrict__ ZT) {
  __shared__ float t[32][33];
  const int kb = blockIdx.x * 32;
  const int cb = blockIdx.y * 32;
  #pragma unroll
  for (int i = 0; i < 32; i += 8) {
    int k = kb + threadIdx.y + i;
    int c = cb + threadIdx.x;
    t[threadIdx.y + i][threadIdx.x] = (c < h) ? Z[(long)k * h + c] : 0.f;
  }
  __syncthreads();
  #pragma unroll
  for (int i = 0; i < 32; i += 8) {
    int c = cb + threadIdx.y + i;
    if (c >= 208) continue;
    long k = kb + threadIdx.x;
    float v = t[threadIdx.x][threadIdx.y + i];
    u16 hi = f2bf(v); float r1 = v - bf2f(hi);
    u16 mi = f2bf(r1); float r2 = r1 - bf2f(mi);
    u16 lo = f2bf(r2);
    ZT[((long)0 * 208 + c) * n + k] = hi;
    ZT[((long)1 * 208 + c) * n + k] = mi;
    ZT[((long)2 * 208 + c) * n + k] = lo;
  }
}

// split fp32 A into exact bf16 hi/lo planes (Al nullable)
__global__ void asplit_k(const float* __restrict__ src, long tot,
                         u16* __restrict__ Ah, u16* __restrict__ Al) {
  long idx = (long)blockIdx.x * 256 + threadIdx.x;
  if (idx >= tot) return;
  float v = src[idx];
  u16 h = f2bf(v);
  Ah[idx] = h;
  if (Al) Al[idx] = f2bf(v - bf2f(h));
}

__global__ void a_from_adj_k(const void* __restrict__ adj, const int* __restrict__ dtf,
                             long tot, u16* __restrict__ Ah) {
  int bf = *dtf;
  long idx = (long)blockIdx.x * 256 + threadIdx.x;
  if (idx >= tot) return;
  Ah[idx] = bf ? ((const u16*)adj)[idx] : f2bf(((const float*)adj)[idx]);
}

// ---------- fp64-accumulating GEMM, 64x64 tile (x@W), fused row-scale epilogue ----------
__global__ __launch_bounds__(256) void gemm64_f64(
    const void* __restrict__ Ap, long lda, int abf,
    const void* __restrict__ Bp, long ldb, int bbf,
    float* __restrict__ C, long ldc, int M, int N, int K,
    const float* __restrict__ dscale, const int* __restrict__ dtf)
{
  const int abf_ = get_bf(abf, dtf);
  const int bbf_ = get_bf(bbf, dtf);
  __shared__ float As[16][64];
  __shared__ float Bs[16][64];
  const int tid = threadIdx.x;
  const int tr = tid >> 4, tc = tid & 15;
  const long row0 = (long)blockIdx.y * 64;
  const long col0 = (long)blockIdx.x * 64;
  double acc[4][4];
  #pragma unroll
  for (int i = 0; i < 4; ++i)
    #pragma unroll
    for (int j = 0; j < 4; ++j) acc[i][j] = 0.0;

  const int am = tid >> 2;
  const int ak = (tid & 3) * 4;
  const int bk = tid >> 4;
  const int bn = (tid & 15) * 4;

  for (int k0 = 0; k0 < K; k0 += 16) {
    float va[4] = {0.f, 0.f, 0.f, 0.f};
    {
      long gm = row0 + am; long gk = k0 + ak;
      if (gm < M && gk < K) ld4(Ap, abf_, gm * lda + gk, gk, K, va);
    }
    As[ak + 0][am] = va[0]; As[ak + 1][am] = va[1];
    As[ak + 2][am] = va[2]; As[ak + 3][am] = va[3];

    float vb[4] = {0.f, 0.f, 0.f, 0.f};
    {
      long gk = k0 + bk; long gn = col0 + bn;
      if (gk < K && gn < N) ld4(Bp, bbf_, gk * ldb + gn, gn, N, vb);
    }
    Bs[bk][bn + 0] = vb[0]; Bs[bk][bn + 1] = vb[1];
    Bs[bk][bn + 2] = vb[2]; Bs[bk][bn + 3] = vb[3];

    __syncthreads();
    #pragma unroll
    for (int kk = 0; kk < 16; ++kk) {
      float a[4], b[4];
      #pragma unroll
      for (int i = 0; i < 4; ++i) a[i] = As[kk][tr * 4 + i];
      #pragma unroll
      for (int j = 0; j < 4; ++j) b[j] = Bs[kk][tc * 4 + j];
      #pragma unroll
      for (int i = 0; i < 4; ++i)
        #pragma unroll
        for (int j = 0; j < 4; ++j)
          acc[i][j] += (double)a[i] * (double)b[j];
    }
    __syncthreads();
  }
  #pragma unroll
  for (int i = 0; i < 4; ++i) {
    long gm = row0 + tr * 4 + i;
    if (gm >= M) continue;
    float sc = dscale ? dscale[gm] : 1.f;
    #pragma unroll
    for (int j = 0; j < 4; ++j) {
      long gn = col0 + tc * 4 + j;
      if (gn < N) {
        float v = (float)acc[i][j];  // f64 -> f32 first (bit-identical to old path)
        C[gm * ldc + gn] = v * sc;
      }
    }
  }
}

// ---------- small kernels ----------
struct UpBatch {
  const void* src[19];
  float* dst[19];
  int n[19];
};

__global__ void upcast_batch_k(UpBatch ub, const int* __restrict__ dtf) {
  int bf = *dtf;
  int a = blockIdx.y;
  int i = blockIdx.x * 256 + threadIdx.x;
  if (i < ub.n[a]) ub.dst[a][i] = ld1(ub.src[a], bf, i);
}

__global__ void rowsum_dinv_k(const void* __restrict__ A, int abf, int n, float* __restrict__ dinv,
                              const int* __restrict__ dtf) {
  const int bf = get_bf(abf, dtf);
  const int row = blockIdx.x;
  const int tid = threadIdx.x;
  const long base = (long)row * n;
  double s = 0.0;
  for (int j = tid; j < n; j += 256) s += (double)ld1(A, bf, base + j);
  __shared__ double red[256];
  red[tid] = s; __syncthreads();
  for (int st = 128; st > 0; st >>= 1) {
    if (tid < st) red[tid] += red[tid + st];
    __syncthreads();
  }
  if (tid == 0) dinv[row] = (float)(1.0 / sqrt(red[0] + 2.0));
}

// Y has leading dim 208; Zs has leading dim h(=200)
__global__ void gcn_epi_k(const float* __restrict__ Y, const float* __restrict__ Zs,
                          const float* __restrict__ dinv, const float* __restrict__ b,
                          float* __restrict__ out, int n, int h, int relu) {
  long idx = (long)blockIdx.x * 256 + threadIdx.x;
  if (idx >= (long)n * h) return;
  int i = (int)(idx / h);
  int j = (int)(idx - (long)i * h);
  float v = dinv[i] * (Y[(long)i * 208 + j] + 2.f * Zs[idx]) + b[j];
  if (relu) v = fmaxf(v, 0.f);
  out[idx] = v;
}

// fused ||p|| + score (one wave per row; norm recomputed per block, deterministic)
__global__ void score_k(const float* __restrict__ x, int h, const float* __restrict__ pw,
                        float* __restrict__ score) {
  int row = blockIdx.x, lane = threadIdx.x;
  double ps = 0.0;
  for (int j = lane; j < h; j += 64) { double w = pw[j]; ps += w * w; }
  for (int off = 32; off > 0; off >>= 1) ps += __shfl_down(ps, off);
  double nrm = sqrt(__shfl(ps, 0));
  const long base = (long)row * h;
  double s = 0.0;
  for (int j = lane; j < h; j += 64) s += (double)x[base + j] * (double)pw[j];
  for (int off = 32; off > 0; off >>= 1) s += __shfl_down(s, off);
  if (lane == 0) score[row] = (float)tanh(s / nrm);
}

// ---------- register/shuffle bitonic top-k (identical network to LDS-only version) ----------
// V elems/thread; strides < V in-thread, strides <= 32V wave shfl_xor, larger via LDS.
template<int V>
__global__ __launch_bounds__(1024) void topk_fast(const float* __restrict__ score,
                                                  int n, int np2, int k,
                                                  int* __restrict__ perm) {
  __shared__ u64 keys[4096];
  const int tid = threadIdx.x;
  const int REGMAX = 32 * V;
  u64 kreg[V];
  #pragma unroll
  for (int r = 0; r < V; ++r) {
    int i = tid * V + r;
    u64 key = 0ULL;
    if (i < n) {
      u32 b = __float_as_uint(score[i]);
      u32 u = (b & 0x80000000u) ? ~b : (b | 0x80000000u);
      key = ((u64)u << 32) | (u32)(~(u32)i);
    }
    kreg[r] = key;
  }

  for (int size = 2; size <= np2; size <<= 1) {
    int stride = size >> 1;
    if (stride > REGMAX) {
      // spill to LDS for the cross-wave strides
      #pragma unroll
      for (int r = 0; r < V; ++r) keys[tid * V + r] = kreg[r];
      __syncthreads();
      for (; stride > REGMAX; stride >>= 1) {
        for (int i = tid; i < np2; i += 1024) {
          int j = i ^ stride;
          if (j > i) {
            u64 a = keys[i], b = keys[j];
            bool up = ((i & size) == 0);
            if (up ? (a > b) : (a < b)) { keys[i] = b; keys[j] = a; }
          }
        }
        __syncthreads();
      }
      #pragma unroll
      for (int r = 0; r < V; ++r) kreg[r] = keys[tid * V + r];
    }
    // wave-local / in-thread strides (no barriers)
    for (; stride >= 1; stride >>= 1) {
      if (stride >= V) {
        int lm = stride / V;
        #pragma unroll
        for (int r = 0; r < V; ++r) {
          u64 mine = kreg[r];
          u64 other = (u64)__shfl_xor((long long)mine, lm);
          int i = tid * V + r;
          bool up = ((i & size) == 0);
          bool lower = ((i & stride) == 0);
          u64 mn = mine < other ? mine : other;
          u64 mx = mine < other ? other : mine;
          kreg[r] = (lower == up) ? mn : mx;
        }
      } else {
        #pragma unroll
        for (int r = 0; r < V; ++r) {
          int pr = r ^ stride;
          if (pr > r) {
            int i = tid * V + r;
            bool up = ((i & size) == 0);
            u64 a = kreg[r], b = kreg[pr];
            if (up ? (a > b) : (a < b)) { kreg[r] = b; kreg[pr] = a; }
          }
        }
      }
    }
  }
  // sorted ascending across elements; emit top-k descending
  #pragma unroll
  for (int r = 0; r < V; ++r) {
    int i = tid * V + r;
    int rank = np2 - 1 - i;
    if (rank < k) perm[rank] = (int)(~(u32)(kreg[r] & 0xFFFFFFFFull));
  }
}

__global__ void gatherx_k(const float* __restrict__ xsrc, const float* __restrict__ score,
                          const int* __restrict__ perm, int k, int h, float* __restrict__ xdst) {
  long idx = (long)blockIdx.x * 256 + threadIdx.x;
  if (idx >= (long)k * h) return;
  int r = (int)(idx / h);
  int c = (int)(idx - (long)r * h);
  int p = perm[r];
  xdst[idx] = xsrc[(long)p * h + c] * score[p];
}

__global__ void copy_k(const float* __restrict__ src, float* __restrict__ dst, long n) {
  long idx = (long)blockIdx.x * 256 + threadIdx.x;
  if (idx < n) dst[idx] = src[idx];
}

__global__ void scatter_add_k(float* __restrict__ dst, const int* __restrict__ perm,
                              const float* __restrict__ src, int k, int h) {
  long idx = (long)blockIdx.x * 256 + threadIdx.x;
  if (idx >= (long)k * h) return;
  int r = (int)(idx / h);
  int c = (int)(idx - (long)r * h);
  dst[(long)perm[r] * h + c] += src[idx];
}

__global__ void matvec2_k(const void* __restrict__ A, int abf, int n,
                          const float* __restrict__ Zs, float* __restrict__ Y,
                          const int* __restrict__ dtf) {
  const int bf = get_bf(abf, dtf);
  int row = blockIdx.x, tid = threadIdx.x;
  const long base = (long)row * n;
  double s0 = 0.0, s1 = 0.0;
  for (int j = tid; j < n; j += 256) {
    double a = (double)ld1(A, bf, base + j);
    s0 += a * (double)Zs[2 * j];
    s1 += a * (double)Zs[2 * j + 1];
  }
  __shared__ double r0[256], r1[256];
  r0[tid] = s0; r1[tid] = s1; __syncthreads();
  for (int st = 128; st > 0; st >>= 1) {
    if (tid < st) { r0[tid] += r0[tid + st]; r1[tid] += r1[tid + st]; }
    __syncthreads();
  }
  if (tid == 0) { Y[2 * row] = (float)r0[0]; Y[2 * row + 1] = (float)r1[0]; }
}

__global__ void final_k(const float* __restrict__ Y, const float* __restrict__ Zs,
                        const float* __restrict__ dinv, const float* __restrict__ b2,
                        int n, float* __restrict__ out) {
  int i = blockIdx.x * 256 + threadIdx.x;
  if (i >= n) return;
  double di = dinv[i];
  double t0 = di * ((double)Y[2 * i] + 2.0 * (double)Zs[2 * i]) + (double)b2[0];
  double t1 = di * ((double)Y[2 * i + 1] + 2.0 * (double)Zs[2 * i + 1]) + (double)b2[1];
  double m = fmax(t0, t1);
  double l = m + log(exp(t0 - m) + exp(t1 - m));
  out[2 * i] = (float)(t0 - l);
  out[2 * i + 1] = (float)(t1 - l);
}

// ---------- host orchestration ----------
extern "C" void kernel_launch(void* const* d_in, const int* in_sizes, int n_in,
                              void* d_out, int out_size, void* d_ws, size_t ws_size,
                              hipStream_t stream) {
  const int N0 = 4096, H = 200;
  const int K1 = 3072, K2 = 1536, K3 = 768;

  const void* in_x = d_in[0];
  const void* adj  = d_in[1];
  const void* w0 = d_in[2];  const void* b0 = d_in[3];
  const void* w1 = d_in[4];  const void* b1 = d_in[5];
  const void* w2 = d_in[6];  const void* b2 = d_in[7];
  const void* w3 = d_in[8];  const void* b3 = d_in[9];
  const void* p1 = d_in[10]; const void* p2 = d_in[11];
  const void* p3 = d_in[12];
  const void* u0w = d_in[13]; const void* u0b = d_in[14];
  const void* u1w = d_in[15]; const void* u1b = d_in[16];
  const void* u2w = d_in[17]; const void* u2b = d_in[18];

  char* wp = (char*)d_ws;
  auto alloc = [&](size_t bytes) -> void* {
    void* p = (void*)wp;
    wp += (bytes + 255) & ~(size_t)255;
    return p;
  };
  float* As1  = (float*)alloc((size_t)K1 * K1 * 4);          // 37.7 MB
  float* As2  = (float*)alloc((size_t)K2 * K2 * 4);          // 9.4 MB
  float* A3   = (float*)alloc((size_t)K3 * K3 * 4);          // 2.4 MB
  // shared scratch: Agb_i8 (syrk operand) / parts (agg + L3 k-split) — disjoint lifetimes
  size_t scrBytes = (size_t)36864 * 208 * 4 + 1024;          // 30.7 MB
  void* scratchU = alloc(scrBytes);
  s8*    Agb  = (s8*)scratchU;
  float* parts = (float*)scratchU;
  u16* Ag3h = (u16*)alloc((size_t)K3 * K2 * 2);              // 2.4 MB
  u16* Ag3l = (u16*)alloc((size_t)K3 * K2 * 2);              // 2.4 MB
  u16* Ah0 = (u16*)alloc((size_t)N0 * N0 * 2);               // 33.5 MB
  u16* Ah1 = (u16*)alloc((size_t)K1 * K1 * 2);               // 18.9 MB
  u16* Ah2 = (u16*)alloc((size_t)K2 * K2 * 2);               // 4.7 MB
  u16* Al2 = (u16*)alloc((size_t)K2 * K2 * 2);               // 4.7 MB
  u16* Ah3 = (u16*)alloc((size_t)K3 * K3 * 2);               // 1.2 MB
  u16* Al3 = (u16*)alloc((size_t)K3 * K3 * 2);               // 1.2 MB
  u16* ZT  = (u16*)alloc((size_t)3 * 208 * N0 * 2);          // 5.1 MB
  float* xs0  = (float*)alloc((size_t)N0 * H * 4);
  float* xs1  = (float*)alloc((size_t)K1 * H * 4);
  float* xs2  = (float*)alloc((size_t)K2 * H * 4);
  float* xcur = (float*)alloc((size_t)N0 * H * 4);
  float* xtmp = (float*)alloc((size_t)N0 * H * 4);
  float* Zbuf = (float*)alloc((size_t)N0 * H * 4);
  float* Ybuf = (float*)alloc((size_t)N0 * 208 * 4);
  float* Xinf = (float*)alloc((size_t)N0 * 3 * 4);
  float* dinv0 = (float*)alloc((size_t)N0 * 4);
  float* dinv1 = (float*)alloc((size_t)K1 * 4);
  float* dinv2 = (float*)alloc((size_t)K2 * 4);
  float* dinv3 = (float*)alloc((size_t)K3 * 4);
  float* scores = (float*)alloc((size_t)N0 * 4);
  int* perm1 = (int*)alloc((size_t)K1 * 4);
  int* perm2 = (int*)alloc((size_t)K2 * 4);
  int* perm3 = (int*)alloc((size_t)K3 * 4);
  int* dtflag = (int*)alloc(256);
  float* w0f = (float*)alloc(3 * H * 4);  float* b0f = (float*)alloc(H * 4);
  float* w1f = (float*)alloc(H * H * 4);  float* b1f = (float*)alloc(H * 4);
  float* w2f = (float*)alloc(H * H * 4);  float* b2f = (float*)alloc(H * 4);
  float* w3f = (float*)alloc(H * H * 4);  float* b3f = (float*)alloc(H * 4);
  float* p1f = (float*)alloc(H * 4);
  float* p2f = (float*)alloc(H * 4);
  float* p3f = (float*)alloc(H * 4);
  float* u0wf = (float*)alloc(H * H * 4); float* u0bf = (float*)alloc(H * 4);
  float* u1wf = (float*)alloc(H * H * 4); float* u1bf = (float*)alloc(H * 4);
  float* u2wf = (float*)alloc(H * 2 * 4); float* u2bf = (float*)alloc(2 * 4);
  (void)in_sizes; (void)n_in; (void)out_size; (void)ws_size;

  detect_init_k<<<dim3(1), dim3(64), 0, stream>>>(dtflag);
  detect_k<<<dim3(4096), dim3(256), 0, stream>>>((const u32*)adj, (long)N0 * N0 / 2, dtflag);

  // batched upcast of all small params (19 arrays, one launch)
  {
    UpBatch ub;
    const void* srcs[19] = {in_x, w0, b0, w1, b1, w2, b2, w3, b3, p1, p2, p3,
                            u0w, u0b, u1w, u1b, u2w, u2b, u2b};
    float* dsts[19] = {Xinf, w0f, b0f, w1f, b1f, w2f, b2f, w3f, b3f, p1f, p2f, p3f,
                       u0wf, u0bf, u1wf, u1bf, u2wf, u2bf, u2bf};
    int ns[19] = {N0 * 3, 3 * H, H, H * H, H, H * H, H, H * H, H, H, H, H,
                  H * H, H, H * H, H, H * 2, 2, 2};
    for (int i = 0; i < 19; ++i) { ub.src[i] = srcs[i]; ub.dst[i] = dsts[i]; ub.n[i] = ns[i]; }
    upcast_batch_k<<<dim3((N0 * 3 + 255) / 256, 19), dim3(256), 0, stream>>>(ub, dtflag);
  }

  a_from_adj_k<<<dim3((unsigned)(((long)N0 * N0 + 255) / 256)), dim3(256), 0, stream>>>(
      adj, dtflag, (long)N0 * N0, Ah0);

  auto gemm64 = [&](const void* A, long lda, int abf, const void* B, long ldb, int bbf,
                    float* C, long ldc, int M, int Nn, int K, const float* dscale) {
    dim3 g((Nn + 63) / 64, (M + 63) / 64);
    gemm64_f64<<<g, dim3(256), 0, stream>>>(A, lda, abf, B, ldb, bbf, C, ldc, M, Nn, K,
                                            dscale, dtflag);
  };

  // GCN: out = maybe_relu(dinv .* (A@Zs + 2 Zs) + b)
  auto gcn = [&](const u16* Ah, const u16* Al, int n, int chunks, const float* dinv,
                 const float* Xin_, int din, const float* W, const float* bb,
                 float* out, int relu) {
    gemm64(Xin_, din, 0, W, H, 0, Zbuf, H, n, H, din, dinv);  // Z = dinv .* (Xin @ W)
    long tot = (long)n * H;
    zsplit_k<<<dim3(n / 32, 7), dim3(32, 8), 0, stream>>>(Zbuf, n, H, ZT);
    agg_mfma<13><<<dim3(n / 128, chunks), dim3(256), 0, stream>>>(
        Ah, Al, ZT, parts, n, (n / 32) / chunks);
    long n208 = (long)n * 208;
    reduce_k<<<dim3((unsigned)((n208 + 255) / 256)), dim3(256), 0, stream>>>(
        parts, Ybuf, n208, chunks);
    gcn_epi_k<<<dim3((unsigned)((tot + 255) / 256)), dim3(256), 0, stream>>>(
        Ybuf, Zbuf, dinv, bb, out, n, H, relu);
  };

  auto pool = [&](const float* xin, int n, int np2, int k, const float* pwf,
                  int* perm, float* xout) {
    score_k<<<dim3(n), dim3(64), 0, stream>>>(xin, H, pwf, scores);
    if (np2 == 4096)
      topk_fast<4><<<dim3(1), dim3(1024), 0, stream>>>(scores, n, np2, k, perm);
    else
      topk_fast<2><<<dim3(1), dim3(1024), 0, stream>>>(scores, n, np2, k, perm);
    long tot = (long)k * H;
    gatherx_k<<<dim3((unsigned)((tot + 255) / 256)), dim3(256), 0, stream>>>(
        xin, scores, perm, k, H, xout);
  };

  // ---------------- forward ----------------
  rowsum_dinv_k<<<dim3(N0), dim3(256), 0, stream>>>(adj, -1, N0, dinv0, dtflag);
  gcn(Ah0, nullptr, N0, 8, dinv0, Xinf, 3, w0f, b0f, xs0, 1);

  // down 0: i8 SYRK (entries {0,1,2})
  pool(xs0, N0, 4096, K1, p1f, perm1, xcur);
  {
    long tot = (long)K1 * N0;
    build_ag_i8_k<<<dim3((unsigned)((tot + 255) / 256)), dim3(256), 0, stream>>>(
        adj, -1, N0, perm1, tot, Agb, dtflag);
    int nt = K1 / 128;
    syrk_tri_i8<<<dim3(nt * (nt + 1) / 2), dim3(256), 0, stream>>>(Agb, N0, As1, K1, N0);
  }
  asplit_k<<<dim3((unsigned)(((long)K1 * K1 + 255) / 256)), dim3(256), 0, stream>>>(
      As1, (long)K1 * K1, Ah1, nullptr);
  rowsum_dinv_k<<<dim3(K1), dim3(256), 0, stream>>>(As1, 0, K1, dinv1, dtflag);
  gcn(Ah1, nullptr, K1, 12, dinv1, xcur, H, w1f, b1f, xs1, 1);

  // down 1: i8 SYRK (entries <= ~71)
  pool(xs1, K1, 4096, K2, p2f, perm2, xcur);
  {
    long tot = (long)K2 * K1;
    build_ag_i8_k<<<dim3((unsigned)((tot + 255) / 256)), dim3(256), 0, stream>>>(
        As1, 0, K1, perm2, tot, Agb, dtflag);
    int nt = K2 / 128;
    syrk_tri_i8<<<dim3(nt * (nt + 1) / 2), dim3(256), 0, stream>>>(Agb, K1, As2, K2, K1);
  }
  asplit_k<<<dim3((unsigned)(((long)K2 * K2 + 255) / 256)), dim3(256), 0, stream>>>(
      As2, (long)K2 * K2, Ah2, Al2);
  rowsum_dinv_k<<<dim3(K2), dim3(256), 0, stream>>>(As2, 0, K2, dinv2, dtflag);
  gcn(Ah2, Al2, K2, 24, dinv2, xcur, H, w2f, b2f, xs2, 1);

  // down 2: bf16 2-plane deterministic K-split triangle (values may exceed 127)
  pool(xs2, K2, 2048, K3, p3f, perm3, xcur);
  {
    long tot = (long)K3 * K2;
    build_ag3_split_k<<<dim3((unsigned)((tot + 255) / 256)), dim3(256), 0, stream>>>(
        As2, K2, perm3, tot, K2, Ag3h, Ag3l);
    int nt = K3 / 128;
    syrk_tri2_parts<<<dim3(nt * (nt + 1) / 2, 8), dim3(256), 0, stream>>>(
        Ag3h, Ag3l, K2, parts, K3, K2 / 8);
    long nn = (long)K3 * K3;
    reduce_tri_mirror_k<<<dim3((unsigned)((nn + 255) / 256)), dim3(256), 0, stream>>>(
        parts, A3, K3, 8);
  }
  asplit_k<<<dim3((unsigned)(((long)K3 * K3 + 255) / 256)), dim3(256), 0, stream>>>(
      A3, (long)K3 * K3, Ah3, Al3);
  rowsum_dinv_k<<<dim3(K3), dim3(256), 0, stream>>>(A3, 0, K3, dinv3, dtflag);
  gcn(Ah3, Al3, K3, 24, dinv3, xcur, H, w3f, b3f, xcur, 1);

  // up 0: j=2
  copy_k<<<dim3((unsigned)(((long)K2 * H + 255) / 256)), dim3(256), 0, stream>>>(xs2, xtmp, (long)K2 * H);
  scatter_add_k<<<dim3((unsigned)(((long)K3 * H + 255) / 256)), dim3(256), 0, stream>>>(xtmp, perm3, xcur, K3, H);
  gcn(Ah2, Al2, K2, 24, dinv2, xtmp, H, u0wf, u0bf, xcur, 1);

  // up 1: j=1
  copy_k<<<dim3((unsigned)(((long)K1 * H + 255) / 256)), dim3(256), 0, stream>>>(xs1, xtmp, (long)K1 * H);
  scatter_add_k<<<dim3((unsigned)(((long)K2 * H + 255) / 256)), dim3(256), 0, stream>>>(xtmp, perm2, xcur, K2, H);
  gcn(Ah1, nullptr, K1, 12, dinv1, xtmp, H, u1wf, u1bf, xcur, 1);

  // up 2: j=0
  copy_k<<<dim3((unsigned)(((long)N0 * H + 255) / 256)), dim3(256), 0, stream>>>(xs0, xtmp, (long)N0 * H);
  scatter_add_k<<<dim3((unsigned)(((long)K1 * H + 255) / 256)), dim3(256), 0, stream>>>(xtmp, perm1, xcur, K1, H);
  gemm64(xtmp, H, 0, u2wf, 2, 0, Zbuf, 2, N0, 2, H, dinv0);   // Z2 = dinv0 .* (x @ u2w)
  matvec2_k<<<dim3(N0), dim3(256), 0, stream>>>(adj, -1, N0, Zbuf, Ybuf, dtflag);
  final_k<<<dim3((N0 + 255) / 256), dim3(256), 0, stream>>>(Ybuf, Zbuf, dinv0, u2bf, N0, (float*)d_out);
}

// Round 9
// 949.865 us; speedup vs baseline: 1.2256x; 1.0249x over previous
//
#include <hip/hip_runtime.h>

typedef unsigned short u16;
typedef unsigned int u32;
typedef unsigned long long u64;
typedef signed char s8;
typedef __attribute__((ext_vector_type(8))) short bfrag8;
typedef __attribute__((ext_vector_type(4))) float f32x4;
typedef __attribute__((ext_vector_type(4))) int i32x4;
typedef __attribute__((address_space(1))) const void gconst_void;
typedef __attribute__((address_space(3))) void lds_void_t;

// ---------- helpers ----------
__device__ __forceinline__ float bf2f(u16 u) {
  return __uint_as_float(((u32)u) << 16);
}
__device__ __forceinline__ u16 f2bf(float f) {
  u32 u = __float_as_uint(f);
  u32 r = (u + 0x7FFFu + ((u >> 16) & 1u)) >> 16;  // RTNE
  return (u16)r;
}
__device__ __forceinline__ float ld1(const void* p, int isbf, long idx) {
  return isbf ? bf2f(((const u16*)p)[idx]) : ((const float*)p)[idx];
}
__device__ __forceinline__ void ld4(const void* p, int isbf, long base, long gc, long bound, float v[4]) {
  if (gc + 3 < bound && ((base & 3) == 0)) {
    if (isbf) {
      const ushort4 u = *(const ushort4*)((const u16*)p + base);
      v[0] = bf2f(u.x); v[1] = bf2f(u.y); v[2] = bf2f(u.z); v[3] = bf2f(u.w);
    } else {
      const float4 f = *(const float4*)((const float*)p + base);
      v[0] = f.x; v[1] = f.y; v[2] = f.z; v[3] = f.w;
    }
  } else {
    #pragma unroll
    for (int d = 0; d < 4; ++d) v[d] = (gc + d < bound) ? ld1(p, isbf, base + d) : 0.f;
  }
}

// ---------- input dtype autodetect ----------
__global__ void detect_init_k(int* flag) { if (threadIdx.x == 0 && blockIdx.x == 0) *flag = 0; }

__global__ void detect_k(const u32* __restrict__ a, long nw, int* __restrict__ flag) {
  long stride = (long)gridDim.x * 256;
  int f = 0;
  for (long j = (long)blockIdx.x * 256 + threadIdx.x; j < nw; j += stride) {
    u32 w = a[j];
    if (w == 0x00003F80u || w == 0x3F803F80u) f = 1;
  }
  if (__any(f)) {
    if ((threadIdx.x & 63) == 0) atomicOr(flag, 1);
  }
}

__device__ __forceinline__ int get_bf(int abf, const int* dtf) {
  return (abf >= 0) ? abf : *dtf;
}

// ---------- async global->LDS stage ----------
__device__ __forceinline__ void stageB16(const void* g, void* lds) {
#if __has_builtin(__builtin_amdgcn_global_load_lds)
  __builtin_amdgcn_global_load_lds((gconst_void*)g, (lds_void_t*)lds, 16, 0, 0);
#else
  int lane = threadIdx.x & 63;
  *(int4*)((char*)lds + lane * 16) = *(const int4*)g;
#endif
}

// ---------- i8 triangle SYRK, fused: C + Ah(+Al) bf16 planes + f64 row sums ----------
__global__ __launch_bounds__(256) void syrk_tri_i8(
    const s8* __restrict__ Ag, int ldk, float* __restrict__ C, int ldc, int K,
    u16* __restrict__ Ah, u16* __restrict__ Al, double* __restrict__ rsum)
{
  __shared__ s8 At[128 * 64];
  __shared__ s8 Bt[128 * 64];
  __shared__ int tb[4][16][17];
  const int t = blockIdx.x;
  int ti = (int)((sqrtf((float)(8 * t + 1)) - 1.0f) * 0.5f);
  while ((ti + 1) * (ti + 2) / 2 <= t) ++ti;
  while (ti * (ti + 1) / 2 > t) --ti;
  const int tj = t - ti * (ti + 1) / 2;

  const int tid = threadIdx.x;
  const int wave = tid >> 6, lane = tid & 63;
  const int wr = wave >> 1, wc = wave & 1;
  const long rowA0 = (long)ti * 128;
  const long rowB0 = (long)tj * 128;

  i32x4 acc[4][4];
  #pragma unroll
  for (int i = 0; i < 4; ++i)
    #pragma unroll
    for (int j = 0; j < 4; ++j) acc[i][j] = (i32x4)0;

  const int srow = lane >> 2;
  const int scol = (lane & 3) * 16;
  const int m = lane & 15, q = lane >> 4;

  for (int k0 = 0; k0 < K; k0 += 64) {
    #pragma unroll
    for (int tt = 0; tt < 2; ++tt) {
      const int r = wave * 32 + tt * 16;
      stageB16(Ag + (rowA0 + r + srow) * (long)ldk + k0 + scol, At + r * 64);
      stageB16(Ag + (rowB0 + r + srow) * (long)ldk + k0 + scol, Bt + r * 64);
    }
    __syncthreads();

    i32x4 af[4], bf[4];
    #pragma unroll
    for (int mt = 0; mt < 4; ++mt)
      af[mt] = *(const i32x4*)(At + (wr * 64 + mt * 16 + m) * 64 + q * 16);
    #pragma unroll
    for (int nt = 0; nt < 4; ++nt)
      bf[nt] = *(const i32x4*)(Bt + (wc * 64 + nt * 16 + m) * 64 + q * 16);
    #pragma unroll
    for (int mt = 0; mt < 4; ++mt)
      #pragma unroll
      for (int nt = 0; nt < 4; ++nt)
        acc[mt][nt] = __builtin_amdgcn_mfma_i32_16x16x64_i8(af[mt], bf[nt], acc[mt][nt], 0, 0, 0);
    __syncthreads();
  }

  // direct (lower) tile: C + bf16 planes + row partials -> f64 atomics
  #pragma unroll
  for (int mt = 0; mt < 4; ++mt) {
    double rp[4] = {0.0, 0.0, 0.0, 0.0};
    #pragma unroll
    for (int nt = 0; nt < 4; ++nt) {
      const long gr0 = rowA0 + wr * 64 + mt * 16 + q * 4;
      const long gc = rowB0 + wc * 64 + nt * 16 + m;
      #pragma unroll
      for (int r = 0; r < 4; ++r) {
        const long gr = gr0 + r;
        int iv = (gr == gc) ? 0 : acc[mt][nt][r];
        float fv = (float)iv;
        long idx = gr * ldc + gc;
        C[idx] = fv;
        u16 h = f2bf(fv);
        Ah[idx] = h;
        if (Al) Al[idx] = f2bf(fv - bf2f(h));
        rp[r] += (double)iv;
      }
    }
    #pragma unroll
    for (int r = 0; r < 4; ++r) {
      double v = rp[r];
      for (int off = 8; off > 0; off >>= 1) v += __shfl_down(v, off);
      if (m == 0) atomicAdd(&rsum[rowA0 + wr * 64 + mt * 16 + q * 4 + r], v);
    }
  }
  // mirror tile + column sums
  if (ti != tj) {
    #pragma unroll
    for (int nt = 0; nt < 4; ++nt) {
      double cp = 0.0;
      #pragma unroll
      for (int mt = 0; mt < 4; ++mt) {
        #pragma unroll
        for (int r = 0; r < 4; ++r) tb[wave][q * 4 + r][m] = acc[mt][nt][r];
        const long baseR = rowB0 + wc * 64 + nt * 16;
        const long baseC = rowA0 + wr * 64 + mt * 16;
        #pragma unroll
        for (int r = 0; r < 4; ++r) {
          float tv = (float)tb[wave][m][q * 4 + r];
          long idx = (baseR + q * 4 + r) * ldc + baseC + m;
          C[idx] = tv;
          u16 h = f2bf(tv);
          Ah[idx] = h;
          if (Al) Al[idx] = f2bf(tv - bf2f(h));
        }
        #pragma unroll
        for (int r = 0; r < 4; ++r) cp += (double)acc[mt][nt][r];
      }
      double v = cp;
      v += __shfl_down(v, 32);
      v += __shfl_down(v, 16);
      if (q == 0) atomicAdd(&rsum[rowB0 + wc * 64 + nt * 16 + m], v);
    }
  }
}

// ---------- bf16 2-plane triangle SYRK, K-split parts (L3) ----------
__global__ __launch_bounds__(256) void syrk_tri2_parts(
    const u16* __restrict__ Ah, const u16* __restrict__ Al, int ldk,
    float* __restrict__ parts, int n, int per)
{
  __shared__ u16 Ath[128 * 32];
  __shared__ u16 Bth[128 * 32];
  __shared__ u16 Atl[128 * 32];
  __shared__ u16 Btl[128 * 32];
  const int t = blockIdx.x;
  int ti = (int)((sqrtf((float)(8 * t + 1)) - 1.0f) * 0.5f);
  while ((ti + 1) * (ti + 2) / 2 <= t) ++ti;
  while (ti * (ti + 1) / 2 > t) --ti;
  const int tj = t - ti * (ti + 1) / 2;

  const int tid = threadIdx.x;
  const int wave = tid >> 6, lane = tid & 63;
  const int wr = wave >> 1, wc = wave & 1;
  const long rowA0 = (long)ti * 128;
  const long rowB0 = (long)tj * 128;
  const int kbeg = blockIdx.y * per;
  const int kend = kbeg + per;

  f32x4 acc[4][4];
  #pragma unroll
  for (int i = 0; i < 4; ++i)
    #pragma unroll
    for (int j = 0; j < 4; ++j) acc[i][j] = (f32x4)0.f;

  const int srow = lane >> 2;
  const int scol = (lane & 3) * 8;
  const int m = lane & 15, q = lane >> 4;

  for (int k0 = kbeg; k0 < kend; k0 += 32) {
    #pragma unroll
    for (int tt = 0; tt < 2; ++tt) {
      const int r = wave * 32 + tt * 16;
      stageB16(Ah + (rowA0 + r + srow) * (long)ldk + k0 + scol, Ath + r * 32);
      stageB16(Ah + (rowB0 + r + srow) * (long)ldk + k0 + scol, Bth + r * 32);
      stageB16(Al + (rowA0 + r + srow) * (long)ldk + k0 + scol, Atl + r * 32);
      stageB16(Al + (rowB0 + r + srow) * (long)ldk + k0 + scol, Btl + r * 32);
    }
    __syncthreads();

    bfrag8 afh[4], afl[4], bfh[4], bfl[4];
    #pragma unroll
    for (int mt = 0; mt < 4; ++mt) {
      afh[mt] = *(const bfrag8*)(Ath + (wr * 64 + mt * 16 + m) * 32 + q * 8);
      afl[mt] = *(const bfrag8*)(Atl + (wr * 64 + mt * 16 + m) * 32 + q * 8);
    }
    #pragma unroll
    for (int nt = 0; nt < 4; ++nt) {
      bfh[nt] = *(const bfrag8*)(Bth + (wc * 64 + nt * 16 + m) * 32 + q * 8);
      bfl[nt] = *(const bfrag8*)(Btl + (wc * 64 + nt * 16 + m) * 32 + q * 8);
    }
    #pragma unroll
    for (int mt = 0; mt < 4; ++mt)
      #pragma unroll
      for (int nt = 0; nt < 4; ++nt) {
        acc[mt][nt] = __builtin_amdgcn_mfma_f32_16x16x32_bf16(afh[mt], bfh[nt], acc[mt][nt], 0, 0, 0);
        acc[mt][nt] = __builtin_amdgcn_mfma_f32_16x16x32_bf16(afh[mt], bfl[nt], acc[mt][nt], 0, 0, 0);
        acc[mt][nt] = __builtin_amdgcn_mfma_f32_16x16x32_bf16(afl[mt], bfh[nt], acc[mt][nt], 0, 0, 0);
        acc[mt][nt] = __builtin_amdgcn_mfma_f32_16x16x32_bf16(afl[mt], bfl[nt], acc[mt][nt], 0, 0, 0);
      }
    __syncthreads();
  }

  float* P = parts + (long)blockIdx.y * n * n;
  #pragma unroll
  for (int mt = 0; mt < 4; ++mt) {
    #pragma unroll
    for (int nt = 0; nt < 4; ++nt) {
      const long gr0 = rowA0 + wr * 64 + mt * 16 + q * 4;
      const long gc = rowB0 + wc * 64 + nt * 16 + m;
      #pragma unroll
      for (int r = 0; r < 4; ++r)
        P[(gr0 + r) * n + gc] = acc[mt][nt][r];
    }
  }
}

// sum nz parts (lower valid), mirror, zero diag; fused Ah/Al write + f64 row sums.
// Requires n % 256 == 0 (each block within one row).
__global__ void reduce_tri_mirror_k(const float* __restrict__ parts, float* __restrict__ C,
                                    u16* __restrict__ Ah, u16* __restrict__ Al,
                                    double* __restrict__ rsum, int n, int nz) {
  __shared__ double red[256];
  const int tid = threadIdx.x;
  long idx = (long)blockIdx.x * 256 + tid;
  long nn = (long)n * n;
  long r = idx / n, c = idx - r * n;
  double myv = 0.0;
  if (idx < nn) {
    if (r == c) {
      C[idx] = 0.f; Ah[idx] = 0; Al[idx] = 0;
    } else if (r > c) {
      float s = 0.f;
      for (int z = 0; z < nz; ++z) s += parts[(long)z * nn + r * n + c];
      long mi = c * n + r;
      C[idx] = s; C[mi] = s;
      u16 h = f2bf(s);
      u16 l = f2bf(s - bf2f(h));
      Ah[idx] = h; Al[idx] = l;
      Ah[mi] = h;  Al[mi] = l;
      myv = (double)s;
      atomicAdd(&rsum[c], (double)s);  // column-side (exact: integers)
    }
  }
  red[tid] = myv;
  __syncthreads();
  for (int st = 128; st > 0; st >>= 1) {
    if (tid < st) red[tid] += red[tid + st];
    __syncthreads();
  }
  if (tid == 0 && idx < nn) atomicAdd(&rsum[r], red[0]);
}

// build i8 augment operand
__global__ void build_ag_i8_k(const void* __restrict__ src, int srcbf, int nsrc,
                              const int* __restrict__ perm, long tot,
                              s8* __restrict__ Ag, const int* __restrict__ dtf) {
  long idx = (long)blockIdx.x * 256 + threadIdx.x;
  if (idx >= tot) return;
  int r = (int)(idx / nsrc);
  int c = (int)(idx - (long)r * nsrc);
  int p = perm[r];
  float v = ld1(src, get_bf(srcbf, dtf), (long)p * nsrc + c);
  if (c == p) v += 1.f;
  Ag[idx] = (s8)(int)v;
}

// build level-2 augment operand in exact 2-plane bf16
__global__ void build_ag3_split_k(const float* __restrict__ src, int nsrc,
                                  const int* __restrict__ perm, long tot, int ld,
                                  u16* __restrict__ Agh, u16* __restrict__ Agl) {
  long idx = (long)blockIdx.x * 256 + threadIdx.x;
  if (idx >= tot) return;
  int r = (int)(idx / ld);
  int c = (int)(idx - (long)r * ld);
  int p = perm[r];
  float v = src[(long)p * nsrc + c];
  if (c == p) v += 1.f;
  u16 h = f2bf(v);
  Agh[idx] = h;
  Agl[idx] = f2bf(v - bf2f(h));
}

// ---------- MFMA aggregation: Y = A @ Z ----------
template<int NT>
__global__ __launch_bounds__(256) void agg_mfma(
    const u16* __restrict__ Ah, const u16* __restrict__ Al,
    const u16* __restrict__ ZT, float* __restrict__ parts,
    int K, int per_steps)
{
  __shared__ u16 At[128 * 32];
  __shared__ u16 Alt[128 * 32];
  __shared__ u16 Zt[3 * NT * 512];
  const int tid = threadIdx.x;
  const int wave = tid >> 6, lane = tid & 63;
  const long row0 = (long)blockIdx.x * 128;
  const int chunk = blockIdx.y;
  const int kbeg = chunk * per_steps * 32;
  const int kend = min(K, kbeg + per_steps * 32);
  const int m = lane & 15, q = lane >> 4;
  const int srow = lane >> 2, scol = (lane & 3) * 8;
  const bool hasAl = (Al != nullptr);

  f32x4 acc[2][NT];
  #pragma unroll
  for (int rt = 0; rt < 2; ++rt)
    #pragma unroll
    for (int ct = 0; ct < NT; ++ct) acc[rt][ct] = (f32x4)0.f;

  for (int k0 = kbeg; k0 < kend; k0 += 32) {
    #pragma unroll
    for (int t = 0; t < 2; ++t) {
      const int r = wave * 32 + t * 16;
      stageB16(Ah + (row0 + r + srow) * (long)K + k0 + scol, At + r * 32);
      if (hasAl)
        stageB16(Al + (row0 + r + srow) * (long)K + k0 + scol, Alt + r * 32);
    }
    for (int s = wave; s < 3 * NT; s += 4) {
      const u16* g = ZT + ((long)(s * 16 + srow)) * K + k0 + scol;
      stageB16(g, Zt + s * 512);
    }
    __syncthreads();

    bfrag8 af0 = *(const bfrag8*)(At + (wave * 32 + m) * 32 + q * 8);
    bfrag8 af1 = *(const bfrag8*)(At + (wave * 32 + 16 + m) * 32 + q * 8);
    bfrag8 al0, al1;
    if (hasAl) {
      al0 = *(const bfrag8*)(Alt + (wave * 32 + m) * 32 + q * 8);
      al1 = *(const bfrag8*)(Alt + (wave * 32 + 16 + m) * 32 + q * 8);
    }
    #pragma unroll
    for (int ct = 0; ct < NT; ++ct) {
      bfrag8 b0 = *(const bfrag8*)(Zt + (0 * NT + ct) * 512 + m * 32 + q * 8);
      bfrag8 b1 = *(const bfrag8*)(Zt + (1 * NT + ct) * 512 + m * 32 + q * 8);
      bfrag8 b2 = *(const bfrag8*)(Zt + (2 * NT + ct) * 512 + m * 32 + q * 8);
      acc[0][ct] = __builtin_amdgcn_mfma_f32_16x16x32_bf16(af0, b0, acc[0][ct], 0, 0, 0);
      acc[0][ct] = __builtin_amdgcn_mfma_f32_16x16x32_bf16(af0, b1, acc[0][ct], 0, 0, 0);
      acc[0][ct] = __builtin_amdgcn_mfma_f32_16x16x32_bf16(af0, b2, acc[0][ct], 0, 0, 0);
      acc[1][ct] = __builtin_amdgcn_mfma_f32_16x16x32_bf16(af1, b0, acc[1][ct], 0, 0, 0);
      acc[1][ct] = __builtin_amdgcn_mfma_f32_16x16x32_bf16(af1, b1, acc[1][ct], 0, 0, 0);
      acc[1][ct] = __builtin_amdgcn_mfma_f32_16x16x32_bf16(af1, b2, acc[1][ct], 0, 0, 0);
      if (hasAl) {
        acc[0][ct] = __builtin_amdgcn_mfma_f32_16x16x32_bf16(al0, b0, acc[0][ct], 0, 0, 0);
        acc[0][ct] = __builtin_amdgcn_mfma_f32_16x16x32_bf16(al0, b1, acc[0][ct], 0, 0, 0);
        acc[1][ct] = __builtin_amdgcn_mfma_f32_16x16x32_bf16(al1, b0, acc[1][ct], 0, 0, 0);
        acc[1][ct] = __builtin_amdgcn_mfma_f32_16x16x32_bf16(al1, b1, acc[1][ct], 0, 0, 0);
      }
    }
    __syncthreads();
  }

  float* P = parts + (long)chunk * gridDim.x * 128 * (NT * 16);
  #pragma unroll
  for (int rt = 0; rt < 2; ++rt) {
    #pragma unroll
    for (int ct = 0; ct < NT; ++ct) {
      const long grow0 = row0 + wave * 32 + rt * 16 + q * 4;
      const long gcol = ct * 16 + m;
      #pragma unroll
      for (int r = 0; r < 4; ++r)
        P[(grow0 + r) * (NT * 16) + gcol] = acc[rt][ct][r];
    }
  }
}

// fused: reduce parts + GCN epilogue (+ optional pooling score, bit-identical to score_k)
__global__ __launch_bounds__(256) void reduce_epi_k(
    const float* __restrict__ parts, const float* __restrict__ Zs,
    const double* __restrict__ rs, const float* __restrict__ b,
    float* __restrict__ out, int n, int nz, int relu,
    const float* __restrict__ pw, float* __restrict__ score)
{
  __shared__ float vrow[200];
  const int i = blockIdx.x, tid = threadIdx.x;
  float dv = (float)(1.0 / sqrt(rs[i] + 2.0));
  if (tid < 200) {
    long base = (long)i * 208 + tid;
    float s = 0.f;
    for (int c = 0; c < nz; ++c) s += parts[(long)c * n * 208 + base];
    float v = dv * (s + 2.f * Zs[(long)i * 200 + tid]) + b[tid];
    if (relu) v = fmaxf(v, 0.f);
    out[(long)i * 200 + tid] = v;
    if (score) vrow[tid] = v;
  }
  if (!score) return;
  __syncthreads();
  if (tid < 64) {
    double ps = 0.0;
    for (int j = tid; j < 200; j += 64) { double w = pw[j]; ps += w * w; }
    for (int off = 32; off > 0; off >>= 1) ps += __shfl_down(ps, off);
    double nrm = sqrt(__shfl(ps, 0));
    double s = 0.0;
    for (int j = tid; j < 200; j += 64) s += (double)vrow[j] * (double)pw[j];
    for (int off = 32; off > 0; off >>= 1) s += __shfl_down(s, off);
    if (tid == 0) score[i] = (float)tanh(s / nrm);
  }
}

// fused adj->bf16 plane + row sums (level 0)
__global__ void a_from_adj_rs_k(const void* __restrict__ adj, const int* __restrict__ dtf,
                                int n, u16* __restrict__ Ah, double* __restrict__ rs) {
  __shared__ double red[256];
  int bf = *dtf;
  const int row = blockIdx.x, tid = threadIdx.x;
  const long base = (long)row * n;
  double s = 0.0;
  for (int j = tid; j < n; j += 256) {
    float v = ld1(adj, bf, base + j);
    Ah[base + j] = bf ? ((const u16*)adj)[base + j] : f2bf(v);
    s += (double)v;
  }
  red[tid] = s; __syncthreads();
  for (int st = 128; st > 0; st >>= 1) {
    if (tid < st) red[tid] += red[tid + st];
    __syncthreads();
  }
  if (tid == 0) rs[row] = red[0];
}

// ---------- fp64 GEMM (x@W) with fused dinv scale + transposed 3-plane ZT split ----------
__global__ __launch_bounds__(256) void gemm64_f64(
    const void* __restrict__ Ap, long lda, int abf,
    const void* __restrict__ Bp, long ldb, int bbf,
    float* __restrict__ C, long ldc, int M, int N, int K,
    const double* __restrict__ rsum, u16* __restrict__ ZT, const int* __restrict__ dtf)
{
  const int abf_ = get_bf(abf, dtf);
  const int bbf_ = get_bf(bbf, dtf);
  __shared__ float As[16][64];
  __shared__ float Bs[16][64];
  const int tid = threadIdx.x;
  const int tr = tid >> 4, tc = tid & 15;
  const long row0 = (long)blockIdx.y * 64;
  const long col0 = (long)blockIdx.x * 64;
  double acc[4][4];
  #pragma unroll
  for (int i = 0; i < 4; ++i)
    #pragma unroll
    for (int j = 0; j < 4; ++j) acc[i][j] = 0.0;

  const int am = tid >> 2;
  const int ak = (tid & 3) * 4;
  const int bk = tid >> 4;
  const int bn = (tid & 15) * 4;

  for (int k0 = 0; k0 < K; k0 += 16) {
    float va[4] = {0.f, 0.f, 0.f, 0.f};
    {
      long gm = row0 + am; long gk = k0 + ak;
      if (gm < M && gk < K) ld4(Ap, abf_, gm * lda + gk, gk, K, va);
    }
    As[ak + 0][am] = va[0]; As[ak + 1][am] = va[1];
    As[ak + 2][am] = va[2]; As[ak + 3][am] = va[3];

    float vb[4] = {0.f, 0.f, 0.f, 0.f};
    {
      long gk = k0 + bk; long gn = col0 + bn;
      if (gk < K && gn < N) ld4(Bp, bbf_, gk * ldb + gn, gn, N, vb);
    }
    Bs[bk][bn + 0] = vb[0]; Bs[bk][bn + 1] = vb[1];
    Bs[bk][bn + 2] = vb[2]; Bs[bk][bn + 3] = vb[3];

    __syncthreads();
    #pragma unroll
    for (int kk = 0; kk < 16; ++kk) {
      float a[4], b[4];
      #pragma unroll
      for (int i = 0; i < 4; ++i) a[i] = As[kk][tr * 4 + i];
      #pragma unroll
      for (int j = 0; j < 4; ++j) b[j] = Bs[kk][tc * 4 + j];
      #pragma unroll
      for (int i = 0; i < 4; ++i)
        #pragma unroll
        for (int j = 0; j < 4; ++j)
          acc[i][j] += (double)a[i] * (double)b[j];
    }
    __syncthreads();
  }
  #pragma unroll
  for (int i = 0; i < 4; ++i) {
    long gm = row0 + tr * 4 + i;
    if (gm >= M) continue;
    float sc = rsum ? (float)(1.0 / sqrt(rsum[gm] + 2.0)) : 1.f;
    #pragma unroll
    for (int j = 0; j < 4; ++j) {
      long gn = col0 + tc * 4 + j;
      if (gn < N) {
        float v0 = (float)acc[i][j];       // f64 -> f32 (bit-identical to prior path)
        float v = v0 * sc;
        C[gm * ldc + gn] = v;
        if (ZT) {
          u16 hi = f2bf(v); float r1 = v - bf2f(hi);
          u16 mi = f2bf(r1); float r2 = r1 - bf2f(mi);
          u16 lo = f2bf(r2);
          ZT[((long)0 * 208 + gn) * M + gm] = hi;
          ZT[((long)1 * 208 + gn) * M + gm] = mi;
          ZT[((long)2 * 208 + gn) * M + gm] = lo;
        }
      }
    }
  }
}

// ---------- small kernels ----------
struct UpBatch {
  const void* src[19];
  float* dst[19];
  int n[19];
};

__global__ void upcast_batch_k(UpBatch ub, const int* __restrict__ dtf) {
  int bf = *dtf;
  int a = blockIdx.y;
  int i = blockIdx.x * 256 + threadIdx.x;
  if (i < ub.n[a]) ub.dst[a][i] = ld1(ub.src[a], bf, i);
}

// register/shuffle bitonic top-k; also emits inverse permutation (-1 = not selected)
template<int V>
__global__ __launch_bounds__(1024) void topk_fast(const float* __restrict__ score,
                                                  int n, int np2, int k,
                                                  int* __restrict__ perm,
                                                  int* __restrict__ inv) {
  __shared__ u64 keys[4096];
  const int tid = threadIdx.x;
  const int REGMAX = 32 * V;
  for (int i = tid; i < n; i += 1024) inv[i] = -1;
  u64 kreg[V];
  #pragma unroll
  for (int r = 0; r < V; ++r) {
    int i = tid * V + r;
    u64 key = 0ULL;
    if (i < n) {
      u32 b = __float_as_uint(score[i]);
      u32 u = (b & 0x80000000u) ? ~b : (b | 0x80000000u);
      key = ((u64)u << 32) | (u32)(~(u32)i);
    }
    kreg[r] = key;
  }

  for (int size = 2; size <= np2; size <<= 1) {
    int stride = size >> 1;
    if (stride > REGMAX) {
      #pragma unroll
      for (int r = 0; r < V; ++r) keys[tid * V + r] = kreg[r];
      __syncthreads();
      for (; stride > REGMAX; stride >>= 1) {
        for (int i = tid; i < np2; i += 1024) {
          int j = i ^ stride;
          if (j > i) {
            u64 a = keys[i], b = keys[j];
            bool up = ((i & size) == 0);
            if (up ? (a > b) : (a < b)) { keys[i] = b; keys[j] = a; }
          }
        }
        __syncthreads();
      }
      #pragma unroll
      for (int r = 0; r < V; ++r) kreg[r] = keys[tid * V + r];
    }
    for (; stride >= 1; stride >>= 1) {
      if (stride >= V) {
        int lm = stride / V;
        #pragma unroll
        for (int r = 0; r < V; ++r) {
          u64 mine = kreg[r];
          u64 other = (u64)__shfl_xor((long long)mine, lm);
          int i = tid * V + r;
          bool up = ((i & size) == 0);
          bool lower = ((i & stride) == 0);
          u64 mn = mine < other ? mine : other;
          u64 mx = mine < other ? other : mine;
          kreg[r] = (lower == up) ? mn : mx;
        }
      } else {
        #pragma unroll
        for (int r = 0; r < V; ++r) {
          int pr = r ^ stride;
          if (pr > r) {
            int i = tid * V + r;
            bool up = ((i & size) == 0);
            u64 a = kreg[r], b = kreg[pr];
            if (up ? (a > b) : (a < b)) { kreg[r] = b; kreg[pr] = a; }
          }
        }
      }
    }
  }
  #pragma unroll
  for (int r = 0; r < V; ++r) {
    int i = tid * V + r;
    int rank = np2 - 1 - i;
    if (rank < k) {
      int idx = (int)(~(u32)(kreg[r] & 0xFFFFFFFFull));
      perm[rank] = idx;
      inv[idx] = rank;
    }
  }
}

__global__ void gatherx_k(const float* __restrict__ xsrc, const float* __restrict__ score,
                          const int* __restrict__ perm, int k, int h, float* __restrict__ xdst) {
  long idx = (long)blockIdx.x * 256 + threadIdx.x;
  if (idx >= (long)k * h) return;
  int r = (int)(idx / h);
  int c = (int)(idx - (long)r * h);
  int p = perm[r];
  xdst[idx] = xsrc[(long)p * h + c] * score[p];
}

// fused copy + scatter-add via inverse perm: dst = xs + upscatter(xpool)
__global__ void upadd_k(const float* __restrict__ xs, const float* __restrict__ xpool,
                        const int* __restrict__ inv, float* __restrict__ dst, long nh, int h) {
  long idx = (long)blockIdx.x * 256 + threadIdx.x;
  if (idx >= nh) return;
  int i = (int)(idx / h);
  int c = (int)(idx - (long)i * h);
  float v = xs[idx];
  int r = inv[i];
  if (r >= 0) v += xpool[(long)r * h + c];
  dst[idx] = v;
}

// fused matvec2 + log-softmax output
__global__ void matvec2_final_k(const void* __restrict__ A, int abf, int n,
                                const float* __restrict__ Zs, const double* __restrict__ rs0,
                                const float* __restrict__ b2, float* __restrict__ out,
                                const int* __restrict__ dtf) {
  const int bf = get_bf(abf, dtf);
  int row = blockIdx.x, tid = threadIdx.x;
  const long base = (long)row * n;
  double s0 = 0.0, s1 = 0.0;
  for (int j = tid; j < n; j += 256) {
    double a = (double)ld1(A, bf, base + j);
    s0 += a * (double)Zs[2 * j];
    s1 += a * (double)Zs[2 * j + 1];
  }
  __shared__ double r0[256], r1[256];
  r0[tid] = s0; r1[tid] = s1; __syncthreads();
  for (int st = 128; st > 0; st >>= 1) {
    if (tid < st) { r0[tid] += r0[tid + st]; r1[tid] += r1[tid + st]; }
    __syncthreads();
  }
  if (tid == 0) {
    double y0 = (double)((float)r0[0]);   // replicate float round-trip of old matvec2
    double y1 = (double)((float)r1[0]);
    double di = (double)((float)(1.0 / sqrt(rs0[row] + 2.0)));
    double t0 = di * (y0 + 2.0 * (double)Zs[2 * row]) + (double)b2[0];
    double t1 = di * (y1 + 2.0 * (double)Zs[2 * row + 1]) + (double)b2[1];
    double mx = fmax(t0, t1);
    double l = mx + log(exp(t0 - mx) + exp(t1 - mx));
    out[2 * row] = (float)(t0 - l);
    out[2 * row + 1] = (float)(t1 - l);
  }
}

// ---------- host orchestration ----------
extern "C" void kernel_launch(void* const* d_in, const int* in_sizes, int n_in,
                              void* d_out, int out_size, void* d_ws, size_t ws_size,
                              hipStream_t stream) {
  const int N0 = 4096, H = 200;
  const int K1 = 3072, K2 = 1536, K3 = 768;

  const void* in_x = d_in[0];
  const void* adj  = d_in[1];
  const void* w0 = d_in[2];  const void* b0 = d_in[3];
  const void* w1 = d_in[4];  const void* b1 = d_in[5];
  const void* w2 = d_in[6];  const void* b2 = d_in[7];
  const void* w3 = d_in[8];  const void* b3 = d_in[9];
  const void* p1 = d_in[10]; const void* p2 = d_in[11];
  const void* p3 = d_in[12];
  const void* u0w = d_in[13]; const void* u0b = d_in[14];
  const void* u1w = d_in[15]; const void* u1b = d_in[16];
  const void* u2w = d_in[17]; const void* u2b = d_in[18];

  char* wp = (char*)d_ws;
  auto alloc = [&](size_t bytes) -> void* {
    void* p = (void*)wp;
    wp += (bytes + 255) & ~(size_t)255;
    return p;
  };
  float* As1  = (float*)alloc((size_t)K1 * K1 * 4);
  float* As2  = (float*)alloc((size_t)K2 * K2 * 4);
  float* A3   = (float*)alloc((size_t)K3 * K3 * 4);
  size_t scrBytes = (size_t)36864 * 208 * 4 + 1024;          // Agb i8 / parts (disjoint lifetimes)
  void* scratchU = alloc(scrBytes);
  s8*    Agb  = (s8*)scratchU;
  float* parts = (float*)scratchU;
  u16* Ag3h = (u16*)alloc((size_t)K3 * K2 * 2);
  u16* Ag3l = (u16*)alloc((size_t)K3 * K2 * 2);
  u16* Ah0 = (u16*)alloc((size_t)N0 * N0 * 2);
  u16* Ah1 = (u16*)alloc((size_t)K1 * K1 * 2);
  u16* Ah2 = (u16*)alloc((size_t)K2 * K2 * 2);
  u16* Al2 = (u16*)alloc((size_t)K2 * K2 * 2);
  u16* Ah3 = (u16*)alloc((size_t)K3 * K3 * 2);
  u16* Al3 = (u16*)alloc((size_t)K3 * K3 * 2);
  u16* ZT  = (u16*)alloc((size_t)3 * 208 * N0 * 2);
  float* xs0  = (float*)alloc((size_t)N0 * H * 4);
  float* xs1  = (float*)alloc((size_t)K1 * H * 4);
  float* xs2  = (float*)alloc((size_t)K2 * H * 4);
  float* xcur = (float*)alloc((size_t)N0 * H * 4);
  float* xtmp = (float*)alloc((size_t)N0 * H * 4);
  float* Zbuf = (float*)alloc((size_t)N0 * H * 4);
  float* Xinf = (float*)alloc((size_t)N0 * 3 * 4);
  double* rs0 = (double*)alloc((size_t)N0 * 8);
  double* rs1 = (double*)alloc((size_t)K1 * 8);
  double* rs2 = (double*)alloc((size_t)K2 * 8);
  double* rs3 = (double*)alloc((size_t)K3 * 8);
  float* scores = (float*)alloc((size_t)N0 * 4);
  int* perm1 = (int*)alloc((size_t)K1 * 4);
  int* perm2 = (int*)alloc((size_t)K2 * 4);
  int* perm3 = (int*)alloc((size_t)K3 * 4);
  int* inv1 = (int*)alloc((size_t)N0 * 4);
  int* inv2 = (int*)alloc((size_t)K1 * 4);
  int* inv3 = (int*)alloc((size_t)K2 * 4);
  int* dtflag = (int*)alloc(256);
  float* w0f = (float*)alloc(3 * H * 4);  float* b0f = (float*)alloc(H * 4);
  float* w1f = (float*)alloc(H * H * 4);  float* b1f = (float*)alloc(H * 4);
  float* w2f = (float*)alloc(H * H * 4);  float* b2f = (float*)alloc(H * 4);
  float* w3f = (float*)alloc(H * H * 4);  float* b3f = (float*)alloc(H * 4);
  float* p1f = (float*)alloc(H * 4);
  float* p2f = (float*)alloc(H * 4);
  float* p3f = (float*)alloc(H * 4);
  float* u0wf = (float*)alloc(H * H * 4); float* u0bf = (float*)alloc(H * 4);
  float* u1wf = (float*)alloc(H * H * 4); float* u1bf = (float*)alloc(H * 4);
  float* u2wf = (float*)alloc(H * 2 * 4); float* u2bf = (float*)alloc(2 * 4);
  (void)in_sizes; (void)n_in; (void)out_size; (void)ws_size;

  detect_init_k<<<dim3(1), dim3(64), 0, stream>>>(dtflag);
  detect_k<<<dim3(4096), dim3(256), 0, stream>>>((const u32*)adj, (long)N0 * N0 / 2, dtflag);

  {
    UpBatch ub;
    const void* srcs[19] = {in_x, w0, b0, w1, b1, w2, b2, w3, b3, p1, p2, p3,
                            u0w, u0b, u1w, u1b, u2w, u2b, u2b};
    float* dsts[19] = {Xinf, w0f, b0f, w1f, b1f, w2f, b2f, w3f, b3f, p1f, p2f, p3f,
                       u0wf, u0bf, u1wf, u1bf, u2wf, u2bf, u2bf};
    int ns[19] = {N0 * 3, 3 * H, H, H * H, H, H * H, H, H * H, H, H, H, H,
                  H * H, H, H * H, H, H * 2, 2, 2};
    for (int i = 0; i < 19; ++i) { ub.src[i] = srcs[i]; ub.dst[i] = dsts[i]; ub.n[i] = ns[i]; }
    upcast_batch_k<<<dim3((N0 * 3 + 255) / 256, 19), dim3(256), 0, stream>>>(ub, dtflag);
  }

  a_from_adj_rs_k<<<dim3(N0), dim3(256), 0, stream>>>(adj, dtflag, N0, Ah0, rs0);

  auto gemm64 = [&](const void* A, long lda, int abf, const void* B, long ldb, int bbf,
                    float* C, long ldc, int M, int Nn, int K, const double* rsum, u16* zt) {
    dim3 g((Nn + 63) / 64, (M + 63) / 64);
    gemm64_f64<<<g, dim3(256), 0, stream>>>(A, lda, abf, B, ldb, bbf, C, ldc, M, Nn, K,
                                            rsum, zt, dtflag);
  };

  // GCN: out = maybe_relu(dinv .* (A@Zs + 2 Zs) + b); optional fused pooling score
  auto gcn = [&](const u16* Ah, const u16* Al, int n, int chunks, const double* rs,
                 const float* Xin_, int din, const float* W, const float* bb,
                 float* out, int relu, const float* pwf, float* scoreOut) {
    gemm64(Xin_, din, 0, W, H, 0, Zbuf, H, n, H, din, rs, ZT);  // Z(+scale) + ZT planes
    agg_mfma<13><<<dim3(n / 128, chunks), dim3(256), 0, stream>>>(
        Ah, Al, ZT, parts, n, (n / 32) / chunks);
    reduce_epi_k<<<dim3(n), dim3(256), 0, stream>>>(
        parts, Zbuf, rs, bb, out, n, chunks, relu, pwf, scoreOut);
  };

  auto pool = [&](const float* xin, int n, int np2, int k, int* perm, int* inv, float* xout) {
    if (np2 == 4096)
      topk_fast<4><<<dim3(1), dim3(1024), 0, stream>>>(scores, n, np2, k, perm, inv);
    else
      topk_fast<2><<<dim3(1), dim3(1024), 0, stream>>>(scores, n, np2, k, perm, inv);
    long tot = (long)k * H;
    gatherx_k<<<dim3((unsigned)((tot + 255) / 256)), dim3(256), 0, stream>>>(
        xin, scores, perm, k, H, xout);
  };

  // ---------------- forward ----------------
  gcn(Ah0, nullptr, N0, 8, rs0, Xinf, 3, w0f, b0f, xs0, 1, p1f, scores);

  // down 0: i8 SYRK (fused Ah1 + rowsum)
  pool(xs0, N0, 4096, K1, perm1, inv1, xcur);
  {
    long tot = (long)K1 * N0;
    build_ag_i8_k<<<dim3((unsigned)((tot + 255) / 256)), dim3(256), 0, stream>>>(
        adj, -1, N0, perm1, tot, Agb, dtflag);
    hipMemsetAsync(rs1, 0, (size_t)K1 * 8, stream);
    int nt = K1 / 128;
    syrk_tri_i8<<<dim3(nt * (nt + 1) / 2), dim3(256), 0, stream>>>(
        Agb, N0, As1, K1, N0, Ah1, nullptr, rs1);
  }
  gcn(Ah1, nullptr, K1, 12, rs1, xcur, H, w1f, b1f, xs1, 1, p2f, scores);

  // down 1: i8 SYRK (fused Ah2/Al2 + rowsum)
  pool(xs1, K1, 4096, K2, perm2, inv2, xcur);
  {
    long tot = (long)K2 * K1;
    build_ag_i8_k<<<dim3((unsigned)((tot + 255) / 256)), dim3(256), 0, stream>>>(
        As1, 0, K1, perm2, tot, Agb, dtflag);
    hipMemsetAsync(rs2, 0, (size_t)K2 * 8, stream);
    int nt = K2 / 128;
    syrk_tri_i8<<<dim3(nt * (nt + 1) / 2), dim3(256), 0, stream>>>(
        Agb, K1, As2, K2, K1, Ah2, Al2, rs2);
  }
  gcn(Ah2, Al2, K2, 24, rs2, xcur, H, w2f, b2f, xs2, 1, p3f, scores);

  // down 2: bf16 2-plane K-split triangle (fused Ah3/Al3 + rowsum in reduce)
  pool(xs2, K2, 2048, K3, perm3, inv3, xcur);
  {
    long tot = (long)K3 * K2;
    build_ag3_split_k<<<dim3((unsigned)((tot + 255) / 256)), dim3(256), 0, stream>>>(
        As2, K2, perm3, tot, K2, Ag3h, Ag3l);
    int nt = K3 / 128;
    syrk_tri2_parts<<<dim3(nt * (nt + 1) / 2, 8), dim3(256), 0, stream>>>(
        Ag3h, Ag3l, K2, parts, K3, K2 / 8);
    hipMemsetAsync(rs3, 0, (size_t)K3 * 8, stream);
    long nn = (long)K3 * K3;
    reduce_tri_mirror_k<<<dim3((unsigned)(nn / 256)), dim3(256), 0, stream>>>(
        parts, A3, Ah3, Al3, rs3, K3, 8);
  }
  gcn(Ah3, Al3, K3, 24, rs3, xcur, H, w3f, b3f, xcur, 1, nullptr, nullptr);

  // up 0: j=2
  upadd_k<<<dim3((unsigned)(((long)K2 * H + 255) / 256)), dim3(256), 0, stream>>>(
      xs2, xcur, inv3, xtmp, (long)K2 * H, H);
  gcn(Ah2, Al2, K2, 24, rs2, xtmp, H, u0wf, u0bf, xcur, 1, nullptr, nullptr);

  // up 1: j=1
  upadd_k<<<dim3((unsigned)(((long)K1 * H + 255) / 256)), dim3(256), 0, stream>>>(
      xs1, xcur, inv2, xtmp, (long)K1 * H, H);
  gcn(Ah1, nullptr, K1, 12, rs1, xtmp, H, u1wf, u1bf, xcur, 1, nullptr, nullptr);

  // up 2: j=0
  upadd_k<<<dim3((unsigned)(((long)N0 * H + 255) / 256)), dim3(256), 0, stream>>>(
      xs0, xcur, inv1, xtmp, (long)N0 * H, H);
  gemm64(xtmp, H, 0, u2wf, 2, 0, Zbuf, 2, N0, 2, H, rs0, nullptr);  // Z2 = dinv0 .* (x @ u2w)
  matvec2_final_k<<<dim3(N0), dim3(256), 0, stream>>>(
      adj, -1, N0, Zbuf, rs0, u2bf, (float*)d_out, dtflag);
}

// Round 10
// 942.234 us; speedup vs baseline: 1.2356x; 1.0081x over previous
//
#include <hip/hip_runtime.h>

typedef unsigned short u16;
typedef unsigned int u32;
typedef unsigned long long u64;
typedef signed char s8;
typedef __attribute__((ext_vector_type(8))) short bfrag8;
typedef __attribute__((ext_vector_type(4))) float f32x4;
typedef __attribute__((ext_vector_type(4))) int i32x4;
typedef __attribute__((address_space(1))) const void gconst_void;
typedef __attribute__((address_space(3))) void lds_void_t;

// ---------- helpers ----------
__device__ __forceinline__ float bf2f(u16 u) {
  return __uint_as_float(((u32)u) << 16);
}
__device__ __forceinline__ u16 f2bf(float f) {
  u32 u = __float_as_uint(f);
  u32 r = (u + 0x7FFFu + ((u >> 16) & 1u)) >> 16;  // RTNE
  return (u16)r;
}
__device__ __forceinline__ float ld1(const void* p, int isbf, long idx) {
  return isbf ? bf2f(((const u16*)p)[idx]) : ((const float*)p)[idx];
}
__device__ __forceinline__ void ld4(const void* p, int isbf, long base, long gc, long bound, float v[4]) {
  if (gc + 3 < bound && ((base & 3) == 0)) {
    if (isbf) {
      const ushort4 u = *(const ushort4*)((const u16*)p + base);
      v[0] = bf2f(u.x); v[1] = bf2f(u.y); v[2] = bf2f(u.z); v[3] = bf2f(u.w);
    } else {
      const float4 f = *(const float4*)((const float*)p + base);
      v[0] = f.x; v[1] = f.y; v[2] = f.z; v[3] = f.w;
    }
  } else {
    #pragma unroll
    for (int d = 0; d < 4; ++d) v[d] = (gc + d < bound) ? ld1(p, isbf, base + d) : 0.f;
  }
}

// ---------- input dtype autodetect ----------
__global__ void detect_init_k(int* flag) { if (threadIdx.x == 0 && blockIdx.x == 0) *flag = 0; }

__global__ void detect_k(const u32* __restrict__ a, long nw, int* __restrict__ flag) {
  long stride = (long)gridDim.x * 256;
  int f = 0;
  for (long j = (long)blockIdx.x * 256 + threadIdx.x; j < nw; j += stride) {
    u32 w = a[j];
    if (w == 0x00003F80u || w == 0x3F803F80u) f = 1;
  }
  if (__any(f)) {
    if ((threadIdx.x & 63) == 0) atomicOr(flag, 1);
  }
}

__device__ __forceinline__ int get_bf(int abf, const int* dtf) {
  return (abf >= 0) ? abf : *dtf;
}

// ---------- async global->LDS stage ----------
__device__ __forceinline__ void stageB16(const void* g, void* lds) {
#if __has_builtin(__builtin_amdgcn_global_load_lds)
  __builtin_amdgcn_global_load_lds((gconst_void*)g, (lds_void_t*)lds, 16, 0, 0);
#else
  int lane = threadIdx.x & 63;
  *(int4*)((char*)lds + lane * 16) = *(const int4*)g;
#endif
}

// ---------- i8 triangle SYRK -> bf16 planes + f64 row sums (no fp32 C) ----------
__global__ __launch_bounds__(256) void syrk_tri_i8(
    const s8* __restrict__ Ag, int ldk, int ldc, int K,
    u16* __restrict__ Ah, u16* __restrict__ Al, double* __restrict__ rsum)
{
  __shared__ s8 At[128 * 64];
  __shared__ s8 Bt[128 * 64];
  __shared__ int tb[4][16][17];
  const int t = blockIdx.x;
  int ti = (int)((sqrtf((float)(8 * t + 1)) - 1.0f) * 0.5f);
  while ((ti + 1) * (ti + 2) / 2 <= t) ++ti;
  while (ti * (ti + 1) / 2 > t) --ti;
  const int tj = t - ti * (ti + 1) / 2;

  const int tid = threadIdx.x;
  const int wave = tid >> 6, lane = tid & 63;
  const int wr = wave >> 1, wc = wave & 1;
  const long rowA0 = (long)ti * 128;
  const long rowB0 = (long)tj * 128;

  i32x4 acc[4][4];
  #pragma unroll
  for (int i = 0; i < 4; ++i)
    #pragma unroll
    for (int j = 0; j < 4; ++j) acc[i][j] = (i32x4)0;

  const int srow = lane >> 2;
  const int scol = (lane & 3) * 16;
  const int m = lane & 15, q = lane >> 4;

  for (int k0 = 0; k0 < K; k0 += 64) {
    #pragma unroll
    for (int tt = 0; tt < 2; ++tt) {
      const int r = wave * 32 + tt * 16;
      stageB16(Ag + (rowA0 + r + srow) * (long)ldk + k0 + scol, At + r * 64);
      stageB16(Ag + (rowB0 + r + srow) * (long)ldk + k0 + scol, Bt + r * 64);
    }
    __syncthreads();

    i32x4 af[4], bf[4];
    #pragma unroll
    for (int mt = 0; mt < 4; ++mt)
      af[mt] = *(const i32x4*)(At + (wr * 64 + mt * 16 + m) * 64 + q * 16);
    #pragma unroll
    for (int nt = 0; nt < 4; ++nt)
      bf[nt] = *(const i32x4*)(Bt + (wc * 64 + nt * 16 + m) * 64 + q * 16);
    #pragma unroll
    for (int mt = 0; mt < 4; ++mt)
      #pragma unroll
      for (int nt = 0; nt < 4; ++nt)
        acc[mt][nt] = __builtin_amdgcn_mfma_i32_16x16x64_i8(af[mt], bf[nt], acc[mt][nt], 0, 0, 0);
    __syncthreads();
  }

  // direct (lower) tile: bf16 planes + row partials -> f64 atomics
  #pragma unroll
  for (int mt = 0; mt < 4; ++mt) {
    double rp[4] = {0.0, 0.0, 0.0, 0.0};
    #pragma unroll
    for (int nt = 0; nt < 4; ++nt) {
      const long gr0 = rowA0 + wr * 64 + mt * 16 + q * 4;
      const long gc = rowB0 + wc * 64 + nt * 16 + m;
      #pragma unroll
      for (int r = 0; r < 4; ++r) {
        const long gr = gr0 + r;
        int iv = (gr == gc) ? 0 : acc[mt][nt][r];
        float fv = (float)iv;
        long idx = gr * ldc + gc;
        u16 h = f2bf(fv);
        Ah[idx] = h;
        if (Al) Al[idx] = f2bf(fv - bf2f(h));
        rp[r] += (double)iv;
      }
    }
    #pragma unroll
    for (int r = 0; r < 4; ++r) {
      double v = rp[r];
      for (int off = 8; off > 0; off >>= 1) v += __shfl_down(v, off);
      if (m == 0) atomicAdd(&rsum[rowA0 + wr * 64 + mt * 16 + q * 4 + r], v);
    }
  }
  // mirror tile + column sums
  if (ti != tj) {
    #pragma unroll
    for (int nt = 0; nt < 4; ++nt) {
      double cp = 0.0;
      #pragma unroll
      for (int mt = 0; mt < 4; ++mt) {
        #pragma unroll
        for (int r = 0; r < 4; ++r) tb[wave][q * 4 + r][m] = acc[mt][nt][r];
        const long baseR = rowB0 + wc * 64 + nt * 16;
        const long baseC = rowA0 + wr * 64 + mt * 16;
        #pragma unroll
        for (int r = 0; r < 4; ++r) {
          float tv = (float)tb[wave][m][q * 4 + r];
          long idx = (baseR + q * 4 + r) * ldc + baseC + m;
          u16 h = f2bf(tv);
          Ah[idx] = h;
          if (Al) Al[idx] = f2bf(tv - bf2f(h));
        }
        #pragma unroll
        for (int r = 0; r < 4; ++r) cp += (double)acc[mt][nt][r];
      }
      double v = cp;
      v += __shfl_down(v, 32);
      v += __shfl_down(v, 16);
      if (q == 0) atomicAdd(&rsum[rowB0 + wc * 64 + nt * 16 + m], v);
    }
  }
}

// ---------- bf16 2-plane triangle SYRK, K-split parts (L3) ----------
__global__ __launch_bounds__(256) void syrk_tri2_parts(
    const u16* __restrict__ Ah, const u16* __restrict__ Al, int ldk,
    float* __restrict__ parts, int n, int per)
{
  __shared__ u16 Ath[128 * 32];
  __shared__ u16 Bth[128 * 32];
  __shared__ u16 Atl[128 * 32];
  __shared__ u16 Btl[128 * 32];
  const int t = blockIdx.x;
  int ti = (int)((sqrtf((float)(8 * t + 1)) - 1.0f) * 0.5f);
  while ((ti + 1) * (ti + 2) / 2 <= t) ++ti;
  while (ti * (ti + 1) / 2 > t) --ti;
  const int tj = t - ti * (ti + 1) / 2;

  const int tid = threadIdx.x;
  const int wave = tid >> 6, lane = tid & 63;
  const int wr = wave >> 1, wc = wave & 1;
  const long rowA0 = (long)ti * 128;
  const long rowB0 = (long)tj * 128;
  const int kbeg = blockIdx.y * per;
  const int kend = kbeg + per;

  f32x4 acc[4][4];
  #pragma unroll
  for (int i = 0; i < 4; ++i)
    #pragma unroll
    for (int j = 0; j < 4; ++j) acc[i][j] = (f32x4)0.f;

  const int srow = lane >> 2;
  const int scol = (lane & 3) * 8;
  const int m = lane & 15, q = lane >> 4;

  for (int k0 = kbeg; k0 < kend; k0 += 32) {
    #pragma unroll
    for (int tt = 0; tt < 2; ++tt) {
      const int r = wave * 32 + tt * 16;
      stageB16(Ah + (rowA0 + r + srow) * (long)ldk + k0 + scol, Ath + r * 32);
      stageB16(Ah + (rowB0 + r + srow) * (long)ldk + k0 + scol, Bth + r * 32);
      stageB16(Al + (rowA0 + r + srow) * (long)ldk + k0 + scol, Atl + r * 32);
      stageB16(Al + (rowB0 + r + srow) * (long)ldk + k0 + scol, Btl + r * 32);
    }
    __syncthreads();

    bfrag8 afh[4], afl[4], bfh[4], bfl[4];
    #pragma unroll
    for (int mt = 0; mt < 4; ++mt) {
      afh[mt] = *(const bfrag8*)(Ath + (wr * 64 + mt * 16 + m) * 32 + q * 8);
      afl[mt] = *(const bfrag8*)(Atl + (wr * 64 + mt * 16 + m) * 32 + q * 8);
    }
    #pragma unroll
    for (int nt = 0; nt < 4; ++nt) {
      bfh[nt] = *(const bfrag8*)(Bth + (wc * 64 + nt * 16 + m) * 32 + q * 8);
      bfl[nt] = *(const bfrag8*)(Btl + (wc * 64 + nt * 16 + m) * 32 + q * 8);
    }
    #pragma unroll
    for (int mt = 0; mt < 4; ++mt)
      #pragma unroll
      for (int nt = 0; nt < 4; ++nt) {
        acc[mt][nt] = __builtin_amdgcn_mfma_f32_16x16x32_bf16(afh[mt], bfh[nt], acc[mt][nt], 0, 0, 0);
        acc[mt][nt] = __builtin_amdgcn_mfma_f32_16x16x32_bf16(afh[mt], bfl[nt], acc[mt][nt], 0, 0, 0);
        acc[mt][nt] = __builtin_amdgcn_mfma_f32_16x16x32_bf16(afl[mt], bfh[nt], acc[mt][nt], 0, 0, 0);
        acc[mt][nt] = __builtin_amdgcn_mfma_f32_16x16x32_bf16(afl[mt], bfl[nt], acc[mt][nt], 0, 0, 0);
      }
    __syncthreads();
  }

  float* P = parts + (long)blockIdx.y * n * n;
  #pragma unroll
  for (int mt = 0; mt < 4; ++mt) {
    #pragma unroll
    for (int nt = 0; nt < 4; ++nt) {
      const long gr0 = rowA0 + wr * 64 + mt * 16 + q * 4;
      const long gc = rowB0 + wc * 64 + nt * 16 + m;
      #pragma unroll
      for (int r = 0; r < 4; ++r)
        P[(gr0 + r) * n + gc] = acc[mt][nt][r];
    }
  }
}

// sum nz parts (lower valid), mirror, zero diag; Ah/Al write + f64 row sums (no fp32 C).
// Requires n % 256 == 0 (each block within one row).
__global__ void reduce_tri_mirror_k(const float* __restrict__ parts,
                                    u16* __restrict__ Ah, u16* __restrict__ Al,
                                    double* __restrict__ rsum, int n, int nz) {
  __shared__ double red[256];
  const int tid = threadIdx.x;
  long idx = (long)blockIdx.x * 256 + tid;
  long nn = (long)n * n;
  long r = idx / n, c = idx - r * n;
  double myv = 0.0;
  if (idx < nn) {
    if (r == c) {
      Ah[idx] = 0; Al[idx] = 0;
    } else if (r > c) {
      float s = 0.f;
      for (int z = 0; z < nz; ++z) s += parts[(long)z * nn + r * n + c];
      long mi = c * n + r;
      u16 h = f2bf(s);
      u16 l = f2bf(s - bf2f(h));
      Ah[idx] = h; Al[idx] = l;
      Ah[mi] = h;  Al[mi] = l;
      myv = (double)s;
      atomicAdd(&rsum[c], (double)s);  // column-side (exact: integers)
    }
  }
  red[tid] = myv;
  __syncthreads();
  for (int st = 128; st > 0; st >>= 1) {
    if (tid < st) red[tid] += red[tid + st];
    __syncthreads();
  }
  if (tid == 0 && idx < nn) atomicAdd(&rsum[r], red[0]);
}

// build i8 augment operand
__global__ void build_ag_i8_k(const void* __restrict__ src, int srcbf, int nsrc,
                              const int* __restrict__ perm, long tot,
                              s8* __restrict__ Ag, const int* __restrict__ dtf) {
  long idx = (long)blockIdx.x * 256 + threadIdx.x;
  if (idx >= tot) return;
  int r = (int)(idx / nsrc);
  int c = (int)(idx - (long)r * nsrc);
  int p = perm[r];
  float v = ld1(src, get_bf(srcbf, dtf), (long)p * nsrc + c);
  if (c == p) v += 1.f;
  Ag[idx] = (s8)(int)v;
}

// build level-2 augment operand in exact 2-plane bf16 from Ah2/Al2 planes
__global__ void build_ag3_split2_k(const u16* __restrict__ srcH, const u16* __restrict__ srcL,
                                   int nsrc, const int* __restrict__ perm, long tot, int ld,
                                   u16* __restrict__ Agh, u16* __restrict__ Agl) {
  long idx = (long)blockIdx.x * 256 + threadIdx.x;
  if (idx >= tot) return;
  int r = (int)(idx / ld);
  int c = (int)(idx - (long)r * ld);
  int p = perm[r];
  long si = (long)p * nsrc + c;
  float v = bf2f(srcH[si]) + bf2f(srcL[si]);  // exact integer reconstruction
  if (c == p) v += 1.f;
  u16 h = f2bf(v);
  Agh[idx] = h;
  Agl[idx] = f2bf(v - bf2f(h));
}

// ---------- MFMA aggregation: Y = A @ Z ----------
template<int NT>
__global__ __launch_bounds__(256) void agg_mfma(
    const u16* __restrict__ Ah, const u16* __restrict__ Al,
    const u16* __restrict__ ZT, float* __restrict__ parts,
    int K, int per_steps)
{
  __shared__ u16 At[128 * 32];
  __shared__ u16 Alt[128 * 32];
  __shared__ u16 Zt[3 * NT * 512];
  const int tid = threadIdx.x;
  const int wave = tid >> 6, lane = tid & 63;
  const long row0 = (long)blockIdx.x * 128;
  const int chunk = blockIdx.y;
  const int kbeg = chunk * per_steps * 32;
  const int kend = min(K, kbeg + per_steps * 32);
  const int m = lane & 15, q = lane >> 4;
  const int srow = lane >> 2, scol = (lane & 3) * 8;
  const bool hasAl = (Al != nullptr);

  f32x4 acc[2][NT];
  #pragma unroll
  for (int rt = 0; rt < 2; ++rt)
    #pragma unroll
    for (int ct = 0; ct < NT; ++ct) acc[rt][ct] = (f32x4)0.f;

  for (int k0 = kbeg; k0 < kend; k0 += 32) {
    #pragma unroll
    for (int t = 0; t < 2; ++t) {
      const int r = wave * 32 + t * 16;
      stageB16(Ah + (row0 + r + srow) * (long)K + k0 + scol, At + r * 32);
      if (hasAl)
        stageB16(Al + (row0 + r + srow) * (long)K + k0 + scol, Alt + r * 32);
    }
    for (int s = wave; s < 3 * NT; s += 4) {
      const u16* g = ZT + ((long)(s * 16 + srow)) * K + k0 + scol;
      stageB16(g, Zt + s * 512);
    }
    __syncthreads();

    bfrag8 af0 = *(const bfrag8*)(At + (wave * 32 + m) * 32 + q * 8);
    bfrag8 af1 = *(const bfrag8*)(At + (wave * 32 + 16 + m) * 32 + q * 8);
    bfrag8 al0, al1;
    if (hasAl) {
      al0 = *(const bfrag8*)(Alt + (wave * 32 + m) * 32 + q * 8);
      al1 = *(const bfrag8*)(Alt + (wave * 32 + 16 + m) * 32 + q * 8);
    }
    #pragma unroll
    for (int ct = 0; ct < NT; ++ct) {
      bfrag8 b0 = *(const bfrag8*)(Zt + (0 * NT + ct) * 512 + m * 32 + q * 8);
      bfrag8 b1 = *(const bfrag8*)(Zt + (1 * NT + ct) * 512 + m * 32 + q * 8);
      bfrag8 b2 = *(const bfrag8*)(Zt + (2 * NT + ct) * 512 + m * 32 + q * 8);
      acc[0][ct] = __builtin_amdgcn_mfma_f32_16x16x32_bf16(af0, b0, acc[0][ct], 0, 0, 0);
      acc[0][ct] = __builtin_amdgcn_mfma_f32_16x16x32_bf16(af0, b1, acc[0][ct], 0, 0, 0);
      acc[0][ct] = __builtin_amdgcn_mfma_f32_16x16x32_bf16(af0, b2, acc[0][ct], 0, 0, 0);
      acc[1][ct] = __builtin_amdgcn_mfma_f32_16x16x32_bf16(af1, b0, acc[1][ct], 0, 0, 0);
      acc[1][ct] = __builtin_amdgcn_mfma_f32_16x16x32_bf16(af1, b1, acc[1][ct], 0, 0, 0);
      acc[1][ct] = __builtin_amdgcn_mfma_f32_16x16x32_bf16(af1, b2, acc[1][ct], 0, 0, 0);
      if (hasAl) {
        acc[0][ct] = __builtin_amdgcn_mfma_f32_16x16x32_bf16(al0, b0, acc[0][ct], 0, 0, 0);
        acc[0][ct] = __builtin_amdgcn_mfma_f32_16x16x32_bf16(al0, b1, acc[0][ct], 0, 0, 0);
        acc[1][ct] = __builtin_amdgcn_mfma_f32_16x16x32_bf16(al1, b0, acc[1][ct], 0, 0, 0);
        acc[1][ct] = __builtin_amdgcn_mfma_f32_16x16x32_bf16(al1, b1, acc[1][ct], 0, 0, 0);
      }
    }
    __syncthreads();
  }

  float* P = parts + (long)chunk * gridDim.x * 128 * (NT * 16);
  #pragma unroll
  for (int rt = 0; rt < 2; ++rt) {
    #pragma unroll
    for (int ct = 0; ct < NT; ++ct) {
      const long grow0 = row0 + wave * 32 + rt * 16 + q * 4;
      const long gcol = ct * 16 + m;
      #pragma unroll
      for (int r = 0; r < 4; ++r)
        P[(grow0 + r) * (NT * 16) + gcol] = acc[rt][ct][r];
    }
  }
}

// fused: reduce parts + GCN epilogue (+ optional pooling score, bit-identical to score_k)
__global__ __launch_bounds__(256) void reduce_epi_k(
    const float* __restrict__ parts, const float* __restrict__ Zs,
    const double* __restrict__ rs, const float* __restrict__ b,
    float* __restrict__ out, int n, int nz, int relu,
    const float* __restrict__ pw, float* __restrict__ score)
{
  __shared__ float vrow[200];
  const int i = blockIdx.x, tid = threadIdx.x;
  float dv = (float)(1.0 / sqrt(rs[i] + 2.0));
  if (tid < 200) {
    long base = (long)i * 208 + tid;
    float s = 0.f;
    for (int c = 0; c < nz; ++c) s += parts[(long)c * n * 208 + base];
    float v = dv * (s + 2.f * Zs[(long)i * 200 + tid]) + b[tid];
    if (relu) v = fmaxf(v, 0.f);
    out[(long)i * 200 + tid] = v;
    if (score) vrow[tid] = v;
  }
  if (!score) return;
  __syncthreads();
  if (tid < 64) {
    double ps = 0.0;
    for (int j = tid; j < 200; j += 64) { double w = pw[j]; ps += w * w; }
    for (int off = 32; off > 0; off >>= 1) ps += __shfl_down(ps, off);
    double nrm = sqrt(__shfl(ps, 0));
    double s = 0.0;
    for (int j = tid; j < 200; j += 64) s += (double)vrow[j] * (double)pw[j];
    for (int off = 32; off > 0; off >>= 1) s += __shfl_down(s, off);
    if (tid == 0) score[i] = (float)tanh(s / nrm);
  }
}

// fused adj->bf16 plane + row sums (level 0)
__global__ void a_from_adj_rs_k(const void* __restrict__ adj, const int* __restrict__ dtf,
                                int n, u16* __restrict__ Ah, double* __restrict__ rs) {
  __shared__ double red[256];
  int bf = *dtf;
  const int row = blockIdx.x, tid = threadIdx.x;
  const long base = (long)row * n;
  double s = 0.0;
  for (int j = tid; j < n; j += 256) {
    float v = ld1(adj, bf, base + j);
    Ah[base + j] = bf ? ((const u16*)adj)[base + j] : f2bf(v);
    s += (double)v;
  }
  red[tid] = s; __syncthreads();
  for (int st = 128; st > 0; st >>= 1) {
    if (tid < st) red[tid] += red[tid + st];
    __syncthreads();
  }
  if (tid == 0) rs[row] = red[0];
}

// ---------- fp64 GEMM (x@W) with fused dinv scale + transposed 3-plane ZT split ----------
__global__ __launch_bounds__(256) void gemm64_f64(
    const void* __restrict__ Ap, long lda, int abf,
    const void* __restrict__ Bp, long ldb, int bbf,
    float* __restrict__ C, long ldc, int M, int N, int K,
    const double* __restrict__ rsum, u16* __restrict__ ZT, const int* __restrict__ dtf)
{
  const int abf_ = get_bf(abf, dtf);
  const int bbf_ = get_bf(bbf, dtf);
  __shared__ float As[16][64];
  __shared__ float Bs[16][64];
  const int tid = threadIdx.x;
  const int tr = tid >> 4, tc = tid & 15;
  const long row0 = (long)blockIdx.y * 64;
  const long col0 = (long)blockIdx.x * 64;
  double acc[4][4];
  #pragma unroll
  for (int i = 0; i < 4; ++i)
    #pragma unroll
    for (int j = 0; j < 4; ++j) acc[i][j] = 0.0;

  const int am = tid >> 2;
  const int ak = (tid & 3) * 4;
  const int bk = tid >> 4;
  const int bn = (tid & 15) * 4;

  for (int k0 = 0; k0 < K; k0 += 16) {
    float va[4] = {0.f, 0.f, 0.f, 0.f};
    {
      long gm = row0 + am; long gk = k0 + ak;
      if (gm < M && gk < K) ld4(Ap, abf_, gm * lda + gk, gk, K, va);
    }
    As[ak + 0][am] = va[0]; As[ak + 1][am] = va[1];
    As[ak + 2][am] = va[2]; As[ak + 3][am] = va[3];

    float vb[4] = {0.f, 0.f, 0.f, 0.f};
    {
      long gk = k0 + bk; long gn = col0 + bn;
      if (gk < K && gn < N) ld4(Bp, bbf_, gk * ldb + gn, gn, N, vb);
    }
    Bs[bk][bn + 0] = vb[0]; Bs[bk][bn + 1] = vb[1];
    Bs[bk][bn + 2] = vb[2]; Bs[bk][bn + 3] = vb[3];

    __syncthreads();
    #pragma unroll
    for (int kk = 0; kk < 16; ++kk) {
      float a[4], b[4];
      #pragma unroll
      for (int i = 0; i < 4; ++i) a[i] = As[kk][tr * 4 + i];
      #pragma unroll
      for (int j = 0; j < 4; ++j) b[j] = Bs[kk][tc * 4 + j];
      #pragma unroll
      for (int i = 0; i < 4; ++i)
        #pragma unroll
        for (int j = 0; j < 4; ++j)
          acc[i][j] += (double)a[i] * (double)b[j];
    }
    __syncthreads();
  }
  #pragma unroll
  for (int i = 0; i < 4; ++i) {
    long gm = row0 + tr * 4 + i;
    if (gm >= M) continue;
    float sc = rsum ? (float)(1.0 / sqrt(rsum[gm] + 2.0)) : 1.f;
    #pragma unroll
    for (int j = 0; j < 4; ++j) {
      long gn = col0 + tc * 4 + j;
      if (gn < N) {
        float v0 = (float)acc[i][j];       // f64 -> f32 (bit-identical to prior path)
        float v = v0 * sc;
        C[gm * ldc + gn] = v;
        if (ZT) {
          u16 hi = f2bf(v); float r1 = v - bf2f(hi);
          u16 mi = f2bf(r1); float r2 = r1 - bf2f(mi);
          u16 lo = f2bf(r2);
          ZT[((long)0 * 208 + gn) * M + gm] = hi;
          ZT[((long)1 * 208 + gn) * M + gm] = mi;
          ZT[((long)2 * 208 + gn) * M + gm] = lo;
        }
      }
    }
  }
}

// ---------- small kernels ----------
struct UpBatch {
  const void* src[19];
  float* dst[19];
  int n[19];
};

__global__ void upcast_batch_k(UpBatch ub, const int* __restrict__ dtf) {
  int bf = *dtf;
  int a = blockIdx.y;
  int i = blockIdx.x * 256 + threadIdx.x;
  if (i < ub.n[a]) ub.dst[a][i] = ld1(ub.src[a], bf, i);
}

// register/shuffle bitonic top-k; also emits inverse permutation (-1 = not selected)
template<int V>
__global__ __launch_bounds__(1024) void topk_fast(const float* __restrict__ score,
                                                  int n, int np2, int k,
                                                  int* __restrict__ perm,
                                                  int* __restrict__ inv) {
  __shared__ u64 keys[4096];
  const int tid = threadIdx.x;
  const int REGMAX = 32 * V;
  for (int i = tid; i < n; i += 1024) inv[i] = -1;
  u64 kreg[V];
  #pragma unroll
  for (int r = 0; r < V; ++r) {
    int i = tid * V + r;
    u64 key = 0ULL;
    if (i < n) {
      u32 b = __float_as_uint(score[i]);
      u32 u = (b & 0x80000000u) ? ~b : (b | 0x80000000u);
      key = ((u64)u << 32) | (u32)(~(u32)i);
    }
    kreg[r] = key;
  }

  for (int size = 2; size <= np2; size <<= 1) {
    int stride = size >> 1;
    if (stride > REGMAX) {
      #pragma unroll
      for (int r = 0; r < V; ++r) keys[tid * V + r] = kreg[r];
      __syncthreads();
      for (; stride > REGMAX; stride >>= 1) {
        for (int i = tid; i < np2; i += 1024) {
          int j = i ^ stride;
          if (j > i) {
            u64 a = keys[i], b = keys[j];
            bool up = ((i & size) == 0);
            if (up ? (a > b) : (a < b)) { keys[i] = b; keys[j] = a; }
          }
        }
        __syncthreads();
      }
      #pragma unroll
      for (int r = 0; r < V; ++r) kreg[r] = keys[tid * V + r];
    }
    for (; stride >= 1; stride >>= 1) {
      if (stride >= V) {
        int lm = stride / V;
        #pragma unroll
        for (int r = 0; r < V; ++r) {
          u64 mine = kreg[r];
          u64 other = (u64)__shfl_xor((long long)mine, lm);
          int i = tid * V + r;
          bool up = ((i & size) == 0);
          bool lower = ((i & stride) == 0);
          u64 mn = mine < other ? mine : other;
          u64 mx = mine < other ? other : mine;
          kreg[r] = (lower == up) ? mn : mx;
        }
      } else {
        #pragma unroll
        for (int r = 0; r < V; ++r) {
          int pr = r ^ stride;
          if (pr > r) {
            int i = tid * V + r;
            bool up = ((i & size) == 0);
            u64 a = kreg[r], b = kreg[pr];
            if (up ? (a > b) : (a < b)) { kreg[r] = b; kreg[pr] = a; }
          }
        }
      }
    }
  }
  #pragma unroll
  for (int r = 0; r < V; ++r) {
    int i = tid * V + r;
    int rank = np2 - 1 - i;
    if (rank < k) {
      int idx = (int)(~(u32)(kreg[r] & 0xFFFFFFFFull));
      perm[rank] = idx;
      inv[idx] = rank;
    }
  }
}

__global__ void gatherx_k(const float* __restrict__ xsrc, const float* __restrict__ score,
                          const int* __restrict__ perm, int k, int h, float* __restrict__ xdst) {
  long idx = (long)blockIdx.x * 256 + threadIdx.x;
  if (idx >= (long)k * h) return;
  int r = (int)(idx / h);
  int c = (int)(idx - (long)r * h);
  int p = perm[r];
  xdst[idx] = xsrc[(long)p * h + c] * score[p];
}

// fused copy + scatter-add via inverse perm: dst = xs + upscatter(xpool)
__global__ void upadd_k(const float* __restrict__ xs, const float* __restrict__ xpool,
                        const int* __restrict__ inv, float* __restrict__ dst, long nh, int h) {
  long idx = (long)blockIdx.x * 256 + threadIdx.x;
  if (idx >= nh) return;
  int i = (int)(idx / h);
  int c = (int)(idx - (long)i * h);
  float v = xs[idx];
  int r = inv[i];
  if (r >= 0) v += xpool[(long)r * h + c];
  dst[idx] = v;
}

// fused matvec2 + log-softmax output
__global__ void matvec2_final_k(const void* __restrict__ A, int abf, int n,
                                const float* __restrict__ Zs, const double* __restrict__ rs0,
                                const float* __restrict__ b2, float* __restrict__ out,
                                const int* __restrict__ dtf) {
  const int bf = get_bf(abf, dtf);
  int row = blockIdx.x, tid = threadIdx.x;
  const long base = (long)row * n;
  double s0 = 0.0, s1 = 0.0;
  for (int j = tid; j < n; j += 256) {
    double a = (double)ld1(A, bf, base + j);
    s0 += a * (double)Zs[2 * j];
    s1 += a * (double)Zs[2 * j + 1];
  }
  __shared__ double r0[256], r1[256];
  r0[tid] = s0; r1[tid] = s1; __syncthreads();
  for (int st = 128; st > 0; st >>= 1) {
    if (tid < st) { r0[tid] += r0[tid + st]; r1[tid] += r1[tid + st]; }
    __syncthreads();
  }
  if (tid == 0) {
    double y0 = (double)((float)r0[0]);
    double y1 = (double)((float)r1[0]);
    double di = (double)((float)(1.0 / sqrt(rs0[row] + 2.0)));
    double t0 = di * (y0 + 2.0 * (double)Zs[2 * row]) + (double)b2[0];
    double t1 = di * (y1 + 2.0 * (double)Zs[2 * row + 1]) + (double)b2[1];
    double mx = fmax(t0, t1);
    double l = mx + log(exp(t0 - mx) + exp(t1 - mx));
    out[2 * row] = (float)(t0 - l);
    out[2 * row + 1] = (float)(t1 - l);
  }
}

// ---------- host orchestration ----------
extern "C" void kernel_launch(void* const* d_in, const int* in_sizes, int n_in,
                              void* d_out, int out_size, void* d_ws, size_t ws_size,
                              hipStream_t stream) {
  const int N0 = 4096, H = 200;
  const int K1 = 3072, K2 = 1536, K3 = 768;

  const void* in_x = d_in[0];
  const void* adj  = d_in[1];
  const void* w0 = d_in[2];  const void* b0 = d_in[3];
  const void* w1 = d_in[4];  const void* b1 = d_in[5];
  const void* w2 = d_in[6];  const void* b2 = d_in[7];
  const void* w3 = d_in[8];  const void* b3 = d_in[9];
  const void* p1 = d_in[10]; const void* p2 = d_in[11];
  const void* p3 = d_in[12];
  const void* u0w = d_in[13]; const void* u0b = d_in[14];
  const void* u1w = d_in[15]; const void* u1b = d_in[16];
  const void* u2w = d_in[17]; const void* u2b = d_in[18];

  char* wp = (char*)d_ws;
  auto alloc = [&](size_t bytes) -> void* {
    void* p = (void*)wp;
    wp += (bytes + 255) & ~(size_t)255;
    return p;
  };
  size_t scrBytes = (size_t)36864 * 208 * 4 + 1024;          // Agb i8 / parts (disjoint lifetimes)
  void* scratchU = alloc(scrBytes);
  s8*    Agb  = (s8*)scratchU;
  float* parts = (float*)scratchU;
  u16* Ag3h = (u16*)alloc((size_t)K3 * K2 * 2);
  u16* Ag3l = (u16*)alloc((size_t)K3 * K2 * 2);
  u16* Ah0 = (u16*)alloc((size_t)N0 * N0 * 2);
  u16* Ah1 = (u16*)alloc((size_t)K1 * K1 * 2);
  u16* Ah2 = (u16*)alloc((size_t)K2 * K2 * 2);
  u16* Al2 = (u16*)alloc((size_t)K2 * K2 * 2);
  u16* Ah3 = (u16*)alloc((size_t)K3 * K3 * 2);
  u16* Al3 = (u16*)alloc((size_t)K3 * K3 * 2);
  u16* ZT  = (u16*)alloc((size_t)3 * 208 * N0 * 2);
  float* xs0  = (float*)alloc((size_t)N0 * H * 4);
  float* xs1  = (float*)alloc((size_t)K1 * H * 4);
  float* xs2  = (float*)alloc((size_t)K2 * H * 4);
  float* xcur = (float*)alloc((size_t)N0 * H * 4);
  float* xtmp = (float*)alloc((size_t)N0 * H * 4);
  float* Zbuf = (float*)alloc((size_t)N0 * H * 4);
  float* Xinf = (float*)alloc((size_t)N0 * 3 * 4);
  double* rs0 = (double*)alloc((size_t)N0 * 8);
  double* rs1 = (double*)alloc((size_t)K1 * 8);   // rs1..rs3 contiguous (256B multiples)
  double* rs2 = (double*)alloc((size_t)K2 * 8);
  double* rs3 = (double*)alloc((size_t)K3 * 8);
  float* scores = (float*)alloc((size_t)N0 * 4);
  int* perm1 = (int*)alloc((size_t)K1 * 4);
  int* perm2 = (int*)alloc((size_t)K2 * 4);
  int* perm3 = (int*)alloc((size_t)K3 * 4);
  int* inv1 = (int*)alloc((size_t)N0 * 4);
  int* inv2 = (int*)alloc((size_t)K1 * 4);
  int* inv3 = (int*)alloc((size_t)K2 * 4);
  int* dtflag = (int*)alloc(256);
  float* w0f = (float*)alloc(3 * H * 4);  float* b0f = (float*)alloc(H * 4);
  float* w1f = (float*)alloc(H * H * 4);  float* b1f = (float*)alloc(H * 4);
  float* w2f = (float*)alloc(H * H * 4);  float* b2f = (float*)alloc(H * 4);
  float* w3f = (float*)alloc(H * H * 4);  float* b3f = (float*)alloc(H * 4);
  float* p1f = (float*)alloc(H * 4);
  float* p2f = (float*)alloc(H * 4);
  float* p3f = (float*)alloc(H * 4);
  float* u0wf = (float*)alloc(H * H * 4); float* u0bf = (float*)alloc(H * 4);
  float* u1wf = (float*)alloc(H * H * 4); float* u1bf = (float*)alloc(H * 4);
  float* u2wf = (float*)alloc(H * 2 * 4); float* u2bf = (float*)alloc(2 * 4);
  (void)in_sizes; (void)n_in; (void)out_size; (void)ws_size;

  detect_init_k<<<dim3(1), dim3(64), 0, stream>>>(dtflag);
  detect_k<<<dim3(4096), dim3(256), 0, stream>>>((const u32*)adj, (long)N0 * N0 / 2, dtflag);

  // zero all atomic row-sum buffers in one memset (rs1..rs3 contiguous)
  hipMemsetAsync(rs1, 0, (size_t)(K1 + K2 + K3) * 8, stream);

  {
    UpBatch ub;
    const void* srcs[19] = {in_x, w0, b0, w1, b1, w2, b2, w3, b3, p1, p2, p3,
                            u0w, u0b, u1w, u1b, u2w, u2b, u2b};
    float* dsts[19] = {Xinf, w0f, b0f, w1f, b1f, w2f, b2f, w3f, b3f, p1f, p2f, p3f,
                       u0wf, u0bf, u1wf, u1bf, u2wf, u2bf, u2bf};
    int ns[19] = {N0 * 3, 3 * H, H, H * H, H, H * H, H, H * H, H, H, H, H,
                  H * H, H, H * H, H, H * 2, 2, 2};
    for (int i = 0; i < 19; ++i) { ub.src[i] = srcs[i]; ub.dst[i] = dsts[i]; ub.n[i] = ns[i]; }
    upcast_batch_k<<<dim3((N0 * 3 + 255) / 256, 19), dim3(256), 0, stream>>>(ub, dtflag);
  }

  a_from_adj_rs_k<<<dim3(N0), dim3(256), 0, stream>>>(adj, dtflag, N0, Ah0, rs0);

  auto gemm64 = [&](const void* A, long lda, int abf, const void* B, long ldb, int bbf,
                    float* C, long ldc, int M, int Nn, int K, const double* rsum, u16* zt) {
    dim3 g((Nn + 63) / 64, (M + 63) / 64);
    gemm64_f64<<<g, dim3(256), 0, stream>>>(A, lda, abf, B, ldb, bbf, C, ldc, M, Nn, K,
                                            rsum, zt, dtflag);
  };

  // GCN: out = maybe_relu(dinv .* (A@Zs + 2 Zs) + b); optional fused pooling score
  auto gcn = [&](const u16* Ah, const u16* Al, int n, int chunks, const double* rs,
                 const float* Xin_, int din, const float* W, const float* bb,
                 float* out, int relu, const float* pwf, float* scoreOut) {
    gemm64(Xin_, din, 0, W, H, 0, Zbuf, H, n, H, din, rs, ZT);  // Z(+scale) + ZT planes
    agg_mfma<13><<<dim3(n / 128, chunks), dim3(256), 0, stream>>>(
        Ah, Al, ZT, parts, n, (n / 32) / chunks);
    reduce_epi_k<<<dim3(n), dim3(256), 0, stream>>>(
        parts, Zbuf, rs, bb, out, n, chunks, relu, pwf, scoreOut);
  };

  auto pool = [&](const float* xin, int n, int np2, int k, int* perm, int* inv, float* xout) {
    if (np2 == 4096)
      topk_fast<4><<<dim3(1), dim3(1024), 0, stream>>>(scores, n, np2, k, perm, inv);
    else
      topk_fast<2><<<dim3(1), dim3(1024), 0, stream>>>(scores, n, np2, k, perm, inv);
    long tot = (long)k * H;
    gatherx_k<<<dim3((unsigned)((tot + 255) / 256)), dim3(256), 0, stream>>>(
        xin, scores, perm, k, H, xout);
  };

  // ---------------- forward ----------------
  gcn(Ah0, nullptr, N0, 8, rs0, Xinf, 3, w0f, b0f, xs0, 1, p1f, scores);

  // down 0: i8 SYRK (Ah1 + rowsum only)
  pool(xs0, N0, 4096, K1, perm1, inv1, xcur);
  {
    long tot = (long)K1 * N0;
    build_ag_i8_k<<<dim3((unsigned)((tot + 255) / 256)), dim3(256), 0, stream>>>(
        adj, -1, N0, perm1, tot, Agb, dtflag);
    int nt = K1 / 128;
    syrk_tri_i8<<<dim3(nt * (nt + 1) / 2), dim3(256), 0, stream>>>(
        Agb, N0, K1, N0, Ah1, nullptr, rs1);
  }
  gcn(Ah1, nullptr, K1, 12, rs1, xcur, H, w1f, b1f, xs1, 1, p2f, scores);

  // down 1: i8 SYRK (Ah2/Al2 + rowsum); source read from bf16 Ah1 (exact ints <= 70)
  pool(xs1, K1, 4096, K2, perm2, inv2, xcur);
  {
    long tot = (long)K2 * K1;
    build_ag_i8_k<<<dim3((unsigned)((tot + 255) / 256)), dim3(256), 0, stream>>>(
        Ah1, 1, K1, perm2, tot, Agb, dtflag);
    int nt = K2 / 128;
    syrk_tri_i8<<<dim3(nt * (nt + 1) / 2), dim3(256), 0, stream>>>(
        Agb, K1, K2, K1, Ah2, Al2, rs2);
  }
  gcn(Ah2, Al2, K2, 24, rs2, xcur, H, w2f, b2f, xs2, 1, p3f, scores);

  // down 2: bf16 2-plane K-split triangle (Ah3/Al3 + rowsum in reduce)
  pool(xs2, K2, 2048, K3, perm3, inv3, xcur);
  {
    long tot = (long)K3 * K2;
    build_ag3_split2_k<<<dim3((unsigned)((tot + 255) / 256)), dim3(256), 0, stream>>>(
        Ah2, Al2, K2, perm3, tot, K2, Ag3h, Ag3l);
    int nt = K3 / 128;
    syrk_tri2_parts<<<dim3(nt * (nt + 1) / 2, 8), dim3(256), 0, stream>>>(
        Ag3h, Ag3l, K2, parts, K3, K2 / 8);
    long nn = (long)K3 * K3;
    reduce_tri_mirror_k<<<dim3((unsigned)(nn / 256)), dim3(256), 0, stream>>>(
        parts, Ah3, Al3, rs3, K3, 8);
  }
  gcn(Ah3, Al3, K3, 24, rs3, xcur, H, w3f, b3f, xcur, 1, nullptr, nullptr);

  // up 0: j=2
  upadd_k<<<dim3((unsigned)(((long)K2 * H + 255) / 256)), dim3(256), 0, stream>>>(
      xs2, xcur, inv3, xtmp, (long)K2 * H, H);
  gcn(Ah2, Al2, K2, 24, rs2, xtmp, H, u0wf, u0bf, xcur, 1, nullptr, nullptr);

  // up 1: j=1
  upadd_k<<<dim3((unsigned)(((long)K1 * H + 255) / 256)), dim3(256), 0, stream>>>(
      xs1, xcur, inv2, xtmp, (long)K1 * H, H);
  gcn(Ah1, nullptr, K1, 12, rs1, xtmp, H, u1wf, u1bf, xcur, 1, nullptr, nullptr);

  // up 2: j=0
  upadd_k<<<dim3((unsigned)(((long)N0 * H + 255) / 256)), dim3(256), 0, stream>>>(
      xs0, xcur, inv1, xtmp, (long)N0 * H, H);
  gemm64(xtmp, H, 0, u2wf, 2, 0, Zbuf, 2, N0, 2, H, rs0, nullptr);  // Z2 = dinv0 .* (x @ u2w)
  matvec2_final_k<<<dim3(N0), dim3(256), 0, stream>>>(
      adj, -1, N0, Zbuf, rs0, u2bf, (float*)d_out, dtflag);
}